// Round 1
// baseline (4415.426 us; speedup 1.0000x reference)
//
#include <hip/hip_runtime.h>
#include <hip/hip_bf16.h>
#include <cstdint>
#include <cstddef>

// Problem constants (match reference)
static constexpr int D_IN  = 128;
static constexpr int D_HID = 128;
static constexpr int D_OUT = 64;
static constexpr int ATTD  = 64;
static constexpr int NG    = 64;

// ---------------------------------------------------------------------------
// Tiny kernel: v_k = w_k @ a[:ATT], v_q = w_q @ a[ATT:], for both layers.
// idx < 128        -> vk1[idx]
// 128 <= idx < 256 -> vq1[idx-128]
// 256 <= idx < 320 -> vk2[idx-256]
// 320 <= idx < 384 -> vq2[idx-320]
// ---------------------------------------------------------------------------
__global__ void prep_att_vecs(const float* __restrict__ w_q1, const float* __restrict__ w_k1,
                              const float* __restrict__ w_att1,
                              const float* __restrict__ w_q2, const float* __restrict__ w_k2,
                              const float* __restrict__ w_att2,
                              float* __restrict__ small) {
    int idx = blockIdx.x * blockDim.x + threadIdx.x;
    if (idx >= 384) return;
    float acc = 0.f;
    if (idx < 128) {
        int d = idx;
        for (int a = 0; a < ATTD; ++a) acc += w_k1[d * ATTD + a] * w_att1[a];
        small[0 + d] = acc;
    } else if (idx < 256) {
        int d = idx - 128;
        for (int a = 0; a < ATTD; ++a) acc += w_q1[d * ATTD + a] * w_att1[ATTD + a];
        small[128 + d] = acc;
    } else if (idx < 320) {
        int d = idx - 256;
        for (int a = 0; a < ATTD; ++a) acc += w_k2[d * ATTD + a] * w_att2[a];
        small[256 + d] = acc;
    } else {
        int d = idx - 320;
        for (int a = 0; a < ATTD; ++a) acc += w_q2[d * ATTD + a] * w_att2[ATTD + a];
        small[320 + d] = acc;
    }
}

// ---------------------------------------------------------------------------
// Dual GEMM: Oa = X @ Wa, Ob = X @ Wb.  X: (M,128) fp32, W: (128,C), C in {64,128}.
// Tile: 64 rows x 64 cols per block, 256 threads, 4x4 microtile per thread.
// grid = (ceil(M/64), C/64, 2)
// ---------------------------------------------------------------------------
__global__ __launch_bounds__(256) void gemm_dual(
        const float* __restrict__ X, int M, int C,
        const float* __restrict__ Wa, const float* __restrict__ Wb,
        float* __restrict__ Oa, float* __restrict__ Ob) {
    constexpr int K = 128;
    __shared__ float xs[K][68];   // transposed tile: xs[k][m_local], pad to 68 (16B-aligned rows)

    const float* W = (blockIdx.z == 0) ? Wa : Wb;
    float* O       = (blockIdx.z == 0) ? Oa : Ob;

    const int r0 = blockIdx.x * 64;
    const int c0 = blockIdx.y * 64;
    const int t  = threadIdx.x;

    // Load X tile (64 rows x 128 cols) via float4, store transposed.
    for (int idx = t; idx < 64 * (K / 4); idx += 256) {
        int m  = idx / (K / 4);
        int kq = idx % (K / 4);
        int row = r0 + m;
        float4 v = make_float4(0.f, 0.f, 0.f, 0.f);
        if (row < M) v = *(const float4*)(X + (size_t)row * K + kq * 4);
        xs[kq * 4 + 0][m] = v.x;
        xs[kq * 4 + 1][m] = v.y;
        xs[kq * 4 + 2][m] = v.z;
        xs[kq * 4 + 3][m] = v.w;
    }
    __syncthreads();

    const int tr = t >> 4;   // 0..15 row-group
    const int tc = t & 15;   // 0..15 col-group
    const float* wcol = W + c0 + tc * 4;

    float acc[4][4] = {};
#pragma unroll 8
    for (int k = 0; k < K; ++k) {
        float4 xv = *(const float4*)&xs[k][tr * 4];
        float4 wv = *(const float4*)(wcol + (size_t)k * C);
        acc[0][0] = fmaf(xv.x, wv.x, acc[0][0]);
        acc[0][1] = fmaf(xv.x, wv.y, acc[0][1]);
        acc[0][2] = fmaf(xv.x, wv.z, acc[0][2]);
        acc[0][3] = fmaf(xv.x, wv.w, acc[0][3]);
        acc[1][0] = fmaf(xv.y, wv.x, acc[1][0]);
        acc[1][1] = fmaf(xv.y, wv.y, acc[1][1]);
        acc[1][2] = fmaf(xv.y, wv.z, acc[1][2]);
        acc[1][3] = fmaf(xv.y, wv.w, acc[1][3]);
        acc[2][0] = fmaf(xv.z, wv.x, acc[2][0]);
        acc[2][1] = fmaf(xv.z, wv.y, acc[2][1]);
        acc[2][2] = fmaf(xv.z, wv.z, acc[2][2]);
        acc[2][3] = fmaf(xv.z, wv.w, acc[2][3]);
        acc[3][0] = fmaf(xv.w, wv.x, acc[3][0]);
        acc[3][1] = fmaf(xv.w, wv.y, acc[3][1]);
        acc[3][2] = fmaf(xv.w, wv.z, acc[3][2]);
        acc[3][3] = fmaf(xv.w, wv.w, acc[3][3]);
    }

#pragma unroll
    for (int i = 0; i < 4; ++i) {
        int row = r0 + tr * 4 + i;
        if (row < M) {
            float4 o = make_float4(acc[i][0], acc[i][1], acc[i][2], acc[i][3]);
            *(float4*)(O + (size_t)row * C + c0 + tc * 4) = o;
        }
    }
}

// ---------------------------------------------------------------------------
// SpMM scatter: out[dst[e]] += ew[e] * feat[src[e]], feature dim D (64 or 128).
// D/4 threads per edge, float4 gather + 4 atomicAdds.
// ---------------------------------------------------------------------------
__global__ __launch_bounds__(256) void spmm_atomic(
        const int* __restrict__ src, const int* __restrict__ dst,
        const float* __restrict__ ew, const float* __restrict__ feat,
        float* __restrict__ out, int E, int D) {
    int tpe = D >> 2;
    int gt = blockIdx.x * blockDim.x + threadIdx.x;
    int e = gt / tpe;
    if (e >= E) return;
    int l = gt - e * tpe;
    int s = src[e];
    int d = dst[e];
    float w = ew[e];
    float4 v = *(const float4*)(feat + (size_t)s * D + l * 4);
    float* o = out + (size_t)d * D + l * 4;
    atomicAdd(o + 0, v.x * w);
    atomicAdd(o + 1, v.y * w);
    atomicAdd(o + 2, v.z * w);
    atomicAdd(o + 3, v.w * w);
}

// ---------------------------------------------------------------------------
// Attention combine: one 64-lane wave per node.
//   e0 = elu(self.vk + self.vq), e1 = elu(nb.vk + self.vq)
//   att = softmax([e0,e1]); h = att0*self + att1*nb + bias  (optional elu)
// ---------------------------------------------------------------------------
__global__ __launch_bounds__(256) void att_combine(
        const float* __restrict__ sf, const float* __restrict__ nf,
        const float* __restrict__ vk, const float* __restrict__ vq,
        const float* __restrict__ bias,
        float* __restrict__ hout, float* __restrict__ attout,
        int M, int D, int elu_out) {
    int wave = threadIdx.x >> 6;
    int lane = threadIdx.x & 63;
    int n = blockIdx.x * (blockDim.x >> 6) + wave;
    if (n >= M) return;

    int per = D >> 6;   // 2 for D=128, 1 for D=64
    float sk = 0.f, sq = 0.f, nk = 0.f;
    float svals[2], nvals[2];
#pragma unroll
    for (int i = 0; i < 2; ++i) {
        if (i < per) {
            int d = lane + i * 64;
            float s = sf[(size_t)n * D + d];
            float nn = nf[(size_t)n * D + d];
            svals[i] = s; nvals[i] = nn;
            float k = vk[d], q = vq[d];
            sk = fmaf(s, k, sk);
            sq = fmaf(s, q, sq);
            nk = fmaf(nn, k, nk);
        }
    }
#pragma unroll
    for (int off = 32; off; off >>= 1) {
        sk += __shfl_xor(sk, off);
        sq += __shfl_xor(sq, off);
        nk += __shfl_xor(nk, off);
    }
    float e0 = sk + sq;
    float e1 = nk + sq;
    e0 = e0 > 0.f ? e0 : expm1f(e0);
    e1 = e1 > 0.f ? e1 : expm1f(e1);
    float m = fmaxf(e0, e1);
    float a0 = expf(e0 - m);
    float a1 = expf(e1 - m);
    float inv = 1.f / (a0 + a1);
    a0 *= inv; a1 *= inv;

#pragma unroll
    for (int i = 0; i < 2; ++i) {
        if (i < per) {
            int d = lane + i * 64;
            float o = fmaf(a0, svals[i], fmaf(a1, nvals[i], bias[d]));
            if (elu_out) o = o > 0.f ? o : expm1f(o);
            hout[(size_t)n * D + d] = o;
        }
    }
    if (lane == 0) {
        attout[2 * (size_t)n + 0] = a0;
        attout[2 * (size_t)n + 1] = a1;
    }
}

// ---------------------------------------------------------------------------
// Segment-sum pooling over sorted graph_ids: LDS-accumulate then global atomics.
// 1024 nodes per block, D_OUT=64, NG=64.
// ---------------------------------------------------------------------------
__global__ __launch_bounds__(256) void pool_sum(
        const float* __restrict__ h, const int* __restrict__ gid,
        float* __restrict__ sums, float* __restrict__ cnt, int M) {
    __shared__ float ls[NG * D_OUT];
    __shared__ float lc[NG];
    for (int i = threadIdx.x; i < NG * D_OUT; i += 256) ls[i] = 0.f;
    if (threadIdx.x < NG) lc[threadIdx.x] = 0.f;
    __syncthreads();

    int d = threadIdx.x & 63;
    int nsub = threadIdx.x >> 6;   // 0..3
    int base = blockIdx.x * 1024;
#pragma unroll 4
    for (int i = 0; i < 256; ++i) {
        int n = base + i * 4 + nsub;
        if (n < M) {
            int g = gid[n];
            atomicAdd(&ls[g * D_OUT + d], h[(size_t)n * D_OUT + d]);
            if (d == 0) atomicAdd(&lc[g], 1.0f);
        }
    }
    __syncthreads();
    for (int i = threadIdx.x; i < NG * D_OUT; i += 256) {
        float v = ls[i];
        if (v != 0.f) atomicAdd(&sums[i], v);
    }
    if (threadIdx.x < NG) {
        float v = lc[threadIdx.x];
        if (v != 0.f) atomicAdd(&cnt[threadIdx.x], v);
    }
}

// ---------------------------------------------------------------------------
// Final: mean + 2-layer MLP -> graph_embd (NG x 1). One thread per graph.
// ---------------------------------------------------------------------------
__global__ void pool_mlp(const float* __restrict__ sums, const float* __restrict__ cnt,
                         const float* __restrict__ w1, const float* __restrict__ b1,
                         const float* __restrict__ w2, const float* __restrict__ b2,
                         float* __restrict__ out) {
    int g = threadIdx.x;
    if (g >= NG) return;
    float c = fmaxf(cnt[g], 1.0f);
    float inv = 1.0f / c;
    float hg[D_OUT];
#pragma unroll
    for (int d = 0; d < D_OUT; ++d) hg[d] = sums[g * D_OUT + d] * inv;
    float acc = b2[0];
    for (int j = 0; j < D_OUT / 2; ++j) {
        float hid = b1[j];
#pragma unroll 8
        for (int d = 0; d < D_OUT; ++d) hid = fmaf(hg[d], w1[d * (D_OUT / 2) + j], hid);
        hid = fmaxf(hid, 0.f);
        acc = fmaf(hid, w2[j], acc);
    }
    out[g] = acc;
}

// ---------------------------------------------------------------------------
extern "C" void kernel_launch(void* const* d_in, const int* in_sizes, int n_in,
                              void* d_out, int out_size, void* d_ws, size_t ws_size,
                              hipStream_t stream) {
    const float* x       = (const float*)d_in[0];
    const int*   esrc    = (const int*)  d_in[1];
    const int*   edst    = (const int*)  d_in[2];
    const float* ew      = (const float*)d_in[3];
    const int*   gid     = (const int*)  d_in[4];
    const float* w_self1 = (const float*)d_in[5];
    const float* w_rel1  = (const float*)d_in[6];
    const float* bias1   = (const float*)d_in[7];
    const float* w_q1    = (const float*)d_in[8];
    const float* w_k1    = (const float*)d_in[9];
    const float* w_att1  = (const float*)d_in[10];
    const float* w_self2 = (const float*)d_in[11];
    const float* w_rel2  = (const float*)d_in[12];
    const float* bias2   = (const float*)d_in[13];
    const float* w_q2    = (const float*)d_in[14];
    const float* w_k2    = (const float*)d_in[15];
    const float* w_att2  = (const float*)d_in[16];
    const float* mlp_w1  = (const float*)d_in[17];
    const float* mlp_b1  = (const float*)d_in[18];
    const float* mlp_w2  = (const float*)d_in[19];
    const float* mlp_b2  = (const float*)d_in[20];

    const int N = in_sizes[0] / D_IN;
    const int E = in_sizes[1];

    float* out = (float*)d_out;
    float* out_embd = out;                       // NG floats
    float* out_att1 = out + NG;                  // N*2
    float* out_att2 = out + NG + 2 * (size_t)N;  // N*2

    // Workspace layout (floats)
    float* ws = (float*)d_ws;
    size_t bigN = (size_t)N * D_HID;   // N*128
    float* bufA = ws;                  // selfft1 -> (selfft2, relft2/h2)
    float* bufB = ws + bigN;           // relft1 -> h1
    float* bufC = ws + 2 * bigN;       // nbft1  -> nbft2
    float* small = ws + 3 * bigN;      // vk1(128) vq1(128) vk2(64) vq2(64) sums(4096) cnt(64)
    float* vk1 = small + 0;
    float* vq1 = small + 128;
    float* vk2 = small + 256;
    float* vq2 = small + 320;
    float* sums = small + 384;
    float* cnt  = small + 384 + NG * D_OUT;

    float* selfft1 = bufA;
    float* relft1  = bufB;
    float* nbft1   = bufC;
    float* h1      = bufB;                   // overwrite relft1 after spmm1
    float* selfft2 = bufA;                   // N*64
    float* relft2  = bufA + (size_t)N * D_OUT;
    float* nbft2   = bufC;                   // N*64
    float* h2      = bufA + (size_t)N * D_OUT;  // overwrite relft2 after spmm2

    // Zero accumulators
    hipMemsetAsync(nbft1, 0, bigN * sizeof(float), stream);
    hipMemsetAsync(sums, 0, (NG * D_OUT + NG) * sizeof(float), stream);

    prep_att_vecs<<<2, 256, 0, stream>>>(w_q1, w_k1, w_att1, w_q2, w_k2, w_att2, small);

    // ---- Layer 1 ----
    {
        dim3 grid((N + 63) / 64, D_HID / 64, 2);
        gemm_dual<<<grid, 256, 0, stream>>>(x, N, D_HID, w_self1, w_rel1, selfft1, relft1);
    }
    {
        int tpe = D_HID / 4;
        long long tot = (long long)E * tpe;
        int blocks = (int)((tot + 255) / 256);
        spmm_atomic<<<blocks, 256, 0, stream>>>(esrc, edst, ew, relft1, nbft1, E, D_HID);
    }
    att_combine<<<(N + 3) / 4, 256, 0, stream>>>(selfft1, nbft1, vk1, vq1, bias1,
                                                 h1, out_att1, N, D_HID, 1);

    // Zero nbft2 (bufC reuse) after layer-1 spmm consumed bufC
    hipMemsetAsync(nbft2, 0, (size_t)N * D_OUT * sizeof(float), stream);

    // ---- Layer 2 ----
    {
        dim3 grid((N + 63) / 64, D_OUT / 64, 2);
        gemm_dual<<<grid, 256, 0, stream>>>(h1, N, D_OUT, w_self2, w_rel2, selfft2, relft2);
    }
    {
        int tpe = D_OUT / 4;
        long long tot = (long long)E * tpe;
        int blocks = (int)((tot + 255) / 256);
        spmm_atomic<<<blocks, 256, 0, stream>>>(esrc, edst, ew, relft2, nbft2, E, D_OUT);
    }
    att_combine<<<(N + 3) / 4, 256, 0, stream>>>(selfft2, nbft2, vk2, vq2, bias2,
                                                 h2, out_att2, N, D_OUT, 0);

    // ---- Pool + MLP ----
    pool_sum<<<(N + 1023) / 1024, 256, 0, stream>>>(h2, gid, sums, cnt, N);
    pool_mlp<<<1, 64, 0, stream>>>(sums, cnt, mlp_w1, mlp_b1, mlp_w2, mlp_b2, out_embd);
}

// Round 2
// 835.695 us; speedup vs baseline: 5.2835x; 5.2835x over previous
//
#include <hip/hip_runtime.h>
#include <hip/hip_bf16.h>
#include <cstdint>
#include <cstddef>

// Problem constants (match reference)
static constexpr int D_IN  = 128;
static constexpr int D_HID = 128;
static constexpr int D_OUT = 64;
static constexpr int ATTD  = 64;
static constexpr int NG    = 64;
static constexpr int SCAN_CHUNK = 2048;   // 256 threads * 8

// ---------------------------------------------------------------------------
// Tiny kernel: v_k = w_k @ a[:ATT], v_q = w_q @ a[ATT:], for both layers.
// ---------------------------------------------------------------------------
__global__ void prep_att_vecs(const float* __restrict__ w_q1, const float* __restrict__ w_k1,
                              const float* __restrict__ w_att1,
                              const float* __restrict__ w_q2, const float* __restrict__ w_k2,
                              const float* __restrict__ w_att2,
                              float* __restrict__ small) {
    int idx = blockIdx.x * blockDim.x + threadIdx.x;
    if (idx >= 384) return;
    float acc = 0.f;
    if (idx < 128) {
        int d = idx;
        for (int a = 0; a < ATTD; ++a) acc += w_k1[d * ATTD + a] * w_att1[a];
        small[0 + d] = acc;
    } else if (idx < 256) {
        int d = idx - 128;
        for (int a = 0; a < ATTD; ++a) acc += w_q1[d * ATTD + a] * w_att1[ATTD + a];
        small[128 + d] = acc;
    } else if (idx < 320) {
        int d = idx - 256;
        for (int a = 0; a < ATTD; ++a) acc += w_k2[d * ATTD + a] * w_att2[a];
        small[256 + d] = acc;
    } else {
        int d = idx - 320;
        for (int a = 0; a < ATTD; ++a) acc += w_q2[d * ATTD + a] * w_att2[ATTD + a];
        small[320 + d] = acc;
    }
}

// ---------------------------------------------------------------------------
// Dual GEMM: Oa = X @ Wa, Ob = X @ Wb.  X: (M,128) fp32, W: (128,C), C in {64,128}.
// ---------------------------------------------------------------------------
__global__ __launch_bounds__(256) void gemm_dual(
        const float* __restrict__ X, int M, int C,
        const float* __restrict__ Wa, const float* __restrict__ Wb,
        float* __restrict__ Oa, float* __restrict__ Ob) {
    constexpr int K = 128;
    __shared__ float xs[K][68];

    const float* W = (blockIdx.z == 0) ? Wa : Wb;
    float* O       = (blockIdx.z == 0) ? Oa : Ob;

    const int r0 = blockIdx.x * 64;
    const int c0 = blockIdx.y * 64;
    const int t  = threadIdx.x;

    for (int idx = t; idx < 64 * (K / 4); idx += 256) {
        int m  = idx / (K / 4);
        int kq = idx % (K / 4);
        int row = r0 + m;
        float4 v = make_float4(0.f, 0.f, 0.f, 0.f);
        if (row < M) v = *(const float4*)(X + (size_t)row * K + kq * 4);
        xs[kq * 4 + 0][m] = v.x;
        xs[kq * 4 + 1][m] = v.y;
        xs[kq * 4 + 2][m] = v.z;
        xs[kq * 4 + 3][m] = v.w;
    }
    __syncthreads();

    const int tr = t >> 4;
    const int tc = t & 15;
    const float* wcol = W + c0 + tc * 4;

    float acc[4][4] = {};
#pragma unroll 8
    for (int k = 0; k < K; ++k) {
        float4 xv = *(const float4*)&xs[k][tr * 4];
        float4 wv = *(const float4*)(wcol + (size_t)k * C);
        acc[0][0] = fmaf(xv.x, wv.x, acc[0][0]);
        acc[0][1] = fmaf(xv.x, wv.y, acc[0][1]);
        acc[0][2] = fmaf(xv.x, wv.z, acc[0][2]);
        acc[0][3] = fmaf(xv.x, wv.w, acc[0][3]);
        acc[1][0] = fmaf(xv.y, wv.x, acc[1][0]);
        acc[1][1] = fmaf(xv.y, wv.y, acc[1][1]);
        acc[1][2] = fmaf(xv.y, wv.z, acc[1][2]);
        acc[1][3] = fmaf(xv.y, wv.w, acc[1][3]);
        acc[2][0] = fmaf(xv.z, wv.x, acc[2][0]);
        acc[2][1] = fmaf(xv.z, wv.y, acc[2][1]);
        acc[2][2] = fmaf(xv.z, wv.z, acc[2][2]);
        acc[2][3] = fmaf(xv.z, wv.w, acc[2][3]);
        acc[3][0] = fmaf(xv.w, wv.x, acc[3][0]);
        acc[3][1] = fmaf(xv.w, wv.y, acc[3][1]);
        acc[3][2] = fmaf(xv.w, wv.z, acc[3][2]);
        acc[3][3] = fmaf(xv.w, wv.w, acc[3][3]);
    }

#pragma unroll
    for (int i = 0; i < 4; ++i) {
        int row = r0 + tr * 4 + i;
        if (row < M) {
            float4 o = make_float4(acc[i][0], acc[i][1], acc[i][2], acc[i][3]);
            *(float4*)(O + (size_t)row * C + c0 + tc * 4) = o;
        }
    }
}

// ---------------------------------------------------------------------------
// CSR build: histogram -> hierarchical exclusive scan -> counting scatter.
// ---------------------------------------------------------------------------
__global__ __launch_bounds__(256) void k_hist(const int* __restrict__ dst, int E,
                                              int* __restrict__ cnt) {
    int i = blockIdx.x * blockDim.x + threadIdx.x;
    if (i < E) atomicAdd(&cnt[dst[i]], 1);
}

__global__ __launch_bounds__(256) void k_chunk_sum(const int* __restrict__ cnt, int n,
                                                   int* __restrict__ psum) {
    __shared__ int red[4];
    int base = blockIdx.x * SCAN_CHUNK;
    int t = threadIdx.x;
    int s = 0;
#pragma unroll
    for (int i = 0; i < 8; ++i) {
        int idx = base + t * 8 + i;
        if (idx < n) s += cnt[idx];
    }
#pragma unroll
    for (int off = 32; off; off >>= 1) s += __shfl_down(s, off);
    if ((t & 63) == 0) red[t >> 6] = s;
    __syncthreads();
    if (t == 0) psum[blockIdx.x] = red[0] + red[1] + red[2] + red[3];
}

// single block, 64 threads: exclusive scan of psum[0..nb), also set rowptr[n]=E
__global__ void k_scan_psum(int* __restrict__ psum, int nb,
                            int* __restrict__ rowptr, int n, int E) {
    int t = threadIdx.x;
    int orig = (t < nb) ? psum[t] : 0;
    int v = orig;
#pragma unroll
    for (int off = 1; off < 64; off <<= 1) {
        int u = __shfl_up(v, off);
        if (t >= off) v += u;
    }
    if (t < nb) psum[t] = v - orig;   // exclusive
    if (t == 0) rowptr[n] = E;
}

__global__ __launch_bounds__(256) void k_chunk_scan(const int* __restrict__ cnt, int n,
        const int* __restrict__ psum, int* __restrict__ rowptr, int* __restrict__ wofs) {
    __shared__ int wsum[4];
    int base = blockIdx.x * SCAN_CHUNK;
    int t = threadIdx.x;
    int vals[8];
    int s = 0;
#pragma unroll
    for (int i = 0; i < 8; ++i) {
        int idx = base + t * 8 + i;
        int c = (idx < n) ? cnt[idx] : 0;
        vals[i] = s;       // exclusive within thread
        s += c;
    }
    int lane = t & 63, w = t >> 6;
    int incl = s;
#pragma unroll
    for (int off = 1; off < 64; off <<= 1) {
        int u = __shfl_up(incl, off);
        if (lane >= off) incl += u;
    }
    if (lane == 63) wsum[w] = incl;
    __syncthreads();
    int wbase = 0;
#pragma unroll
    for (int i = 0; i < 4; ++i) if (i < w) wbase += wsum[i];
    int texcl = wbase + incl - s;   // exclusive prefix of this thread within block
    int off0 = psum[blockIdx.x] + texcl;
#pragma unroll
    for (int i = 0; i < 8; ++i) {
        int idx = base + t * 8 + i;
        if (idx < n) {
            int r = off0 + vals[i];
            rowptr[idx] = r;
            wofs[idx]   = r;
        }
    }
}

__global__ __launch_bounds__(256) void k_scatter(const int* __restrict__ src,
        const int* __restrict__ dst, const float* __restrict__ ew, int E,
        int* __restrict__ wofs, float2* __restrict__ sorted) {
    int i = blockIdx.x * blockDim.x + threadIdx.x;
    if (i < E) {
        int d = dst[i];
        int pos = atomicAdd(&wofs[d], 1);
        sorted[pos] = make_float2(__int_as_float(src[i]), ew[i]);
    }
}

// ---------------------------------------------------------------------------
// Fused gather-SpMM + attention combine. One 64-lane wave per node.
// PER = D/64 (2 for layer1 D=128, 1 for layer2 D=64).
// hout may alias selfft (each wave reads/writes only its own row).
// ---------------------------------------------------------------------------
template <int PER>
__global__ __launch_bounds__(256) void fused_spmm_att(
        const float* __restrict__ selfft, const float* __restrict__ relft,
        const int* __restrict__ rowptr, const float2* __restrict__ sorted,
        const float* __restrict__ vk, const float* __restrict__ vq,
        const float* __restrict__ bias,
        float* __restrict__ hout, float* __restrict__ attout,
        int M, int elu_out) {
    int wave = threadIdx.x >> 6;
    int lane = threadIdx.x & 63;
    int n = blockIdx.x * 4 + wave;
    if (n >= M) return;

    float sv[PER], nb[PER];
    if (PER == 2) {
        float2 s2 = ((const float2*)selfft)[(size_t)n * 64 + lane];
        sv[0] = s2.x; sv[1] = s2.y;
        nb[0] = 0.f;  nb[1] = 0.f;
    } else {
        sv[0] = selfft[(size_t)n * 64 + lane];
        nb[0] = 0.f;
    }

    int beg = rowptr[n], end = rowptr[n + 1];
    int e = beg;
    if (e < end) {
        float2 sw = sorted[e];
        while (++e < end) {
            float2 swn = sorted[e];            // prefetch next edge meta
            int s = __float_as_int(sw.x);
            float w = sw.y;
            if (PER == 2) {
                float2 v = ((const float2*)relft)[(size_t)s * 64 + lane];
                nb[0] = fmaf(w, v.x, nb[0]);
                nb[1] = fmaf(w, v.y, nb[1]);
            } else {
                nb[0] = fmaf(w, relft[(size_t)s * 64 + lane], nb[0]);
            }
            sw = swn;
        }
        int s = __float_as_int(sw.x);
        float w = sw.y;
        if (PER == 2) {
            float2 v = ((const float2*)relft)[(size_t)s * 64 + lane];
            nb[0] = fmaf(w, v.x, nb[0]);
            nb[1] = fmaf(w, v.y, nb[1]);
        } else {
            nb[0] = fmaf(w, relft[(size_t)s * 64 + lane], nb[0]);
        }
    }

    // attention logits
    float vkl[PER], vql[PER], bl[PER];
    if (PER == 2) {
        float2 k2 = ((const float2*)vk)[lane];
        float2 q2 = ((const float2*)vq)[lane];
        float2 b2 = ((const float2*)bias)[lane];
        vkl[0] = k2.x; vkl[1] = k2.y;
        vql[0] = q2.x; vql[1] = q2.y;
        bl[0]  = b2.x; bl[1]  = b2.y;
    } else {
        vkl[0] = vk[lane]; vql[0] = vq[lane]; bl[0] = bias[lane];
    }
    float sk = 0.f, sq = 0.f, nk = 0.f;
#pragma unroll
    for (int i = 0; i < PER; ++i) {
        sk = fmaf(sv[i], vkl[i], sk);
        sq = fmaf(sv[i], vql[i], sq);
        nk = fmaf(nb[i], vkl[i], nk);
    }
#pragma unroll
    for (int off = 32; off; off >>= 1) {
        sk += __shfl_xor(sk, off);
        sq += __shfl_xor(sq, off);
        nk += __shfl_xor(nk, off);
    }
    float e0 = sk + sq;
    float e1 = nk + sq;
    e0 = e0 > 0.f ? e0 : expm1f(e0);
    e1 = e1 > 0.f ? e1 : expm1f(e1);
    float m = fmaxf(e0, e1);
    float a0 = expf(e0 - m);
    float a1 = expf(e1 - m);
    float inv = 1.f / (a0 + a1);
    a0 *= inv; a1 *= inv;

    if (PER == 2) {
        float2 o;
        o.x = fmaf(a0, sv[0], fmaf(a1, nb[0], bl[0]));
        o.y = fmaf(a0, sv[1], fmaf(a1, nb[1], bl[1]));
        if (elu_out) {
            o.x = o.x > 0.f ? o.x : expm1f(o.x);
            o.y = o.y > 0.f ? o.y : expm1f(o.y);
        }
        ((float2*)hout)[(size_t)n * 64 + lane] = o;
    } else {
        float o = fmaf(a0, sv[0], fmaf(a1, nb[0], bl[0]));
        if (elu_out) o = o > 0.f ? o : expm1f(o);
        hout[(size_t)n * 64 + lane] = o;
    }
    if (lane == 0) {
        attout[2 * (size_t)n + 0] = a0;
        attout[2 * (size_t)n + 1] = a1;
    }
}

// ---------------------------------------------------------------------------
// Segment-sum pooling over graph_ids: LDS-accumulate then global atomics.
// ---------------------------------------------------------------------------
__global__ __launch_bounds__(256) void pool_sum(
        const float* __restrict__ h, const int* __restrict__ gid,
        float* __restrict__ sums, float* __restrict__ cnt, int M) {
    __shared__ float ls[NG * D_OUT];
    __shared__ float lc[NG];
    for (int i = threadIdx.x; i < NG * D_OUT; i += 256) ls[i] = 0.f;
    if (threadIdx.x < NG) lc[threadIdx.x] = 0.f;
    __syncthreads();

    int d = threadIdx.x & 63;
    int nsub = threadIdx.x >> 6;
    int base = blockIdx.x * 1024;
#pragma unroll 4
    for (int i = 0; i < 256; ++i) {
        int n = base + i * 4 + nsub;
        if (n < M) {
            int g = gid[n];
            atomicAdd(&ls[g * D_OUT + d], h[(size_t)n * D_OUT + d]);
            if (d == 0) atomicAdd(&lc[g], 1.0f);
        }
    }
    __syncthreads();
    for (int i = threadIdx.x; i < NG * D_OUT; i += 256) {
        float v = ls[i];
        if (v != 0.f) atomicAdd(&sums[i], v);
    }
    if (threadIdx.x < NG) {
        float v = lc[threadIdx.x];
        if (v != 0.f) atomicAdd(&cnt[threadIdx.x], v);
    }
}

__global__ void pool_mlp(const float* __restrict__ sums, const float* __restrict__ cnt,
                         const float* __restrict__ w1, const float* __restrict__ b1,
                         const float* __restrict__ w2, const float* __restrict__ b2,
                         float* __restrict__ out) {
    int g = threadIdx.x;
    if (g >= NG) return;
    float c = fmaxf(cnt[g], 1.0f);
    float inv = 1.0f / c;
    float hg[D_OUT];
#pragma unroll
    for (int d = 0; d < D_OUT; ++d) hg[d] = sums[g * D_OUT + d] * inv;
    float acc = b2[0];
    for (int j = 0; j < D_OUT / 2; ++j) {
        float hid = b1[j];
#pragma unroll 8
        for (int d = 0; d < D_OUT; ++d) hid = fmaf(hg[d], w1[d * (D_OUT / 2) + j], hid);
        hid = fmaxf(hid, 0.f);
        acc = fmaf(hid, w2[j], acc);
    }
    out[g] = acc;
}

// ---------------------------------------------------------------------------
extern "C" void kernel_launch(void* const* d_in, const int* in_sizes, int n_in,
                              void* d_out, int out_size, void* d_ws, size_t ws_size,
                              hipStream_t stream) {
    const float* x       = (const float*)d_in[0];
    const int*   esrc    = (const int*)  d_in[1];
    const int*   edst    = (const int*)  d_in[2];
    const float* ew      = (const float*)d_in[3];
    const int*   gid     = (const int*)  d_in[4];
    const float* w_self1 = (const float*)d_in[5];
    const float* w_rel1  = (const float*)d_in[6];
    const float* bias1   = (const float*)d_in[7];
    const float* w_q1    = (const float*)d_in[8];
    const float* w_k1    = (const float*)d_in[9];
    const float* w_att1  = (const float*)d_in[10];
    const float* w_self2 = (const float*)d_in[11];
    const float* w_rel2  = (const float*)d_in[12];
    const float* bias2   = (const float*)d_in[13];
    const float* w_q2    = (const float*)d_in[14];
    const float* w_k2    = (const float*)d_in[15];
    const float* w_att2  = (const float*)d_in[16];
    const float* mlp_w1  = (const float*)d_in[17];
    const float* mlp_b1  = (const float*)d_in[18];
    const float* mlp_w2  = (const float*)d_in[19];
    const float* mlp_b2  = (const float*)d_in[20];

    const int N = in_sizes[0] / D_IN;
    const int E = in_sizes[1];

    float* out = (float*)d_out;
    float* out_embd = out;
    float* out_att1 = out + NG;
    float* out_att2 = out + NG + 2 * (size_t)N;

    // ---- Workspace layout (floats) ----
    float* ws = (float*)d_ws;
    size_t bigN = (size_t)N * D_HID;          // N*128
    float* bufA = ws;                          // selfft1 / h1 (in-place)
    float* bufB = ws + bigN;                   // relft1 -> (selfft2, relft2)
    // int region
    int* ip      = (int*)(ws + 2 * bigN);
    int* hcnt    = ip;                         // N
    int* rowptr  = ip + N;                     // N+1
    int* wofs    = ip + 2 * N + 1;             // N
    int* psum    = ip + 3 * N + 1;             // 64
    size_t int_end = 2 * bigN + 3 * (size_t)N + 1 + 64;
    int_end = (int_end + 1) & ~(size_t)1;      // 8B align for float2
    float2* sorted = (float2*)(ws + int_end);  // E float2
    float* small = ws + int_end + 2 * (size_t)E;
    float* vk1 = small + 0;
    float* vq1 = small + 128;
    float* vk2 = small + 256;
    float* vq2 = small + 320;
    float* sums = small + 384;
    float* cnt  = small + 384 + NG * D_OUT;

    float* selfft1 = bufA;
    float* relft1  = bufB;
    float* h1      = bufA;                     // in-place with selfft1
    float* selfft2 = bufB;                     // N*64 (relft1 dead by then)
    float* relft2  = bufB + (size_t)N * D_OUT;
    float* h2      = bufB;                     // in-place with selfft2

    // ---- zero accumulators ----
    hipMemsetAsync(hcnt, 0, (size_t)N * sizeof(int), stream);
    hipMemsetAsync(sums, 0, (NG * D_OUT + NG) * sizeof(float), stream);

    prep_att_vecs<<<2, 256, 0, stream>>>(w_q1, w_k1, w_att1, w_q2, w_k2, w_att2, small);

    // ---- CSR build (shared by both layers) ----
    int nchunks = (N + SCAN_CHUNK - 1) / SCAN_CHUNK;   // <= 64
    k_hist<<<(E + 255) / 256, 256, 0, stream>>>(edst, E, hcnt);
    k_chunk_sum<<<nchunks, 256, 0, stream>>>(hcnt, N, psum);
    k_scan_psum<<<1, 64, 0, stream>>>(psum, nchunks, rowptr, N, E);
    k_chunk_scan<<<nchunks, 256, 0, stream>>>(hcnt, N, psum, rowptr, wofs);
    k_scatter<<<(E + 255) / 256, 256, 0, stream>>>(esrc, edst, ew, E, wofs, sorted);

    // ---- Layer 1 ----
    {
        dim3 grid((N + 63) / 64, D_HID / 64, 2);
        gemm_dual<<<grid, 256, 0, stream>>>(x, N, D_HID, w_self1, w_rel1, selfft1, relft1);
    }
    fused_spmm_att<2><<<(N + 3) / 4, 256, 0, stream>>>(
        selfft1, relft1, rowptr, sorted, vk1, vq1, bias1, h1, out_att1, N, 1);

    // ---- Layer 2 ----
    {
        dim3 grid((N + 63) / 64, D_OUT / 64, 2);
        gemm_dual<<<grid, 256, 0, stream>>>(h1, N, D_OUT, w_self2, w_rel2, selfft2, relft2);
    }
    fused_spmm_att<1><<<(N + 3) / 4, 256, 0, stream>>>(
        selfft2, relft2, rowptr, sorted, vk2, vq2, bias2, h2, out_att2, N, 0);

    // ---- Pool + MLP ----
    pool_sum<<<(N + 1023) / 1024, 256, 0, stream>>>(h2, gid, sums, cnt, N);
    pool_mlp<<<1, 64, 0, stream>>>(sums, cnt, mlp_w1, mlp_b1, mlp_w2, mlp_b2, out_embd);
}

// Round 3
// 690.175 us; speedup vs baseline: 6.3975x; 1.2108x over previous
//
#include <hip/hip_runtime.h>
#include <hip/hip_bf16.h>
#include <cstdint>
#include <cstddef>

static constexpr int D_IN  = 128;
static constexpr int D_HID = 128;
static constexpr int D_OUT = 64;
static constexpr int ATTD  = 64;
static constexpr int NG    = 64;
static constexpr int SCAN_CHUNK = 2048;   // 256 threads * 8

typedef __attribute__((ext_vector_type(8))) short s16x8;
typedef __attribute__((ext_vector_type(4))) float f32x4;
typedef unsigned short ushort_t;
typedef unsigned int uint_t;

__device__ __forceinline__ unsigned short bf_bits(float f) {
    union { __hip_bfloat16 h; unsigned short u; } cv;
    cv.h = __float2bfloat16(f);
    return cv.u;
}
__device__ __forceinline__ float bf_lo(uint_t v) { return __uint_as_float(v << 16); }
__device__ __forceinline__ float bf_hi(uint_t v) { return __uint_as_float(v & 0xffff0000u); }
__device__ __forceinline__ float bf_one(unsigned short u) { return __uint_as_float(((uint_t)u) << 16); }

// ---------------------------------------------------------------------------
// Weight prep: WT[c*128 + k] = bf16(W[k*C + c]) for the 4 GEMM weight matrices.
// Layout in wt: self1 [0,16384) rel1 [16384,32768) self2 [32768,40960) rel2 [40960,49152)
// ---------------------------------------------------------------------------
__global__ void prep_wt(const float* __restrict__ w_self1, const float* __restrict__ w_rel1,
                        const float* __restrict__ w_self2, const float* __restrict__ w_rel2,
                        ushort_t* __restrict__ wt) {
    int idx = blockIdx.x * 256 + threadIdx.x;
    if (idx >= 49152) return;
    const float* src; int base, Cc;
    if (idx < 16384)      { src = w_self1; base = 0;     Cc = 128; }
    else if (idx < 32768) { src = w_rel1;  base = 16384; Cc = 128; }
    else if (idx < 40960) { src = w_self2; base = 32768; Cc = 64;  }
    else                  { src = w_rel2;  base = 40960; Cc = 64;  }
    int l = idx - base;
    int c = l >> 7;        // / 128 (K = 128 for all)
    int k = l & 127;
    wt[base + l] = bf_bits(src[k * Cc + c]);
}

// ---------------------------------------------------------------------------
// v_k = w_k @ a[:ATT], v_q = w_q @ a[ATT:] for both layers (fp32).
// ---------------------------------------------------------------------------
__global__ void prep_att_vecs(const float* __restrict__ w_q1, const float* __restrict__ w_k1,
                              const float* __restrict__ w_att1,
                              const float* __restrict__ w_q2, const float* __restrict__ w_k2,
                              const float* __restrict__ w_att2,
                              float* __restrict__ small) {
    int idx = blockIdx.x * blockDim.x + threadIdx.x;
    if (idx >= 384) return;
    float acc = 0.f;
    if (idx < 128) {
        int d = idx;
        for (int a = 0; a < ATTD; ++a) acc += w_k1[d * ATTD + a] * w_att1[a];
        small[0 + d] = acc;
    } else if (idx < 256) {
        int d = idx - 128;
        for (int a = 0; a < ATTD; ++a) acc += w_q1[d * ATTD + a] * w_att1[ATTD + a];
        small[128 + d] = acc;
    } else if (idx < 320) {
        int d = idx - 256;
        for (int a = 0; a < ATTD; ++a) acc += w_k2[d * ATTD + a] * w_att2[a];
        small[256 + d] = acc;
    } else {
        int d = idx - 320;
        for (int a = 0; a < ATTD; ++a) acc += w_q2[d * ATTD + a] * w_att2[ATTD + a];
        small[320 + d] = acc;
    }
}

// ---------------------------------------------------------------------------
// MFMA bf16 dual GEMM: z=0: Oa = A @ Wa (fp32 or bf16 out per OA_BF),
//                      z=1: Ob = A @ Wb (always bf16 out).
// A: (M,128) fp32 (A32) or bf16. WT buffers are transposed bf16 [c][k], K=128.
// Block: 256 thr = 4 waves; block tile 64 rows x C cols; wave tile 16 x C.
// MFMA 16x16x32_bf16: A frag row=lane&15, k=(lane>>4)*8+e; B frag col=lane&15,
// same k; D col=lane&15, row=(lane>>4)*4+reg.
// ---------------------------------------------------------------------------
template <int C, bool A32, bool OA_BF>
__global__ __launch_bounds__(256) void gemm_mfma(
        const void* __restrict__ A, int M,
        const ushort_t* __restrict__ WTa, const ushort_t* __restrict__ WTb,
        void* __restrict__ Oa, ushort_t* __restrict__ Ob) {
    constexpr int K = 128;
    constexpr int RS = K + 8;               // padded LDS row (bf16 elems)
    __shared__ ushort_t wt[C * RS];

    const ushort_t* WT = blockIdx.z ? WTb : WTa;
    for (int idx = threadIdx.x; idx < C * (K / 8); idx += 256) {
        int c  = idx / (K / 8);
        int kc = idx % (K / 8);
        *(uint4*)&wt[c * RS + kc * 8] = *(const uint4*)&WT[c * K + kc * 8];
    }
    __syncthreads();

    const int w    = threadIdx.x >> 6;
    const int lane = threadIdx.x & 63;
    const int row  = blockIdx.x * 64 + w * 16 + (lane & 15);
    const int rowc = row < M ? row : (M - 1);
    const int kb   = (lane >> 4) * 8;

    s16x8 afr[4];
    if (A32) {
        const float* Af = (const float*)A + (size_t)rowc * K + kb;
#pragma unroll
        for (int ks = 0; ks < 4; ++ks) {
            float4 f0 = *(const float4*)(Af + ks * 32);
            float4 f1 = *(const float4*)(Af + ks * 32 + 4);
            s16x8 a;
            a[0] = (short)bf_bits(f0.x); a[1] = (short)bf_bits(f0.y);
            a[2] = (short)bf_bits(f0.z); a[3] = (short)bf_bits(f0.w);
            a[4] = (short)bf_bits(f1.x); a[5] = (short)bf_bits(f1.y);
            a[6] = (short)bf_bits(f1.z); a[7] = (short)bf_bits(f1.w);
            afr[ks] = a;
        }
    } else {
        const ushort_t* Ab = (const ushort_t*)A + (size_t)rowc * K + kb;
#pragma unroll
        for (int ks = 0; ks < 4; ++ks) afr[ks] = *(const s16x8*)(Ab + ks * 32);
    }

    const int colc = lane & 15;
    const int r0   = blockIdx.x * 64 + w * 16 + (lane >> 4) * 4;

#pragma unroll
    for (int ct = 0; ct < C / 16; ++ct) {
        f32x4 acc = {0.f, 0.f, 0.f, 0.f};
        const int colb = ct * 16 + colc;
#pragma unroll
        for (int ks = 0; ks < 4; ++ks) {
            s16x8 b = *(const s16x8*)&wt[colb * RS + ks * 32 + kb];
            acc = __builtin_amdgcn_mfma_f32_16x16x32_bf16(afr[ks], b, acc, 0, 0, 0);
        }
        if (blockIdx.z == 0) {
            if (OA_BF) {
                ushort_t* O = (ushort_t*)Oa;
#pragma unroll
                for (int j = 0; j < 4; ++j)
                    if (r0 + j < M) O[(size_t)(r0 + j) * C + colb] = bf_bits(acc[j]);
            } else {
                float* O = (float*)Oa;
#pragma unroll
                for (int j = 0; j < 4; ++j)
                    if (r0 + j < M) O[(size_t)(r0 + j) * C + colb] = acc[j];
            }
        } else {
#pragma unroll
            for (int j = 0; j < 4; ++j)
                if (r0 + j < M) Ob[(size_t)(r0 + j) * C + colb] = bf_bits(acc[j]);
        }
    }
}

// ---------------------------------------------------------------------------
// CSR build: histogram -> hierarchical exclusive scan -> counting scatter.
// After k_scatter, rowptr[n] holds END of segment n (begin = rowptr[n-1] or 0).
// ---------------------------------------------------------------------------
__global__ __launch_bounds__(256) void k_hist(const int* __restrict__ dst, int E,
                                              int* __restrict__ cnt) {
    int i = blockIdx.x * blockDim.x + threadIdx.x;
    if (i < E) atomicAdd(&cnt[dst[i]], 1);
}

__global__ __launch_bounds__(256) void k_chunk_sum(const int* __restrict__ cnt, int n,
                                                   int* __restrict__ psum) {
    __shared__ int red[4];
    int base = blockIdx.x * SCAN_CHUNK;
    int t = threadIdx.x;
    int s = 0;
#pragma unroll
    for (int i = 0; i < 8; ++i) {
        int idx = base + t * 8 + i;
        if (idx < n) s += cnt[idx];
    }
#pragma unroll
    for (int off = 32; off; off >>= 1) s += __shfl_down(s, off);
    if ((t & 63) == 0) red[t >> 6] = s;
    __syncthreads();
    if (t == 0) psum[blockIdx.x] = red[0] + red[1] + red[2] + red[3];
}

__global__ void k_scan_psum(int* __restrict__ psum, int nb) {
    int t = threadIdx.x;
    int orig = (t < nb) ? psum[t] : 0;
    int v = orig;
#pragma unroll
    for (int off = 1; off < 64; off <<= 1) {
        int u = __shfl_up(v, off);
        if (t >= off) v += u;
    }
    if (t < nb) psum[t] = v - orig;   // exclusive
}

__global__ __launch_bounds__(256) void k_chunk_scan(const int* __restrict__ cnt, int n,
        const int* __restrict__ psum, int* __restrict__ rowptr) {
    __shared__ int wsum[4];
    int base = blockIdx.x * SCAN_CHUNK;
    int t = threadIdx.x;
    int vals[8];
    int s = 0;
#pragma unroll
    for (int i = 0; i < 8; ++i) {
        int idx = base + t * 8 + i;
        int c = (idx < n) ? cnt[idx] : 0;
        vals[i] = s;
        s += c;
    }
    int lane = t & 63, w = t >> 6;
    int incl = s;
#pragma unroll
    for (int off = 1; off < 64; off <<= 1) {
        int u = __shfl_up(incl, off);
        if (lane >= off) incl += u;
    }
    if (lane == 63) wsum[w] = incl;
    __syncthreads();
    int wbase = 0;
#pragma unroll
    for (int i = 0; i < 4; ++i) if (i < w) wbase += wsum[i];
    int texcl = wbase + incl - s;
    int off0 = psum[blockIdx.x] + texcl;
#pragma unroll
    for (int i = 0; i < 8; ++i) {
        int idx = base + t * 8 + i;
        if (idx < n) rowptr[idx] = off0 + vals[i];
    }
}

__global__ __launch_bounds__(256) void k_scatter(const int* __restrict__ src,
        const int* __restrict__ dst, const float* __restrict__ ew, int E,
        int* __restrict__ rowptr, float2* __restrict__ sorted) {
    int i = blockIdx.x * blockDim.x + threadIdx.x;
    if (i < E) {
        int d = dst[i];
        int pos = atomicAdd(&rowptr[d], 1);
        sorted[pos] = make_float2(__int_as_float(src[i]), ew[i]);
    }
}

// ---------------------------------------------------------------------------
// Fused gather-SpMM + attention combine. One 64-lane wave per node.
// FIRST (layer1): D=128, selfft bf16 in, h out bf16+elu.
// !FIRST (layer2): D=64, selfft fp32 in, h out fp32, no elu.
// relft is always bf16.
// ---------------------------------------------------------------------------
template <int PER, bool FIRST>
__global__ __launch_bounds__(256) void fused_spmm_att(
        const void* __restrict__ selfp, const ushort_t* __restrict__ relft,
        const int* __restrict__ rowptr, const float2* __restrict__ sorted,
        const float* __restrict__ vk, const float* __restrict__ vq,
        const float* __restrict__ bias,
        void* __restrict__ hout, float* __restrict__ attout, int M) {
    int wave = threadIdx.x >> 6;
    int lane = threadIdx.x & 63;
    int n = blockIdx.x * 4 + wave;
    if (n >= M) return;

    float sv[PER], nb[PER];
    if (FIRST) {
        uint_t s2 = ((const uint_t*)selfp)[(size_t)n * 64 + lane];
        sv[0] = bf_lo(s2); sv[1] = bf_hi(s2);
        nb[0] = 0.f; nb[1] = 0.f;
    } else {
        sv[0] = ((const float*)selfp)[(size_t)n * 64 + lane];
        nb[0] = 0.f;
    }

    int beg = (n > 0) ? rowptr[n - 1] : 0;
    int end = rowptr[n];
    int e = beg;
    if (e < end) {
        float2 sw = sorted[e];
        while (++e < end) {
            float2 swn = sorted[e];            // prefetch next edge meta
            int s = __float_as_int(sw.x);
            float w = sw.y;
            if (PER == 2) {
                uint_t v = ((const uint_t*)relft)[(size_t)s * 64 + lane];
                nb[0] = fmaf(w, bf_lo(v), nb[0]);
                nb[1] = fmaf(w, bf_hi(v), nb[1]);
            } else {
                nb[0] = fmaf(w, bf_one(relft[(size_t)s * 64 + lane]), nb[0]);
            }
            sw = swn;
        }
        int s = __float_as_int(sw.x);
        float w = sw.y;
        if (PER == 2) {
            uint_t v = ((const uint_t*)relft)[(size_t)s * 64 + lane];
            nb[0] = fmaf(w, bf_lo(v), nb[0]);
            nb[1] = fmaf(w, bf_hi(v), nb[1]);
        } else {
            nb[0] = fmaf(w, bf_one(relft[(size_t)s * 64 + lane]), nb[0]);
        }
    }

    float vkl[PER], vql[PER], bl[PER];
    if (PER == 2) {
        float2 k2 = ((const float2*)vk)[lane];
        float2 q2 = ((const float2*)vq)[lane];
        float2 b2 = ((const float2*)bias)[lane];
        vkl[0] = k2.x; vkl[1] = k2.y;
        vql[0] = q2.x; vql[1] = q2.y;
        bl[0]  = b2.x; bl[1]  = b2.y;
    } else {
        vkl[0] = vk[lane]; vql[0] = vq[lane]; bl[0] = bias[lane];
    }
    float sk = 0.f, sq = 0.f, nk = 0.f;
#pragma unroll
    for (int i = 0; i < PER; ++i) {
        sk = fmaf(sv[i], vkl[i], sk);
        sq = fmaf(sv[i], vql[i], sq);
        nk = fmaf(nb[i], vkl[i], nk);
    }
#pragma unroll
    for (int off = 32; off; off >>= 1) {
        sk += __shfl_xor(sk, off);
        sq += __shfl_xor(sq, off);
        nk += __shfl_xor(nk, off);
    }
    float e0 = sk + sq;
    float e1 = nk + sq;
    e0 = e0 > 0.f ? e0 : expm1f(e0);
    e1 = e1 > 0.f ? e1 : expm1f(e1);
    float m = fmaxf(e0, e1);
    float a0 = expf(e0 - m);
    float a1 = expf(e1 - m);
    float inv = 1.f / (a0 + a1);
    a0 *= inv; a1 *= inv;

    if (FIRST) {
        float o0 = fmaf(a0, sv[0], fmaf(a1, nb[0], bl[0]));
        float o1 = fmaf(a0, sv[1], fmaf(a1, nb[1], bl[1]));
        o0 = o0 > 0.f ? o0 : expm1f(o0);
        o1 = o1 > 0.f ? o1 : expm1f(o1);
        uint_t packed = (uint_t)bf_bits(o0) | ((uint_t)bf_bits(o1) << 16);
        ((uint_t*)hout)[(size_t)n * 64 + lane] = packed;
    } else {
        float o = fmaf(a0, sv[0], fmaf(a1, nb[0], bl[0]));
        ((float*)hout)[(size_t)n * 64 + lane] = o;
    }
    if (lane == 0) {
        attout[2 * (size_t)n + 0] = a0;
        attout[2 * (size_t)n + 1] = a1;
    }
}

// ---------------------------------------------------------------------------
// Segment-sum pooling: LDS-accumulate then global atomics.
// ---------------------------------------------------------------------------
__global__ __launch_bounds__(256) void pool_sum(
        const float* __restrict__ h, const int* __restrict__ gid,
        float* __restrict__ sums, float* __restrict__ cnt, int M) {
    __shared__ float ls[NG * D_OUT];
    __shared__ float lc[NG];
    for (int i = threadIdx.x; i < NG * D_OUT; i += 256) ls[i] = 0.f;
    if (threadIdx.x < NG) lc[threadIdx.x] = 0.f;
    __syncthreads();

    int d = threadIdx.x & 63;
    int nsub = threadIdx.x >> 6;
    int base = blockIdx.x * 1024;
#pragma unroll 4
    for (int i = 0; i < 256; ++i) {
        int n = base + i * 4 + nsub;
        if (n < M) {
            int g = gid[n];
            atomicAdd(&ls[g * D_OUT + d], h[(size_t)n * D_OUT + d]);
            if (d == 0) atomicAdd(&lc[g], 1.0f);
        }
    }
    __syncthreads();
    for (int i = threadIdx.x; i < NG * D_OUT; i += 256) {
        float v = ls[i];
        if (v != 0.f) atomicAdd(&sums[i], v);
    }
    if (threadIdx.x < NG) {
        float v = lc[threadIdx.x];
        if (v != 0.f) atomicAdd(&cnt[threadIdx.x], v);
    }
}

__global__ void pool_mlp(const float* __restrict__ sums, const float* __restrict__ cnt,
                         const float* __restrict__ w1, const float* __restrict__ b1,
                         const float* __restrict__ w2, const float* __restrict__ b2,
                         float* __restrict__ out) {
    int g = threadIdx.x;
    if (g >= NG) return;
    float c = fmaxf(cnt[g], 1.0f);
    float inv = 1.0f / c;
    float hg[D_OUT];
#pragma unroll
    for (int d = 0; d < D_OUT; ++d) hg[d] = sums[g * D_OUT + d] * inv;
    float acc = b2[0];
    for (int j = 0; j < D_OUT / 2; ++j) {
        float hid = b1[j];
#pragma unroll 8
        for (int d = 0; d < D_OUT; ++d) hid = fmaf(hg[d], w1[d * (D_OUT / 2) + j], hid);
        hid = fmaxf(hid, 0.f);
        acc = fmaf(hid, w2[j], acc);
    }
    out[g] = acc;
}

// ---------------------------------------------------------------------------
extern "C" void kernel_launch(void* const* d_in, const int* in_sizes, int n_in,
                              void* d_out, int out_size, void* d_ws, size_t ws_size,
                              hipStream_t stream) {
    const float* x       = (const float*)d_in[0];
    const int*   esrc    = (const int*)  d_in[1];
    const int*   edst    = (const int*)  d_in[2];
    const float* ew      = (const float*)d_in[3];
    const int*   gid     = (const int*)  d_in[4];
    const float* w_self1 = (const float*)d_in[5];
    const float* w_rel1  = (const float*)d_in[6];
    const float* bias1   = (const float*)d_in[7];
    const float* w_q1    = (const float*)d_in[8];
    const float* w_k1    = (const float*)d_in[9];
    const float* w_att1  = (const float*)d_in[10];
    const float* w_self2 = (const float*)d_in[11];
    const float* w_rel2  = (const float*)d_in[12];
    const float* bias2   = (const float*)d_in[13];
    const float* w_q2    = (const float*)d_in[14];
    const float* w_k2    = (const float*)d_in[15];
    const float* w_att2  = (const float*)d_in[16];
    const float* mlp_w1  = (const float*)d_in[17];
    const float* mlp_b1  = (const float*)d_in[18];
    const float* mlp_w2  = (const float*)d_in[19];
    const float* mlp_b2  = (const float*)d_in[20];

    const int N = in_sizes[0] / D_IN;
    const int E = in_sizes[1];

    float* out = (float*)d_out;
    float* out_embd = out;
    float* out_att1 = out + NG;
    float* out_att2 = out + NG + 2 * (size_t)N;

    // ---- Workspace layout (float units) ----
    // bufS: N*64 f  : selfft1 bf16 (N x 128)      -> selfft2 fp32 (N x 64)
    // bufR: N*64 f  : relft1  bf16 (N x 128)      -> relft2 bf16 (N x 64, first half)
    // bufH: N*64 f  : h1      bf16 (N x 128)      -> h2 fp32 (N x 64)
    float* ws = (float*)d_ws;
    size_t nf = (size_t)N;
    float* bufS = ws;
    float* bufR = ws + nf * 64;
    float* bufH = ws + nf * 128;
    int* ip     = (int*)(ws + nf * 192);
    int* hcnt   = ip;              // N
    int* rowptr = ip + N;          // N
    int* psum   = ip + 2 * N;      // 64
    size_t int_end = nf * 192 + 2 * nf + 64;
    int_end = (int_end + 1) & ~(size_t)1;
    float2* sorted = (float2*)(ws + int_end);     // E float2
    float* small = ws + int_end + 2 * (size_t)E;
    float* vk1 = small + 0;
    float* vq1 = small + 128;
    float* vk2 = small + 256;
    float* vq2 = small + 320;
    float* sums = small + 384;
    float* cnt  = small + 384 + NG * D_OUT;
    ushort_t* wtb = (ushort_t*)(small + 384 + NG * D_OUT + NG);
    ushort_t* wt_s1 = wtb;
    ushort_t* wt_r1 = wtb + 16384;
    ushort_t* wt_s2 = wtb + 32768;
    ushort_t* wt_r2 = wtb + 40960;

    hipMemsetAsync(hcnt, 0, (size_t)N * sizeof(int), stream);
    hipMemsetAsync(sums, 0, (NG * D_OUT + NG) * sizeof(float), stream);

    prep_wt<<<192, 256, 0, stream>>>(w_self1, w_rel1, w_self2, w_rel2, wtb);
    prep_att_vecs<<<2, 256, 0, stream>>>(w_q1, w_k1, w_att1, w_q2, w_k2, w_att2, small);

    // ---- CSR build (shared by both layers) ----
    int nchunks = (N + SCAN_CHUNK - 1) / SCAN_CHUNK;   // <= 64
    k_hist<<<(E + 255) / 256, 256, 0, stream>>>(edst, E, hcnt);
    k_chunk_sum<<<nchunks, 256, 0, stream>>>(hcnt, N, psum);
    k_scan_psum<<<1, 64, 0, stream>>>(psum, nchunks);
    k_chunk_scan<<<nchunks, 256, 0, stream>>>(hcnt, N, psum, rowptr);
    k_scatter<<<(E + 255) / 256, 256, 0, stream>>>(esrc, edst, ew, E, rowptr, sorted);

    // ---- Layer 1 ----
    {
        dim3 grid((N + 63) / 64, 1, 2);
        gemm_mfma<128, true, true><<<grid, 256, 0, stream>>>(
            x, N, wt_s1, wt_r1, (void*)bufS, (ushort_t*)bufR);
    }
    fused_spmm_att<2, true><<<(N + 3) / 4, 256, 0, stream>>>(
        (const void*)bufS, (const ushort_t*)bufR, rowptr, sorted,
        vk1, vq1, bias1, (void*)bufH, out_att1, N);

    // ---- Layer 2 ----
    {
        dim3 grid((N + 63) / 64, 1, 2);
        gemm_mfma<64, false, false><<<grid, 256, 0, stream>>>(
            (const void*)bufH, N, wt_s2, wt_r2, (void*)bufS, (ushort_t*)bufR);
    }
    fused_spmm_att<1, false><<<(N + 3) / 4, 256, 0, stream>>>(
        (const void*)bufS, (const ushort_t*)bufR, rowptr, sorted,
        vk2, vq2, bias2, (void*)bufH, out_att2, N);

    // ---- Pool + MLP ----
    pool_sum<<<(N + 1023) / 1024, 256, 0, stream>>>(bufH, gid, sums, cnt, N);
    pool_mlp<<<1, 64, 0, stream>>>(sums, cnt, mlp_w1, mlp_b1, mlp_w2, mlp_b2, out_embd);
}

// Round 4
// 523.506 us; speedup vs baseline: 8.4343x; 1.3184x over previous
//
#include <hip/hip_runtime.h>
#include <hip/hip_bf16.h>
#include <cstdint>
#include <cstddef>

static constexpr int D_IN  = 128;
static constexpr int D_HID = 128;
static constexpr int D_OUT = 64;
static constexpr int ATTD  = 64;
static constexpr int NG    = 64;
static constexpr int SCAN_CHUNK = 2048;   // 256 threads * 8

typedef __attribute__((ext_vector_type(8))) short s16x8;
typedef __attribute__((ext_vector_type(4))) float f32x4;
typedef unsigned short ushort_t;
typedef unsigned int uint_t;

__device__ __forceinline__ unsigned short bf_bits(float f) {
    union { __hip_bfloat16 h; unsigned short u; } cv;
    cv.h = __float2bfloat16(f);
    return cv.u;
}
__device__ __forceinline__ float bf_lo(uint_t v) { return __uint_as_float(v << 16); }
__device__ __forceinline__ float bf_hi(uint_t v) { return __uint_as_float(v & 0xffff0000u); }
__device__ __forceinline__ float bf_one(unsigned short u) { return __uint_as_float(((uint_t)u) << 16); }

// ---------------------------------------------------------------------------
// Weight prep: WT[c*128 + k] = bf16(W[k*C + c]) for the 4 GEMM weight matrices.
// ---------------------------------------------------------------------------
__global__ void prep_wt(const float* __restrict__ w_self1, const float* __restrict__ w_rel1,
                        const float* __restrict__ w_self2, const float* __restrict__ w_rel2,
                        ushort_t* __restrict__ wt) {
    int idx = blockIdx.x * 256 + threadIdx.x;
    if (idx >= 49152) return;
    const float* src; int base, Cc;
    if (idx < 16384)      { src = w_self1; base = 0;     Cc = 128; }
    else if (idx < 32768) { src = w_rel1;  base = 16384; Cc = 128; }
    else if (idx < 40960) { src = w_self2; base = 32768; Cc = 64;  }
    else                  { src = w_rel2;  base = 40960; Cc = 64;  }
    int l = idx - base;
    int c = l >> 7;
    int k = l & 127;
    wt[base + l] = bf_bits(src[k * Cc + c]);
}

// ---------------------------------------------------------------------------
// v_k = w_k @ a[:ATT], v_q = w_q @ a[ATT:] for both layers (fp32).
// ---------------------------------------------------------------------------
__global__ void prep_att_vecs(const float* __restrict__ w_q1, const float* __restrict__ w_k1,
                              const float* __restrict__ w_att1,
                              const float* __restrict__ w_q2, const float* __restrict__ w_k2,
                              const float* __restrict__ w_att2,
                              float* __restrict__ small) {
    int idx = blockIdx.x * blockDim.x + threadIdx.x;
    if (idx >= 384) return;
    float acc = 0.f;
    if (idx < 128) {
        int d = idx;
        for (int a = 0; a < ATTD; ++a) acc += w_k1[d * ATTD + a] * w_att1[a];
        small[0 + d] = acc;
    } else if (idx < 256) {
        int d = idx - 128;
        for (int a = 0; a < ATTD; ++a) acc += w_q1[d * ATTD + a] * w_att1[ATTD + a];
        small[128 + d] = acc;
    } else if (idx < 320) {
        int d = idx - 256;
        for (int a = 0; a < ATTD; ++a) acc += w_k2[d * ATTD + a] * w_att2[a];
        small[256 + d] = acc;
    } else {
        int d = idx - 320;
        for (int a = 0; a < ATTD; ++a) acc += w_q2[d * ATTD + a] * w_att2[ATTD + a];
        small[320 + d] = acc;
    }
}

// ---------------------------------------------------------------------------
// MFMA bf16 dual GEMM (same as round 3, verified correct).
// ---------------------------------------------------------------------------
template <int C, bool A32, bool OA_BF>
__global__ __launch_bounds__(256) void gemm_mfma(
        const void* __restrict__ A, int M,
        const ushort_t* __restrict__ WTa, const ushort_t* __restrict__ WTb,
        void* __restrict__ Oa, ushort_t* __restrict__ Ob) {
    constexpr int K = 128;
    constexpr int RS = K + 8;
    __shared__ ushort_t wt[C * RS];

    const ushort_t* WT = blockIdx.z ? WTb : WTa;
    for (int idx = threadIdx.x; idx < C * (K / 8); idx += 256) {
        int c  = idx / (K / 8);
        int kc = idx % (K / 8);
        *(uint4*)&wt[c * RS + kc * 8] = *(const uint4*)&WT[c * K + kc * 8];
    }
    __syncthreads();

    const int w    = threadIdx.x >> 6;
    const int lane = threadIdx.x & 63;
    const int row  = blockIdx.x * 64 + w * 16 + (lane & 15);
    const int rowc = row < M ? row : (M - 1);
    const int kb   = (lane >> 4) * 8;

    s16x8 afr[4];
    if (A32) {
        const float* Af = (const float*)A + (size_t)rowc * K + kb;
#pragma unroll
        for (int ks = 0; ks < 4; ++ks) {
            float4 f0 = *(const float4*)(Af + ks * 32);
            float4 f1 = *(const float4*)(Af + ks * 32 + 4);
            s16x8 a;
            a[0] = (short)bf_bits(f0.x); a[1] = (short)bf_bits(f0.y);
            a[2] = (short)bf_bits(f0.z); a[3] = (short)bf_bits(f0.w);
            a[4] = (short)bf_bits(f1.x); a[5] = (short)bf_bits(f1.y);
            a[6] = (short)bf_bits(f1.z); a[7] = (short)bf_bits(f1.w);
            afr[ks] = a;
        }
    } else {
        const ushort_t* Ab = (const ushort_t*)A + (size_t)rowc * K + kb;
#pragma unroll
        for (int ks = 0; ks < 4; ++ks) afr[ks] = *(const s16x8*)(Ab + ks * 32);
    }

    const int colc = lane & 15;
    const int r0   = blockIdx.x * 64 + w * 16 + (lane >> 4) * 4;

#pragma unroll
    for (int ct = 0; ct < C / 16; ++ct) {
        f32x4 acc = {0.f, 0.f, 0.f, 0.f};
        const int colb = ct * 16 + colc;
#pragma unroll
        for (int ks = 0; ks < 4; ++ks) {
            s16x8 b = *(const s16x8*)&wt[colb * RS + ks * 32 + kb];
            acc = __builtin_amdgcn_mfma_f32_16x16x32_bf16(afr[ks], b, acc, 0, 0, 0);
        }
        if (blockIdx.z == 0) {
            if (OA_BF) {
                ushort_t* O = (ushort_t*)Oa;
#pragma unroll
                for (int j = 0; j < 4; ++j)
                    if (r0 + j < M) O[(size_t)(r0 + j) * C + colb] = bf_bits(acc[j]);
            } else {
                float* O = (float*)Oa;
#pragma unroll
                for (int j = 0; j < 4; ++j)
                    if (r0 + j < M) O[(size_t)(r0 + j) * C + colb] = acc[j];
            }
        } else {
#pragma unroll
            for (int j = 0; j < 4; ++j)
                if (r0 + j < M) Ob[(size_t)(r0 + j) * C + colb] = bf_bits(acc[j]);
        }
    }
}

// ---------------------------------------------------------------------------
// CSR build: histogram -> hierarchical exclusive scan -> counting scatter.
// After k_scatter, rowptr[n] holds END of segment n (begin = rowptr[n-1] or 0).
// ---------------------------------------------------------------------------
__global__ __launch_bounds__(256) void k_hist(const int* __restrict__ dst, int E,
                                              int* __restrict__ cnt) {
    int i = blockIdx.x * blockDim.x + threadIdx.x;
    if (i < E) atomicAdd(&cnt[dst[i]], 1);
}

__global__ __launch_bounds__(256) void k_chunk_sum(const int* __restrict__ cnt, int n,
                                                   int* __restrict__ psum) {
    __shared__ int red[4];
    int base = blockIdx.x * SCAN_CHUNK;
    int t = threadIdx.x;
    int s = 0;
#pragma unroll
    for (int i = 0; i < 8; ++i) {
        int idx = base + t * 8 + i;
        if (idx < n) s += cnt[idx];
    }
#pragma unroll
    for (int off = 32; off; off >>= 1) s += __shfl_down(s, off);
    if ((t & 63) == 0) red[t >> 6] = s;
    __syncthreads();
    if (t == 0) psum[blockIdx.x] = red[0] + red[1] + red[2] + red[3];
}

__global__ void k_scan_psum(int* __restrict__ psum, int nb) {
    int t = threadIdx.x;
    int orig = (t < nb) ? psum[t] : 0;
    int v = orig;
#pragma unroll
    for (int off = 1; off < 64; off <<= 1) {
        int u = __shfl_up(v, off);
        if (t >= off) v += u;
    }
    if (t < nb) psum[t] = v - orig;
}

__global__ __launch_bounds__(256) void k_chunk_scan(const int* __restrict__ cnt, int n,
        const int* __restrict__ psum, int* __restrict__ rowptr) {
    __shared__ int wsum[4];
    int base = blockIdx.x * SCAN_CHUNK;
    int t = threadIdx.x;
    int vals[8];
    int s = 0;
#pragma unroll
    for (int i = 0; i < 8; ++i) {
        int idx = base + t * 8 + i;
        int c = (idx < n) ? cnt[idx] : 0;
        vals[i] = s;
        s += c;
    }
    int lane = t & 63, w = t >> 6;
    int incl = s;
#pragma unroll
    for (int off = 1; off < 64; off <<= 1) {
        int u = __shfl_up(incl, off);
        if (lane >= off) incl += u;
    }
    if (lane == 63) wsum[w] = incl;
    __syncthreads();
    int wbase = 0;
#pragma unroll
    for (int i = 0; i < 4; ++i) if (i < w) wbase += wsum[i];
    int texcl = wbase + incl - s;
    int off0 = psum[blockIdx.x] + texcl;
#pragma unroll
    for (int i = 0; i < 8; ++i) {
        int idx = base + t * 8 + i;
        if (idx < n) rowptr[idx] = off0 + vals[i];
    }
}

__global__ __launch_bounds__(256) void k_scatter(const int* __restrict__ src,
        const int* __restrict__ dst, const float* __restrict__ ew, int E,
        int* __restrict__ rowptr, float2* __restrict__ sorted) {
    int i = blockIdx.x * blockDim.x + threadIdx.x;
    if (i < E) {
        int d = dst[i];
        int pos = atomicAdd(&rowptr[d], 1);
        sorted[pos] = make_float2(__int_as_float(src[i]), ew[i]);
    }
}

// ---------------------------------------------------------------------------
// Fused gather-SpMM + attention combine. One 64-lane wave per node.
// 8-wide edge batches with clamped tail (zero weight) -> 8 gathers in flight.
// FIRST (layer1): D=128, selfft bf16 in, h out bf16+elu.
// !FIRST (layer2): D=64, selfft fp32 in, h out fp32, no elu.
// ---------------------------------------------------------------------------
template <int PER, bool FIRST>
__global__ __launch_bounds__(256) void fused_spmm_att(
        const void* __restrict__ selfp, const ushort_t* __restrict__ relft,
        const int* __restrict__ rowptr, const float2* __restrict__ sorted,
        const float* __restrict__ vk, const float* __restrict__ vq,
        const float* __restrict__ bias,
        void* __restrict__ hout, float* __restrict__ attout, int M) {
    int wave = threadIdx.x >> 6;
    int lane = threadIdx.x & 63;
    int n = blockIdx.x * 4 + wave;
    if (n >= M) return;

    float sv[PER], nb[PER];
    if (FIRST) {
        uint_t s2 = ((const uint_t*)selfp)[(size_t)n * 64 + lane];
        sv[0] = bf_lo(s2); sv[1] = bf_hi(s2);
        nb[0] = 0.f; nb[1] = 0.f;
    } else {
        sv[0] = ((const float*)selfp)[(size_t)n * 64 + lane];
        nb[0] = 0.f;
    }

    const int beg = (n > 0) ? rowptr[n - 1] : 0;
    const int end = rowptr[n];
    const uint_t*   rel32 = (const uint_t*)relft;

    for (int e = beg; e < end; e += 8) {
        // load 8 edge metas (clamped), mask weights past end
        float2 swb[8];
        float  wb[8];
        int    sb[8];
#pragma unroll
        for (int j = 0; j < 8; ++j) {
            int idx = e + j;
            int cl  = idx < end ? idx : end - 1;
            swb[j] = sorted[cl];
            wb[j]  = idx < end ? swb[j].y : 0.f;
            sb[j]  = __float_as_int(swb[j].x);
        }
        if (PER == 2) {
            uint_t vv[8];
#pragma unroll
            for (int j = 0; j < 8; ++j) vv[j] = rel32[(size_t)sb[j] * 64 + lane];
#pragma unroll
            for (int j = 0; j < 8; ++j) {
                nb[0] = fmaf(wb[j], bf_lo(vv[j]), nb[0]);
                nb[1] = fmaf(wb[j], bf_hi(vv[j]), nb[1]);
            }
        } else {
            ushort_t vv[8];
#pragma unroll
            for (int j = 0; j < 8; ++j) vv[j] = relft[(size_t)sb[j] * 64 + lane];
#pragma unroll
            for (int j = 0; j < 8; ++j) nb[0] = fmaf(wb[j], bf_one(vv[j]), nb[0]);
        }
    }

    float vkl[PER], vql[PER], bl[PER];
    if (PER == 2) {
        float2 k2 = ((const float2*)vk)[lane];
        float2 q2 = ((const float2*)vq)[lane];
        float2 b2 = ((const float2*)bias)[lane];
        vkl[0] = k2.x; vkl[1] = k2.y;
        vql[0] = q2.x; vql[1] = q2.y;
        bl[0]  = b2.x; bl[1]  = b2.y;
    } else {
        vkl[0] = vk[lane]; vql[0] = vq[lane]; bl[0] = bias[lane];
    }
    float sk = 0.f, sq = 0.f, nk = 0.f;
#pragma unroll
    for (int i = 0; i < PER; ++i) {
        sk = fmaf(sv[i], vkl[i], sk);
        sq = fmaf(sv[i], vql[i], sq);
        nk = fmaf(nb[i], vkl[i], nk);
    }
#pragma unroll
    for (int off = 32; off; off >>= 1) {
        sk += __shfl_xor(sk, off);
        sq += __shfl_xor(sq, off);
        nk += __shfl_xor(nk, off);
    }
    float e0 = sk + sq;
    float e1 = nk + sq;
    e0 = e0 > 0.f ? e0 : expm1f(e0);
    e1 = e1 > 0.f ? e1 : expm1f(e1);
    float m = fmaxf(e0, e1);
    float a0 = expf(e0 - m);
    float a1 = expf(e1 - m);
    float inv = 1.f / (a0 + a1);
    a0 *= inv; a1 *= inv;

    if (FIRST) {
        float o0 = fmaf(a0, sv[0], fmaf(a1, nb[0], bl[0]));
        float o1 = fmaf(a0, sv[1], fmaf(a1, nb[1], bl[1]));
        o0 = o0 > 0.f ? o0 : expm1f(o0);
        o1 = o1 > 0.f ? o1 : expm1f(o1);
        uint_t packed = (uint_t)bf_bits(o0) | ((uint_t)bf_bits(o1) << 16);
        ((uint_t*)hout)[(size_t)n * 64 + lane] = packed;
    } else {
        float o = fmaf(a0, sv[0], fmaf(a1, nb[0], bl[0]));
        ((float*)hout)[(size_t)n * 64 + lane] = o;
    }
    if (lane == 0) {
        attout[2 * (size_t)n + 0] = a0;
        attout[2 * (size_t)n + 1] = a1;
    }
}

// ---------------------------------------------------------------------------
// Segment-sum pooling: LDS-accumulate then global atomics.
// ---------------------------------------------------------------------------
__global__ __launch_bounds__(256) void pool_sum(
        const float* __restrict__ h, const int* __restrict__ gid,
        float* __restrict__ sums, float* __restrict__ cnt, int M) {
    __shared__ float ls[NG * D_OUT];
    __shared__ float lc[NG];
    for (int i = threadIdx.x; i < NG * D_OUT; i += 256) ls[i] = 0.f;
    if (threadIdx.x < NG) lc[threadIdx.x] = 0.f;
    __syncthreads();

    int d = threadIdx.x & 63;
    int nsub = threadIdx.x >> 6;
    int base = blockIdx.x * 1024;
#pragma unroll 4
    for (int i = 0; i < 256; ++i) {
        int n = base + i * 4 + nsub;
        if (n < M) {
            int g = gid[n];
            atomicAdd(&ls[g * D_OUT + d], h[(size_t)n * D_OUT + d]);
            if (d == 0) atomicAdd(&lc[g], 1.0f);
        }
    }
    __syncthreads();
    for (int i = threadIdx.x; i < NG * D_OUT; i += 256) {
        float v = ls[i];
        if (v != 0.f) atomicAdd(&sums[i], v);
    }
    if (threadIdx.x < NG) {
        float v = lc[threadIdx.x];
        if (v != 0.f) atomicAdd(&cnt[threadIdx.x], v);
    }
}

__global__ void pool_mlp(const float* __restrict__ sums, const float* __restrict__ cnt,
                         const float* __restrict__ w1, const float* __restrict__ b1,
                         const float* __restrict__ w2, const float* __restrict__ b2,
                         float* __restrict__ out) {
    int g = threadIdx.x;
    if (g >= NG) return;
    float c = fmaxf(cnt[g], 1.0f);
    float inv = 1.0f / c;
    float hg[D_OUT];
#pragma unroll
    for (int d = 0; d < D_OUT; ++d) hg[d] = sums[g * D_OUT + d] * inv;
    float acc = b2[0];
    for (int j = 0; j < D_OUT / 2; ++j) {
        float hid = b1[j];
#pragma unroll 8
        for (int d = 0; d < D_OUT; ++d) hid = fmaf(hg[d], w1[d * (D_OUT / 2) + j], hid);
        hid = fmaxf(hid, 0.f);
        acc = fmaf(hid, w2[j], acc);
    }
    out[g] = acc;
}

// ---------------------------------------------------------------------------
extern "C" void kernel_launch(void* const* d_in, const int* in_sizes, int n_in,
                              void* d_out, int out_size, void* d_ws, size_t ws_size,
                              hipStream_t stream) {
    const float* x       = (const float*)d_in[0];
    const int*   esrc    = (const int*)  d_in[1];
    const int*   edst    = (const int*)  d_in[2];
    const float* ew      = (const float*)d_in[3];
    const int*   gid     = (const int*)  d_in[4];
    const float* w_self1 = (const float*)d_in[5];
    const float* w_rel1  = (const float*)d_in[6];
    const float* bias1   = (const float*)d_in[7];
    const float* w_q1    = (const float*)d_in[8];
    const float* w_k1    = (const float*)d_in[9];
    const float* w_att1  = (const float*)d_in[10];
    const float* w_self2 = (const float*)d_in[11];
    const float* w_rel2  = (const float*)d_in[12];
    const float* bias2   = (const float*)d_in[13];
    const float* w_q2    = (const float*)d_in[14];
    const float* w_k2    = (const float*)d_in[15];
    const float* w_att2  = (const float*)d_in[16];
    const float* mlp_w1  = (const float*)d_in[17];
    const float* mlp_b1  = (const float*)d_in[18];
    const float* mlp_w2  = (const float*)d_in[19];
    const float* mlp_b2  = (const float*)d_in[20];

    const int N = in_sizes[0] / D_IN;
    const int E = in_sizes[1];

    float* out = (float*)d_out;
    float* out_embd = out;
    float* out_att1 = out + NG;
    float* out_att2 = out + NG + 2 * (size_t)N;

    // ---- Workspace layout (float units) ----
    float* ws = (float*)d_ws;
    size_t nf = (size_t)N;
    float* bufS = ws;                  // selfft1 bf16 (Nx128) -> selfft2 fp32 (Nx64)
    float* bufR = ws + nf * 64;        // relft1 bf16 (Nx128) -> relft2 bf16 (Nx64)
    float* bufH = ws + nf * 128;       // h1 bf16 (Nx128) -> h2 fp32 (Nx64)
    int* ip     = (int*)(ws + nf * 192);
    int* hcnt   = ip;              // N
    int* rowptr = ip + N;          // N
    int* psum   = ip + 2 * N;      // 64
    size_t int_end = nf * 192 + 2 * nf + 64;
    int_end = (int_end + 1) & ~(size_t)1;
    float2* sorted = (float2*)(ws + int_end);     // E float2
    float* small = ws + int_end + 2 * (size_t)E;
    float* vk1 = small + 0;
    float* vq1 = small + 128;
    float* vk2 = small + 256;
    float* vq2 = small + 320;
    float* sums = small + 384;
    float* cnt  = small + 384 + NG * D_OUT;
    ushort_t* wtb = (ushort_t*)(small + 384 + NG * D_OUT + NG);
    ushort_t* wt_s1 = wtb;
    ushort_t* wt_r1 = wtb + 16384;
    ushort_t* wt_s2 = wtb + 32768;
    ushort_t* wt_r2 = wtb + 40960;

    hipMemsetAsync(hcnt, 0, (size_t)N * sizeof(int), stream);
    hipMemsetAsync(sums, 0, (NG * D_OUT + NG) * sizeof(float), stream);

    prep_wt<<<192, 256, 0, stream>>>(w_self1, w_rel1, w_self2, w_rel2, wtb);
    prep_att_vecs<<<2, 256, 0, stream>>>(w_q1, w_k1, w_att1, w_q2, w_k2, w_att2, small);

    // ---- CSR build (shared by both layers) ----
    int nchunks = (N + SCAN_CHUNK - 1) / SCAN_CHUNK;
    k_hist<<<(E + 255) / 256, 256, 0, stream>>>(edst, E, hcnt);
    k_chunk_sum<<<nchunks, 256, 0, stream>>>(hcnt, N, psum);
    k_scan_psum<<<1, 64, 0, stream>>>(psum, nchunks);
    k_chunk_scan<<<nchunks, 256, 0, stream>>>(hcnt, N, psum, rowptr);
    k_scatter<<<(E + 255) / 256, 256, 0, stream>>>(esrc, edst, ew, E, rowptr, sorted);

    // ---- Layer 1 ----
    {
        dim3 grid((N + 63) / 64, 1, 2);
        gemm_mfma<128, true, true><<<grid, 256, 0, stream>>>(
            x, N, wt_s1, wt_r1, (void*)bufS, (ushort_t*)bufR);
    }
    fused_spmm_att<2, true><<<(N + 3) / 4, 256, 0, stream>>>(
        (const void*)bufS, (const ushort_t*)bufR, rowptr, sorted,
        vk1, vq1, bias1, (void*)bufH, out_att1, N);

    // ---- Layer 2 ----
    {
        dim3 grid((N + 63) / 64, 1, 2);
        gemm_mfma<64, false, false><<<grid, 256, 0, stream>>>(
            (const void*)bufH, N, wt_s2, wt_r2, (void*)bufS, (ushort_t*)bufR);
    }
    fused_spmm_att<1, false><<<(N + 3) / 4, 256, 0, stream>>>(
        (const void*)bufS, (const ushort_t*)bufR, rowptr, sorted,
        vk2, vq2, bias2, (void*)bufH, out_att2, N);

    // ---- Pool + MLP ----
    pool_sum<<<(N + 1023) / 1024, 256, 0, stream>>>(bufH, gid, sums, cnt, N);
    pool_mlp<<<1, 64, 0, stream>>>(sums, cnt, mlp_w1, mlp_b1, mlp_w2, mlp_b2, out_embd);
}

// Round 5
// 417.874 us; speedup vs baseline: 10.5664x; 1.2528x over previous
//
#include <hip/hip_runtime.h>
#include <hip/hip_bf16.h>
#include <cstdint>
#include <cstddef>

static constexpr int D_IN  = 128;
static constexpr int D_HID = 128;
static constexpr int D_OUT = 64;
static constexpr int ATTD  = 64;
static constexpr int NG    = 64;
static constexpr int NB    = 256;   // coarse buckets (dst >> 9)
static constexpr int NBLK  = 256;   // partition blocks
static constexpr int BSHIFT = 9;    // 512 dst per bucket

typedef __attribute__((ext_vector_type(8))) short s16x8;
typedef __attribute__((ext_vector_type(4))) float f32x4;
typedef unsigned short ushort_t;
typedef unsigned int uint_t;

__device__ __forceinline__ unsigned short bf_bits(float f) {
    union { __hip_bfloat16 h; unsigned short u; } cv;
    cv.h = __float2bfloat16(f);
    return cv.u;
}
__device__ __forceinline__ float bf_lo(uint_t v) { return __uint_as_float(v << 16); }
__device__ __forceinline__ float bf_hi(uint_t v) { return __uint_as_float(v & 0xffff0000u); }
__device__ __forceinline__ float bf_one(unsigned short u) { return __uint_as_float(((uint_t)u) << 16); }

// ---------------------------------------------------------------------------
// Weight prep: WT[c*128 + k] = bf16(W[k*C + c]) for the 4 GEMM weight matrices.
// ---------------------------------------------------------------------------
__global__ void prep_wt(const float* __restrict__ w_self1, const float* __restrict__ w_rel1,
                        const float* __restrict__ w_self2, const float* __restrict__ w_rel2,
                        ushort_t* __restrict__ wt) {
    int idx = blockIdx.x * 256 + threadIdx.x;
    if (idx >= 49152) return;
    const float* src; int base, Cc;
    if (idx < 16384)      { src = w_self1; base = 0;     Cc = 128; }
    else if (idx < 32768) { src = w_rel1;  base = 16384; Cc = 128; }
    else if (idx < 40960) { src = w_self2; base = 32768; Cc = 64;  }
    else                  { src = w_rel2;  base = 40960; Cc = 64;  }
    int l = idx - base;
    int c = l >> 7;
    int k = l & 127;
    wt[base + l] = bf_bits(src[k * Cc + c]);
}

// ---------------------------------------------------------------------------
// v_k = w_k @ a[:ATT], v_q = w_q @ a[ATT:] for both layers (fp32).
// ---------------------------------------------------------------------------
__global__ void prep_att_vecs(const float* __restrict__ w_q1, const float* __restrict__ w_k1,
                              const float* __restrict__ w_att1,
                              const float* __restrict__ w_q2, const float* __restrict__ w_k2,
                              const float* __restrict__ w_att2,
                              float* __restrict__ small) {
    int idx = blockIdx.x * blockDim.x + threadIdx.x;
    if (idx >= 384) return;
    float acc = 0.f;
    if (idx < 128) {
        int d = idx;
        for (int a = 0; a < ATTD; ++a) acc += w_k1[d * ATTD + a] * w_att1[a];
        small[0 + d] = acc;
    } else if (idx < 256) {
        int d = idx - 128;
        for (int a = 0; a < ATTD; ++a) acc += w_q1[d * ATTD + a] * w_att1[ATTD + a];
        small[128 + d] = acc;
    } else if (idx < 320) {
        int d = idx - 256;
        for (int a = 0; a < ATTD; ++a) acc += w_k2[d * ATTD + a] * w_att2[a];
        small[256 + d] = acc;
    } else {
        int d = idx - 320;
        for (int a = 0; a < ATTD; ++a) acc += w_q2[d * ATTD + a] * w_att2[ATTD + a];
        small[320 + d] = acc;
    }
}

// ---------------------------------------------------------------------------
// MFMA bf16 dual GEMM (verified).
// ---------------------------------------------------------------------------
template <int C, bool A32, bool OA_BF>
__global__ __launch_bounds__(256) void gemm_mfma(
        const void* __restrict__ A, int M,
        const ushort_t* __restrict__ WTa, const ushort_t* __restrict__ WTb,
        void* __restrict__ Oa, ushort_t* __restrict__ Ob) {
    constexpr int K = 128;
    constexpr int RS = K + 8;
    __shared__ ushort_t wt[C * RS];

    const ushort_t* WT = blockIdx.z ? WTb : WTa;
    for (int idx = threadIdx.x; idx < C * (K / 8); idx += 256) {
        int c  = idx / (K / 8);
        int kc = idx % (K / 8);
        *(uint4*)&wt[c * RS + kc * 8] = *(const uint4*)&WT[c * K + kc * 8];
    }
    __syncthreads();

    const int w    = threadIdx.x >> 6;
    const int lane = threadIdx.x & 63;
    const int row  = blockIdx.x * 64 + w * 16 + (lane & 15);
    const int rowc = row < M ? row : (M - 1);
    const int kb   = (lane >> 4) * 8;

    s16x8 afr[4];
    if (A32) {
        const float* Af = (const float*)A + (size_t)rowc * K + kb;
#pragma unroll
        for (int ks = 0; ks < 4; ++ks) {
            float4 f0 = *(const float4*)(Af + ks * 32);
            float4 f1 = *(const float4*)(Af + ks * 32 + 4);
            s16x8 a;
            a[0] = (short)bf_bits(f0.x); a[1] = (short)bf_bits(f0.y);
            a[2] = (short)bf_bits(f0.z); a[3] = (short)bf_bits(f0.w);
            a[4] = (short)bf_bits(f1.x); a[5] = (short)bf_bits(f1.y);
            a[6] = (short)bf_bits(f1.z); a[7] = (short)bf_bits(f1.w);
            afr[ks] = a;
        }
    } else {
        const ushort_t* Ab = (const ushort_t*)A + (size_t)rowc * K + kb;
#pragma unroll
        for (int ks = 0; ks < 4; ++ks) afr[ks] = *(const s16x8*)(Ab + ks * 32);
    }

    const int colc = lane & 15;
    const int r0   = blockIdx.x * 64 + w * 16 + (lane >> 4) * 4;

#pragma unroll
    for (int ct = 0; ct < C / 16; ++ct) {
        f32x4 acc = {0.f, 0.f, 0.f, 0.f};
        const int colb = ct * 16 + colc;
#pragma unroll
        for (int ks = 0; ks < 4; ++ks) {
            s16x8 b = *(const s16x8*)&wt[colb * RS + ks * 32 + kb];
            acc = __builtin_amdgcn_mfma_f32_16x16x32_bf16(afr[ks], b, acc, 0, 0, 0);
        }
        if (blockIdx.z == 0) {
            if (OA_BF) {
                ushort_t* O = (ushort_t*)Oa;
#pragma unroll
                for (int j = 0; j < 4; ++j)
                    if (r0 + j < M) O[(size_t)(r0 + j) * C + colb] = bf_bits(acc[j]);
            } else {
                float* O = (float*)Oa;
#pragma unroll
                for (int j = 0; j < 4; ++j)
                    if (r0 + j < M) O[(size_t)(r0 + j) * C + colb] = acc[j];
            }
        } else {
#pragma unroll
            for (int j = 0; j < 4; ++j)
                if (r0 + j < M) Ob[(size_t)(r0 + j) * C + colb] = bf_bits(acc[j]);
        }
    }
}

// ---------------------------------------------------------------------------
// Two-level counting sort of edges by dst (replaces hist+atomic scatter).
// P1: coarse partition into NB buckets of 512 dst; P2: per-bucket LDS sort.
// Record pack: x = src (bits 0..19) | dstLocal (bits 20..28), y = w bits.
// ---------------------------------------------------------------------------
__global__ __launch_bounds__(256) void part_hist(const int* __restrict__ dst, int E,
                                                 int chunk, int* __restrict__ bh) {
    __shared__ int h[NB];
    h[threadIdx.x] = 0;
    __syncthreads();
    int beg = blockIdx.x * chunk;
    int end = min(E, beg + chunk);
    for (int i = beg + threadIdx.x; i < end; i += 256)
        atomicAdd(&h[dst[i] >> BSHIFT], 1);
    __syncthreads();
    bh[threadIdx.x * NBLK + blockIdx.x] = h[threadIdx.x];
}

// single block, 256 threads
__global__ void part_scan(int* __restrict__ bh, int* __restrict__ bb, int E) {
    __shared__ int wsum[4];
    int t = threadIdx.x;
    int run = 0;
    for (int blk = 0; blk < NBLK; ++blk) {
        int v = bh[t * NBLK + blk];
        bh[t * NBLK + blk] = run;
        run += v;
    }
    int lane = t & 63, w = t >> 6;
    int incl = run;
#pragma unroll
    for (int off = 1; off < 64; off <<= 1) {
        int u = __shfl_up(incl, off);
        if (lane >= off) incl += u;
    }
    if (lane == 63) wsum[w] = incl;
    __syncthreads();
    int wbase = 0;
#pragma unroll
    for (int i = 0; i < 4; ++i) if (i < w) wbase += wsum[i];
    int base = wbase + incl - run;   // exclusive bucket base
    bb[t] = base;
    if (t == 255) bb[256] = base + run;   // == E
    for (int blk = 0; blk < NBLK; ++blk)
        bh[t * NBLK + blk] += base;
}

__global__ __launch_bounds__(256) void part_scatter(const int* __restrict__ src,
        const int* __restrict__ dst, const float* __restrict__ ew, int E, int chunk,
        const int* __restrict__ bh, uint2* __restrict__ part) {
    __shared__ int ofs[NB];
    ofs[threadIdx.x] = bh[threadIdx.x * NBLK + blockIdx.x];
    __syncthreads();
    int beg = blockIdx.x * chunk;
    int end = min(E, beg + chunk);
    for (int i = beg + threadIdx.x; i < end; i += 256) {
        int d = dst[i];
        int b = d >> BSHIFT;
        int pos = atomicAdd(&ofs[b], 1);
        part[pos] = make_uint2((uint_t)src[i] | ((uint_t)(d & 511) << 20),
                               __float_as_uint(ew[i]));
    }
}

// one block per bucket: LDS fine hist + scan -> rowptr + locality-friendly scatter
__global__ __launch_bounds__(256) void bucket_sort(const uint2* __restrict__ part,
        const int* __restrict__ bb, int* __restrict__ rowptr,
        float2* __restrict__ sorted, int N_) {
    __shared__ int hist[512];
    __shared__ int wsum[4];
    int b = blockIdx.x;
    int t = threadIdx.x;
    int start = bb[b], end = bb[b + 1];
    hist[t] = 0; hist[t + 256] = 0;
    __syncthreads();
    for (int i = start + t; i < end; i += 256)
        atomicAdd(&hist[part[i].x >> 20], 1);
    __syncthreads();
    int v0 = hist[2 * t], v1 = hist[2 * t + 1];
    int pair = v0 + v1;
    int lane = t & 63, w = t >> 6;
    int incl = pair;
#pragma unroll
    for (int off = 1; off < 64; off <<= 1) {
        int u = __shfl_up(incl, off);
        if (lane >= off) incl += u;
    }
    if (lane == 63) wsum[w] = incl;
    __syncthreads();
    int wbase = 0;
#pragma unroll
    for (int i = 0; i < 4; ++i) if (i < w) wbase += wsum[i];
    int excl = wbase + incl - pair;       // exclusive over dstLocal pairs
    __syncthreads();                      // all hist reads done before overwrite
    hist[2 * t]     = start + excl;       // absolute scatter offsets
    hist[2 * t + 1] = start + excl + v0;
    int dst0 = (b << BSHIFT) + 2 * t;
    if (dst0 < N_)     rowptr[dst0]     = start + excl + v0;        // inclusive end
    if (dst0 + 1 < N_) rowptr[dst0 + 1] = start + excl + v0 + v1;
    __syncthreads();
    for (int i = start + t; i < end; i += 256) {
        uint2 r = part[i];
        int dl = r.x >> 20;
        int s  = r.x & 0xFFFFF;
        int pos = atomicAdd(&hist[dl], 1);
        sorted[pos] = make_float2(__int_as_float(s), __uint_as_float(r.y));
    }
}

// ---------------------------------------------------------------------------
// Fused gather-SpMM + attention combine. One 64-lane wave per node.
// 8-wide edge batches with clamped tail (zero weight) -> 8 gathers in flight.
// ---------------------------------------------------------------------------
template <int PER, bool FIRST>
__global__ __launch_bounds__(256) void fused_spmm_att(
        const void* __restrict__ selfp, const ushort_t* __restrict__ relft,
        const int* __restrict__ rowptr, const float2* __restrict__ sorted,
        const float* __restrict__ vk, const float* __restrict__ vq,
        const float* __restrict__ bias,
        void* __restrict__ hout, float* __restrict__ attout, int M) {
    int wave = threadIdx.x >> 6;
    int lane = threadIdx.x & 63;
    int n = blockIdx.x * 4 + wave;
    if (n >= M) return;

    float sv[PER], nb[PER];
    if (FIRST) {
        uint_t s2 = ((const uint_t*)selfp)[(size_t)n * 64 + lane];
        sv[0] = bf_lo(s2); sv[1] = bf_hi(s2);
        nb[0] = 0.f; nb[1] = 0.f;
    } else {
        sv[0] = ((const float*)selfp)[(size_t)n * 64 + lane];
        nb[0] = 0.f;
    }

    const int beg = (n > 0) ? rowptr[n - 1] : 0;
    const int end = rowptr[n];
    const uint_t* rel32 = (const uint_t*)relft;

    for (int e = beg; e < end; e += 8) {
        float2 swb[8];
        float  wb[8];
        int    sb[8];
#pragma unroll
        for (int j = 0; j < 8; ++j) {
            int idx = e + j;
            int cl  = idx < end ? idx : end - 1;
            swb[j] = sorted[cl];
            wb[j]  = idx < end ? swb[j].y : 0.f;
            sb[j]  = __float_as_int(swb[j].x);
        }
        if (PER == 2) {
            uint_t vv[8];
#pragma unroll
            for (int j = 0; j < 8; ++j) vv[j] = rel32[(size_t)sb[j] * 64 + lane];
#pragma unroll
            for (int j = 0; j < 8; ++j) {
                nb[0] = fmaf(wb[j], bf_lo(vv[j]), nb[0]);
                nb[1] = fmaf(wb[j], bf_hi(vv[j]), nb[1]);
            }
        } else {
            ushort_t vv[8];
#pragma unroll
            for (int j = 0; j < 8; ++j) vv[j] = relft[(size_t)sb[j] * 64 + lane];
#pragma unroll
            for (int j = 0; j < 8; ++j) nb[0] = fmaf(wb[j], bf_one(vv[j]), nb[0]);
        }
    }

    float vkl[PER], vql[PER], bl[PER];
    if (PER == 2) {
        float2 k2 = ((const float2*)vk)[lane];
        float2 q2 = ((const float2*)vq)[lane];
        float2 b2 = ((const float2*)bias)[lane];
        vkl[0] = k2.x; vkl[1] = k2.y;
        vql[0] = q2.x; vql[1] = q2.y;
        bl[0]  = b2.x; bl[1]  = b2.y;
    } else {
        vkl[0] = vk[lane]; vql[0] = vq[lane]; bl[0] = bias[lane];
    }
    float sk = 0.f, sq = 0.f, nk = 0.f;
#pragma unroll
    for (int i = 0; i < PER; ++i) {
        sk = fmaf(sv[i], vkl[i], sk);
        sq = fmaf(sv[i], vql[i], sq);
        nk = fmaf(nb[i], vkl[i], nk);
    }
#pragma unroll
    for (int off = 32; off; off >>= 1) {
        sk += __shfl_xor(sk, off);
        sq += __shfl_xor(sq, off);
        nk += __shfl_xor(nk, off);
    }
    float e0 = sk + sq;
    float e1 = nk + sq;
    e0 = e0 > 0.f ? e0 : expm1f(e0);
    e1 = e1 > 0.f ? e1 : expm1f(e1);
    float m = fmaxf(e0, e1);
    float a0 = expf(e0 - m);
    float a1 = expf(e1 - m);
    float inv = 1.f / (a0 + a1);
    a0 *= inv; a1 *= inv;

    if (FIRST) {
        float o0 = fmaf(a0, sv[0], fmaf(a1, nb[0], bl[0]));
        float o1 = fmaf(a0, sv[1], fmaf(a1, nb[1], bl[1]));
        o0 = o0 > 0.f ? o0 : expm1f(o0);
        o1 = o1 > 0.f ? o1 : expm1f(o1);
        uint_t packed = (uint_t)bf_bits(o0) | ((uint_t)bf_bits(o1) << 16);
        ((uint_t*)hout)[(size_t)n * 64 + lane] = packed;
    } else {
        float o = fmaf(a0, sv[0], fmaf(a1, nb[0], bl[0]));
        ((float*)hout)[(size_t)n * 64 + lane] = o;
    }
    if (lane == 0) {
        attout[2 * (size_t)n + 0] = a0;
        attout[2 * (size_t)n + 1] = a1;
    }
}

// ---------------------------------------------------------------------------
// Segment-sum pooling: LDS-accumulate then global atomics.
// ---------------------------------------------------------------------------
__global__ __launch_bounds__(256) void pool_sum(
        const float* __restrict__ h, const int* __restrict__ gid,
        float* __restrict__ sums, float* __restrict__ cnt, int M) {
    __shared__ float ls[NG * D_OUT];
    __shared__ float lc[NG];
    for (int i = threadIdx.x; i < NG * D_OUT; i += 256) ls[i] = 0.f;
    if (threadIdx.x < NG) lc[threadIdx.x] = 0.f;
    __syncthreads();

    int d = threadIdx.x & 63;
    int nsub = threadIdx.x >> 6;
    int base = blockIdx.x * 1024;
#pragma unroll 4
    for (int i = 0; i < 256; ++i) {
        int n = base + i * 4 + nsub;
        if (n < M) {
            int g = gid[n];
            atomicAdd(&ls[g * D_OUT + d], h[(size_t)n * D_OUT + d]);
            if (d == 0) atomicAdd(&lc[g], 1.0f);
        }
    }
    __syncthreads();
    for (int i = threadIdx.x; i < NG * D_OUT; i += 256) {
        float v = ls[i];
        if (v != 0.f) atomicAdd(&sums[i], v);
    }
    if (threadIdx.x < NG) {
        float v = lc[threadIdx.x];
        if (v != 0.f) atomicAdd(&cnt[threadIdx.x], v);
    }
}

__global__ void pool_mlp(const float* __restrict__ sums, const float* __restrict__ cnt,
                         const float* __restrict__ w1, const float* __restrict__ b1,
                         const float* __restrict__ w2, const float* __restrict__ b2,
                         float* __restrict__ out) {
    int g = threadIdx.x;
    if (g >= NG) return;
    float c = fmaxf(cnt[g], 1.0f);
    float inv = 1.0f / c;
    float hg[D_OUT];
#pragma unroll
    for (int d = 0; d < D_OUT; ++d) hg[d] = sums[g * D_OUT + d] * inv;
    float acc = b2[0];
    for (int j = 0; j < D_OUT / 2; ++j) {
        float hid = b1[j];
#pragma unroll 8
        for (int d = 0; d < D_OUT; ++d) hid = fmaf(hg[d], w1[d * (D_OUT / 2) + j], hid);
        hid = fmaxf(hid, 0.f);
        acc = fmaf(hid, w2[j], acc);
    }
    out[g] = acc;
}

// ---------------------------------------------------------------------------
extern "C" void kernel_launch(void* const* d_in, const int* in_sizes, int n_in,
                              void* d_out, int out_size, void* d_ws, size_t ws_size,
                              hipStream_t stream) {
    const float* x       = (const float*)d_in[0];
    const int*   esrc    = (const int*)  d_in[1];
    const int*   edst    = (const int*)  d_in[2];
    const float* ew      = (const float*)d_in[3];
    const int*   gid     = (const int*)  d_in[4];
    const float* w_self1 = (const float*)d_in[5];
    const float* w_rel1  = (const float*)d_in[6];
    const float* bias1   = (const float*)d_in[7];
    const float* w_q1    = (const float*)d_in[8];
    const float* w_k1    = (const float*)d_in[9];
    const float* w_att1  = (const float*)d_in[10];
    const float* w_self2 = (const float*)d_in[11];
    const float* w_rel2  = (const float*)d_in[12];
    const float* bias2   = (const float*)d_in[13];
    const float* w_q2    = (const float*)d_in[14];
    const float* w_k2    = (const float*)d_in[15];
    const float* w_att2  = (const float*)d_in[16];
    const float* mlp_w1  = (const float*)d_in[17];
    const float* mlp_b1  = (const float*)d_in[18];
    const float* mlp_w2  = (const float*)d_in[19];
    const float* mlp_b2  = (const float*)d_in[20];

    const int N = in_sizes[0] / D_IN;
    const int E = in_sizes[1];

    float* out = (float*)d_out;
    float* out_embd = out;
    float* out_att1 = out + NG;
    float* out_att2 = out + NG + 2 * (size_t)N;

    // ---- Workspace layout (float units) ----
    float* ws = (float*)d_ws;
    size_t nf = (size_t)N;
    float* bufS = ws;                  // selfft1 bf16 (Nx128) -> selfft2 fp32 (Nx64)
    float* bufR = ws + nf * 64;        // relft1 bf16 (Nx128) -> relft2 bf16 (Nx64)
    float* bufH = ws + nf * 128;       // part[] during sort -> h1 bf16 -> h2 fp32
    uint2* part = (uint2*)bufH;        // E uint2 = 12.8MB <= N*64*4B, dead before fused1
    int* ip     = (int*)(ws + nf * 192);
    int* rowptr = ip;                  // N
    int* bb     = ip + N;              // 257
    int* bh     = ip + N + 257;        // NB*NBLK = 65536
    size_t int_end = nf * 192 + nf + 257 + (size_t)NB * NBLK;
    int_end = (int_end + 1) & ~(size_t)1;
    float2* sorted = (float2*)(ws + int_end);     // E float2
    float* small = ws + int_end + 2 * (size_t)E;
    float* vk1 = small + 0;
    float* vq1 = small + 128;
    float* vk2 = small + 256;
    float* vq2 = small + 320;
    float* sums = small + 384;
    float* cnt  = small + 384 + NG * D_OUT;
    ushort_t* wtb = (ushort_t*)(small + 384 + NG * D_OUT + NG);
    ushort_t* wt_s1 = wtb;
    ushort_t* wt_r1 = wtb + 16384;
    ushort_t* wt_s2 = wtb + 32768;
    ushort_t* wt_r2 = wtb + 40960;

    hipMemsetAsync(sums, 0, (NG * D_OUT + NG) * sizeof(float), stream);

    prep_wt<<<192, 256, 0, stream>>>(w_self1, w_rel1, w_self2, w_rel2, wtb);
    prep_att_vecs<<<2, 256, 0, stream>>>(w_q1, w_k1, w_att1, w_q2, w_k2, w_att2, small);

    // ---- Edge sort (two-level counting sort, shared by both layers) ----
    const int chunk = (E + NBLK - 1) / NBLK;
    const int nbuck = (N + (1 << BSHIFT) - 1) >> BSHIFT;    // 196
    part_hist<<<NBLK, 256, 0, stream>>>(edst, E, chunk, bh);
    part_scan<<<1, 256, 0, stream>>>(bh, bb, E);
    part_scatter<<<NBLK, 256, 0, stream>>>(esrc, edst, ew, E, chunk, bh, part);
    bucket_sort<<<nbuck, 256, 0, stream>>>(part, bb, rowptr, sorted, N);

    // ---- Layer 1 ----
    {
        dim3 grid((N + 63) / 64, 1, 2);
        gemm_mfma<128, true, true><<<grid, 256, 0, stream>>>(
            x, N, wt_s1, wt_r1, (void*)bufS, (ushort_t*)bufR);
    }
    fused_spmm_att<2, true><<<(N + 3) / 4, 256, 0, stream>>>(
        (const void*)bufS, (const ushort_t*)bufR, rowptr, sorted,
        vk1, vq1, bias1, (void*)bufH, out_att1, N);

    // ---- Layer 2 ----
    {
        dim3 grid((N + 63) / 64, 1, 2);
        gemm_mfma<64, false, false><<<grid, 256, 0, stream>>>(
            (const void*)bufH, N, wt_s2, wt_r2, (void*)bufS, (ushort_t*)bufR);
    }
    fused_spmm_att<1, false><<<(N + 3) / 4, 256, 0, stream>>>(
        (const void*)bufS, (const ushort_t*)bufR, rowptr, sorted,
        vk2, vq2, bias2, (void*)bufH, out_att2, N);

    // ---- Pool + MLP ----
    pool_sum<<<(N + 1023) / 1024, 256, 0, stream>>>(bufH, gid, sums, cnt, N);
    pool_mlp<<<1, 64, 0, stream>>>(sums, cnt, mlp_w1, mlp_b1, mlp_w2, mlp_b2, out_embd);
}

// Round 6
// 357.630 us; speedup vs baseline: 12.3463x; 1.1685x over previous
//
#include <hip/hip_runtime.h>
#include <hip/hip_bf16.h>
#include <cstdint>
#include <cstddef>

static constexpr int D_IN  = 128;
static constexpr int D_HID = 128;
static constexpr int D_OUT = 64;
static constexpr int ATTD  = 64;
static constexpr int NG    = 64;
static constexpr int NB    = 256;   // coarse buckets (dst >> 9)
static constexpr int NBLK  = 256;   // partition blocks
static constexpr int BSHIFT = 9;    // 512 dst per bucket

typedef __attribute__((ext_vector_type(8))) short s16x8;
typedef __attribute__((ext_vector_type(4))) float f32x4;
typedef unsigned short ushort_t;
typedef unsigned int uint_t;

__device__ __forceinline__ unsigned short bf_bits(float f) {
    union { __hip_bfloat16 h; unsigned short u; } cv;
    cv.h = __float2bfloat16(f);
    return cv.u;
}
__device__ __forceinline__ float bf_lo(uint_t v) { return __uint_as_float(v << 16); }
__device__ __forceinline__ float bf_hi(uint_t v) { return __uint_as_float(v & 0xffff0000u); }
__device__ __forceinline__ float bf_one(unsigned short u) { return __uint_as_float(((uint_t)u) << 16); }

// ---------------------------------------------------------------------------
// Weight prep: WT[c*128 + k] = bf16(W[k*C + c]) for the 4 GEMM weight matrices.
// ---------------------------------------------------------------------------
__global__ void prep_wt(const float* __restrict__ w_self1, const float* __restrict__ w_rel1,
                        const float* __restrict__ w_self2, const float* __restrict__ w_rel2,
                        ushort_t* __restrict__ wt) {
    int idx = blockIdx.x * 256 + threadIdx.x;
    if (idx >= 49152) return;
    const float* src; int base, Cc;
    if (idx < 16384)      { src = w_self1; base = 0;     Cc = 128; }
    else if (idx < 32768) { src = w_rel1;  base = 16384; Cc = 128; }
    else if (idx < 40960) { src = w_self2; base = 32768; Cc = 64;  }
    else                  { src = w_rel2;  base = 40960; Cc = 64;  }
    int l = idx - base;
    int c = l >> 7;
    int k = l & 127;
    wt[base + l] = bf_bits(src[k * Cc + c]);
}

// ---------------------------------------------------------------------------
// v_k = w_k @ a[:ATT], v_q = w_q @ a[ATT:] for both layers (fp32).
// ---------------------------------------------------------------------------
__global__ void prep_att_vecs(const float* __restrict__ w_q1, const float* __restrict__ w_k1,
                              const float* __restrict__ w_att1,
                              const float* __restrict__ w_q2, const float* __restrict__ w_k2,
                              const float* __restrict__ w_att2,
                              float* __restrict__ small) {
    int idx = blockIdx.x * blockDim.x + threadIdx.x;
    if (idx >= 384) return;
    float acc = 0.f;
    if (idx < 128) {
        int d = idx;
        for (int a = 0; a < ATTD; ++a) acc += w_k1[d * ATTD + a] * w_att1[a];
        small[0 + d] = acc;
    } else if (idx < 256) {
        int d = idx - 128;
        for (int a = 0; a < ATTD; ++a) acc += w_q1[d * ATTD + a] * w_att1[ATTD + a];
        small[128 + d] = acc;
    } else if (idx < 320) {
        int d = idx - 256;
        for (int a = 0; a < ATTD; ++a) acc += w_k2[d * ATTD + a] * w_att2[a];
        small[256 + d] = acc;
    } else {
        int d = idx - 320;
        for (int a = 0; a < ATTD; ++a) acc += w_q2[d * ATTD + a] * w_att2[ATTD + a];
        small[320 + d] = acc;
    }
}

// ---------------------------------------------------------------------------
// MFMA bf16 dual GEMM (verified).
// ---------------------------------------------------------------------------
template <int C, bool A32, bool OA_BF>
__global__ __launch_bounds__(256) void gemm_mfma(
        const void* __restrict__ A, int M,
        const ushort_t* __restrict__ WTa, const ushort_t* __restrict__ WTb,
        void* __restrict__ Oa, ushort_t* __restrict__ Ob) {
    constexpr int K = 128;
    constexpr int RS = K + 8;
    __shared__ ushort_t wt[C * RS];

    const ushort_t* WT = blockIdx.z ? WTb : WTa;
    for (int idx = threadIdx.x; idx < C * (K / 8); idx += 256) {
        int c  = idx / (K / 8);
        int kc = idx % (K / 8);
        *(uint4*)&wt[c * RS + kc * 8] = *(const uint4*)&WT[c * K + kc * 8];
    }
    __syncthreads();

    const int w    = threadIdx.x >> 6;
    const int lane = threadIdx.x & 63;
    const int row  = blockIdx.x * 64 + w * 16 + (lane & 15);
    const int rowc = row < M ? row : (M - 1);
    const int kb   = (lane >> 4) * 8;

    s16x8 afr[4];
    if (A32) {
        const float* Af = (const float*)A + (size_t)rowc * K + kb;
#pragma unroll
        for (int ks = 0; ks < 4; ++ks) {
            float4 f0 = *(const float4*)(Af + ks * 32);
            float4 f1 = *(const float4*)(Af + ks * 32 + 4);
            s16x8 a;
            a[0] = (short)bf_bits(f0.x); a[1] = (short)bf_bits(f0.y);
            a[2] = (short)bf_bits(f0.z); a[3] = (short)bf_bits(f0.w);
            a[4] = (short)bf_bits(f1.x); a[5] = (short)bf_bits(f1.y);
            a[6] = (short)bf_bits(f1.z); a[7] = (short)bf_bits(f1.w);
            afr[ks] = a;
        }
    } else {
        const ushort_t* Ab = (const ushort_t*)A + (size_t)rowc * K + kb;
#pragma unroll
        for (int ks = 0; ks < 4; ++ks) afr[ks] = *(const s16x8*)(Ab + ks * 32);
    }

    const int colc = lane & 15;
    const int r0   = blockIdx.x * 64 + w * 16 + (lane >> 4) * 4;

#pragma unroll
    for (int ct = 0; ct < C / 16; ++ct) {
        f32x4 acc = {0.f, 0.f, 0.f, 0.f};
        const int colb = ct * 16 + colc;
#pragma unroll
        for (int ks = 0; ks < 4; ++ks) {
            s16x8 b = *(const s16x8*)&wt[colb * RS + ks * 32 + kb];
            acc = __builtin_amdgcn_mfma_f32_16x16x32_bf16(afr[ks], b, acc, 0, 0, 0);
        }
        if (blockIdx.z == 0) {
            if (OA_BF) {
                ushort_t* O = (ushort_t*)Oa;
#pragma unroll
                for (int j = 0; j < 4; ++j)
                    if (r0 + j < M) O[(size_t)(r0 + j) * C + colb] = bf_bits(acc[j]);
            } else {
                float* O = (float*)Oa;
#pragma unroll
                for (int j = 0; j < 4; ++j)
                    if (r0 + j < M) O[(size_t)(r0 + j) * C + colb] = acc[j];
            }
        } else {
#pragma unroll
            for (int j = 0; j < 4; ++j)
                if (r0 + j < M) Ob[(size_t)(r0 + j) * C + colb] = bf_bits(acc[j]);
        }
    }
}

// ---------------------------------------------------------------------------
// Two-level counting sort of edges by dst.
// ---------------------------------------------------------------------------
__global__ __launch_bounds__(256) void part_hist(const int* __restrict__ dst, int E,
                                                 int chunk, int* __restrict__ bh) {
    __shared__ int h[NB];
    h[threadIdx.x] = 0;
    __syncthreads();
    int beg = blockIdx.x * chunk;
    int end = min(E, beg + chunk);
    for (int i = beg + threadIdx.x; i < end; i += 256)
        atomicAdd(&h[dst[i] >> BSHIFT], 1);
    __syncthreads();
    bh[threadIdx.x * NBLK + blockIdx.x] = h[threadIdx.x];
}

// single block, 256 threads
__global__ void part_scan(int* __restrict__ bh, int* __restrict__ bb, int E) {
    __shared__ int wsum[4];
    int t = threadIdx.x;
    int run = 0;
    for (int blk = 0; blk < NBLK; ++blk) {
        int v = bh[t * NBLK + blk];
        bh[t * NBLK + blk] = run;
        run += v;
    }
    int lane = t & 63, w = t >> 6;
    int incl = run;
#pragma unroll
    for (int off = 1; off < 64; off <<= 1) {
        int u = __shfl_up(incl, off);
        if (lane >= off) incl += u;
    }
    if (lane == 63) wsum[w] = incl;
    __syncthreads();
    int wbase = 0;
#pragma unroll
    for (int i = 0; i < 4; ++i) if (i < w) wbase += wsum[i];
    int base = wbase + incl - run;   // exclusive bucket base
    bb[t] = base;
    if (t == 255) bb[256] = base + run;   // == E
    for (int blk = 0; blk < NBLK; ++blk)
        bh[t * NBLK + blk] += base;
}

__global__ __launch_bounds__(256) void part_scatter(const int* __restrict__ src,
        const int* __restrict__ dst, const float* __restrict__ ew, int E, int chunk,
        const int* __restrict__ bh, uint2* __restrict__ part) {
    __shared__ int ofs[NB];
    ofs[threadIdx.x] = bh[threadIdx.x * NBLK + blockIdx.x];
    __syncthreads();
    int beg = blockIdx.x * chunk;
    int end = min(E, beg + chunk);
    for (int i = beg + threadIdx.x; i < end; i += 256) {
        int d = dst[i];
        int b = d >> BSHIFT;
        int pos = atomicAdd(&ofs[b], 1);
        part[pos] = make_uint2((uint_t)src[i] | ((uint_t)(d & 511) << 20),
                               __float_as_uint(ew[i]));
    }
}

// one block per bucket: LDS fine hist + scan -> rowptr + scatter
__global__ __launch_bounds__(256) void bucket_sort(const uint2* __restrict__ part,
        const int* __restrict__ bb, int* __restrict__ rowptr,
        float2* __restrict__ sorted, int N_) {
    __shared__ int hist[512];
    __shared__ int wsum[4];
    int b = blockIdx.x;
    int t = threadIdx.x;
    int start = bb[b], end = bb[b + 1];
    hist[t] = 0; hist[t + 256] = 0;
    __syncthreads();
    for (int i = start + t; i < end; i += 256)
        atomicAdd(&hist[part[i].x >> 20], 1);
    __syncthreads();
    int v0 = hist[2 * t], v1 = hist[2 * t + 1];
    int pair = v0 + v1;
    int lane = t & 63, w = t >> 6;
    int incl = pair;
#pragma unroll
    for (int off = 1; off < 64; off <<= 1) {
        int u = __shfl_up(incl, off);
        if (lane >= off) incl += u;
    }
    if (lane == 63) wsum[w] = incl;
    __syncthreads();
    int wbase = 0;
#pragma unroll
    for (int i = 0; i < 4; ++i) if (i < w) wbase += wsum[i];
    int excl = wbase + incl - pair;
    __syncthreads();
    hist[2 * t]     = start + excl;
    hist[2 * t + 1] = start + excl + v0;
    int dst0 = (b << BSHIFT) + 2 * t;
    if (dst0 < N_)     rowptr[dst0]     = start + excl + v0;
    if (dst0 + 1 < N_) rowptr[dst0 + 1] = start + excl + v0 + v1;
    __syncthreads();
    for (int i = start + t; i < end; i += 256) {
        uint2 r = part[i];
        int dl = r.x >> 20;
        int s  = r.x & 0xFFFFF;
        int pos = atomicAdd(&hist[dl], 1);
        sorted[pos] = make_float2(__int_as_float(s), __uint_as_float(r.y));
    }
}

// ---------------------------------------------------------------------------
// Fused gather-SpMM + attention combine. One 64-lane wave per node.
// ---------------------------------------------------------------------------
template <int PER, bool FIRST>
__global__ __launch_bounds__(256) void fused_spmm_att(
        const void* __restrict__ selfp, const ushort_t* __restrict__ relft,
        const int* __restrict__ rowptr, const float2* __restrict__ sorted,
        const float* __restrict__ vk, const float* __restrict__ vq,
        const float* __restrict__ bias,
        void* __restrict__ hout, float* __restrict__ attout, int M) {
    int wave = threadIdx.x >> 6;
    int lane = threadIdx.x & 63;
    int n = blockIdx.x * 4 + wave;
    if (n >= M) return;

    float sv[PER], nb[PER];
    if (FIRST) {
        uint_t s2 = ((const uint_t*)selfp)[(size_t)n * 64 + lane];
        sv[0] = bf_lo(s2); sv[1] = bf_hi(s2);
        nb[0] = 0.f; nb[1] = 0.f;
    } else {
        sv[0] = ((const float*)selfp)[(size_t)n * 64 + lane];
        nb[0] = 0.f;
    }

    const int beg = (n > 0) ? rowptr[n - 1] : 0;
    const int end = rowptr[n];
    const uint_t* rel32 = (const uint_t*)relft;

    for (int e = beg; e < end; e += 8) {
        float2 swb[8];
        float  wb[8];
        int    sb[8];
#pragma unroll
        for (int j = 0; j < 8; ++j) {
            int idx = e + j;
            int cl  = idx < end ? idx : end - 1;
            swb[j] = sorted[cl];
            wb[j]  = idx < end ? swb[j].y : 0.f;
            sb[j]  = __float_as_int(swb[j].x);
        }
        if (PER == 2) {
            uint_t vv[8];
#pragma unroll
            for (int j = 0; j < 8; ++j) vv[j] = rel32[(size_t)sb[j] * 64 + lane];
#pragma unroll
            for (int j = 0; j < 8; ++j) {
                nb[0] = fmaf(wb[j], bf_lo(vv[j]), nb[0]);
                nb[1] = fmaf(wb[j], bf_hi(vv[j]), nb[1]);
            }
        } else {
            ushort_t vv[8];
#pragma unroll
            for (int j = 0; j < 8; ++j) vv[j] = relft[(size_t)sb[j] * 64 + lane];
#pragma unroll
            for (int j = 0; j < 8; ++j) nb[0] = fmaf(wb[j], bf_one(vv[j]), nb[0]);
        }
    }

    float vkl[PER], vql[PER], bl[PER];
    if (PER == 2) {
        float2 k2 = ((const float2*)vk)[lane];
        float2 q2 = ((const float2*)vq)[lane];
        float2 b2 = ((const float2*)bias)[lane];
        vkl[0] = k2.x; vkl[1] = k2.y;
        vql[0] = q2.x; vql[1] = q2.y;
        bl[0]  = b2.x; bl[1]  = b2.y;
    } else {
        vkl[0] = vk[lane]; vql[0] = vq[lane]; bl[0] = bias[lane];
    }
    float sk = 0.f, sq = 0.f, nk = 0.f;
#pragma unroll
    for (int i = 0; i < PER; ++i) {
        sk = fmaf(sv[i], vkl[i], sk);
        sq = fmaf(sv[i], vql[i], sq);
        nk = fmaf(nb[i], vkl[i], nk);
    }
#pragma unroll
    for (int off = 32; off; off >>= 1) {
        sk += __shfl_xor(sk, off);
        sq += __shfl_xor(sq, off);
        nk += __shfl_xor(nk, off);
    }
    float e0 = sk + sq;
    float e1 = nk + sq;
    e0 = e0 > 0.f ? e0 : expm1f(e0);
    e1 = e1 > 0.f ? e1 : expm1f(e1);
    float m = fmaxf(e0, e1);
    float a0 = expf(e0 - m);
    float a1 = expf(e1 - m);
    float inv = 1.f / (a0 + a1);
    a0 *= inv; a1 *= inv;

    if (FIRST) {
        float o0 = fmaf(a0, sv[0], fmaf(a1, nb[0], bl[0]));
        float o1 = fmaf(a0, sv[1], fmaf(a1, nb[1], bl[1]));
        o0 = o0 > 0.f ? o0 : expm1f(o0);
        o1 = o1 > 0.f ? o1 : expm1f(o1);
        uint_t packed = (uint_t)bf_bits(o0) | ((uint_t)bf_bits(o1) << 16);
        ((uint_t*)hout)[(size_t)n * 64 + lane] = packed;
    } else {
        float o = fmaf(a0, sv[0], fmaf(a1, nb[0], bl[0]));
        ((float*)hout)[(size_t)n * 64 + lane] = o;
    }
    if (lane == 0) {
        attout[2 * (size_t)n + 0] = a0;
        attout[2 * (size_t)n + 1] = a1;
    }
}

// ---------------------------------------------------------------------------
// Pool: register accumulation over sorted gid, flush on graph change.
// One wave per contiguous node chunk; lane = feature dim.
// ---------------------------------------------------------------------------
__global__ __launch_bounds__(256) void pool_sum_v2(
        const float* __restrict__ h, const int* __restrict__ gid,
        float* __restrict__ sums, float* __restrict__ cnt, int M, int chunk) {
    int wave = threadIdx.x >> 6;
    int lane = threadIdx.x & 63;
    int wid  = blockIdx.x * 4 + wave;
    int beg  = wid * chunk;
    int end  = min(M, beg + chunk);
    if (beg >= end) return;

    int   cur_g = gid[beg];
    float acc   = 0.f;
    int   cl    = 0;
    for (int n = beg; n < end; ++n) {
        int g = gid[n];
        if (g != cur_g) {
            atomicAdd(&sums[(size_t)cur_g * D_OUT + lane], acc);
            if (lane == 0) atomicAdd(&cnt[cur_g], (float)cl);
            cur_g = g; acc = 0.f; cl = 0;
        }
        acc += h[(size_t)n * D_OUT + lane];
        ++cl;
    }
    atomicAdd(&sums[(size_t)cur_g * D_OUT + lane], acc);
    if (lane == 0) atomicAdd(&cnt[cur_g], (float)cl);
}

__global__ void pool_mlp(const float* __restrict__ sums, const float* __restrict__ cnt,
                         const float* __restrict__ w1, const float* __restrict__ b1,
                         const float* __restrict__ w2, const float* __restrict__ b2,
                         float* __restrict__ out) {
    int g = threadIdx.x;
    if (g >= NG) return;
    float c = fmaxf(cnt[g], 1.0f);
    float inv = 1.0f / c;
    float hg[D_OUT];
#pragma unroll
    for (int d = 0; d < D_OUT; ++d) hg[d] = sums[g * D_OUT + d] * inv;
    float acc = b2[0];
    for (int j = 0; j < D_OUT / 2; ++j) {
        float hid = b1[j];
#pragma unroll 8
        for (int d = 0; d < D_OUT; ++d) hid = fmaf(hg[d], w1[d * (D_OUT / 2) + j], hid);
        hid = fmaxf(hid, 0.f);
        acc = fmaf(hid, w2[j], acc);
    }
    out[g] = acc;
}

// ---------------------------------------------------------------------------
extern "C" void kernel_launch(void* const* d_in, const int* in_sizes, int n_in,
                              void* d_out, int out_size, void* d_ws, size_t ws_size,
                              hipStream_t stream) {
    const float* x       = (const float*)d_in[0];
    const int*   esrc    = (const int*)  d_in[1];
    const int*   edst    = (const int*)  d_in[2];
    const float* ew      = (const float*)d_in[3];
    const int*   gid     = (const int*)  d_in[4];
    const float* w_self1 = (const float*)d_in[5];
    const float* w_rel1  = (const float*)d_in[6];
    const float* bias1   = (const float*)d_in[7];
    const float* w_q1    = (const float*)d_in[8];
    const float* w_k1    = (const float*)d_in[9];
    const float* w_att1  = (const float*)d_in[10];
    const float* w_self2 = (const float*)d_in[11];
    const float* w_rel2  = (const float*)d_in[12];
    const float* bias2   = (const float*)d_in[13];
    const float* w_q2    = (const float*)d_in[14];
    const float* w_k2    = (const float*)d_in[15];
    const float* w_att2  = (const float*)d_in[16];
    const float* mlp_w1  = (const float*)d_in[17];
    const float* mlp_b1  = (const float*)d_in[18];
    const float* mlp_w2  = (const float*)d_in[19];
    const float* mlp_b2  = (const float*)d_in[20];

    const int N = in_sizes[0] / D_IN;
    const int E = in_sizes[1];

    float* out = (float*)d_out;
    float* out_embd = out;
    float* out_att1 = out + NG;
    float* out_att2 = out + NG + 2 * (size_t)N;

    // ---- Workspace layout (float units) ----
    float* ws = (float*)d_ws;
    size_t nf = (size_t)N;
    float* bufS = ws;                  // selfft1 bf16 (Nx128) -> selfft2 fp32 (Nx64)
    float* bufR = ws + nf * 64;        // relft1 bf16 (Nx128) -> relft2 bf16 (Nx64)
    float* bufH = ws + nf * 128;       // part[] during sort -> h1 bf16 -> h2 fp32
    uint2* part = (uint2*)bufH;        // E uint2, dead before fused1
    int* ip     = (int*)(ws + nf * 192);
    int* rowptr = ip;                  // N
    int* bb     = ip + N;              // 257
    int* bh     = ip + N + 257;        // NB*NBLK = 65536
    size_t int_end = nf * 192 + nf + 257 + (size_t)NB * NBLK;
    int_end = (int_end + 1) & ~(size_t)1;
    float2* sorted = (float2*)(ws + int_end);     // E float2
    float* small = ws + int_end + 2 * (size_t)E;
    float* vk1 = small + 0;
    float* vq1 = small + 128;
    float* vk2 = small + 256;
    float* vq2 = small + 320;
    float* sums = small + 384;
    float* cnt  = small + 384 + NG * D_OUT;
    ushort_t* wtb = (ushort_t*)(small + 384 + NG * D_OUT + NG);
    ushort_t* wt_s1 = wtb;
    ushort_t* wt_r1 = wtb + 16384;
    ushort_t* wt_s2 = wtb + 32768;
    ushort_t* wt_r2 = wtb + 40960;

    hipMemsetAsync(sums, 0, (NG * D_OUT + NG) * sizeof(float), stream);

    prep_wt<<<192, 256, 0, stream>>>(w_self1, w_rel1, w_self2, w_rel2, wtb);
    prep_att_vecs<<<2, 256, 0, stream>>>(w_q1, w_k1, w_att1, w_q2, w_k2, w_att2, small);

    // ---- Edge sort (two-level counting sort, shared by both layers) ----
    const int chunk = (E + NBLK - 1) / NBLK;
    const int nbuck = (N + (1 << BSHIFT) - 1) >> BSHIFT;
    part_hist<<<NBLK, 256, 0, stream>>>(edst, E, chunk, bh);
    part_scan<<<1, 256, 0, stream>>>(bh, bb, E);
    part_scatter<<<NBLK, 256, 0, stream>>>(esrc, edst, ew, E, chunk, bh, part);
    bucket_sort<<<nbuck, 256, 0, stream>>>(part, bb, rowptr, sorted, N);

    // ---- Layer 1 ----
    {
        dim3 grid((N + 63) / 64, 1, 2);
        gemm_mfma<128, true, true><<<grid, 256, 0, stream>>>(
            x, N, wt_s1, wt_r1, (void*)bufS, (ushort_t*)bufR);
    }
    fused_spmm_att<2, true><<<(N + 3) / 4, 256, 0, stream>>>(
        (const void*)bufS, (const ushort_t*)bufR, rowptr, sorted,
        vk1, vq1, bias1, (void*)bufH, out_att1, N);

    // ---- Layer 2 ----
    {
        dim3 grid((N + 63) / 64, 1, 2);
        gemm_mfma<64, false, false><<<grid, 256, 0, stream>>>(
            (const void*)bufH, N, wt_s2, wt_r2, (void*)bufS, (ushort_t*)bufR);
    }
    fused_spmm_att<1, false><<<(N + 3) / 4, 256, 0, stream>>>(
        (const void*)bufS, (const ushort_t*)bufR, rowptr, sorted,
        vk2, vq2, bias2, (void*)bufH, out_att2, N);

    // ---- Pool + MLP ----
    {
        int pblocks = 1024;
        int pchunk  = (N + pblocks * 4 - 1) / (pblocks * 4);
        pool_sum_v2<<<pblocks, 256, 0, stream>>>(bufH, gid, sums, cnt, N, pchunk);
    }
    pool_mlp<<<1, 64, 0, stream>>>(sums, cnt, mlp_w1, mlp_b1, mlp_w2, mlp_b2, out_embd);
}

// Round 7
// 349.814 us; speedup vs baseline: 12.6222x; 1.0223x over previous
//
#include <hip/hip_runtime.h>
#include <hip/hip_bf16.h>
#include <cstdint>
#include <cstddef>

static constexpr int D_IN  = 128;
static constexpr int D_HID = 128;
static constexpr int D_OUT = 64;
static constexpr int ATTD  = 64;
static constexpr int NG    = 64;
static constexpr int NB    = 256;   // coarse buckets (dst >> 9)
static constexpr int NBLK  = 256;   // partition blocks
static constexpr int BSHIFT = 9;    // 512 dst per bucket

typedef __attribute__((ext_vector_type(8))) short s16x8;
typedef __attribute__((ext_vector_type(4))) float f32x4;
typedef unsigned short ushort_t;
typedef unsigned int uint_t;

__device__ __forceinline__ unsigned short bf_bits(float f) {
    union { __hip_bfloat16 h; unsigned short u; } cv;
    cv.h = __float2bfloat16(f);
    return cv.u;
}
__device__ __forceinline__ float bf_lo(uint_t v) { return __uint_as_float(v << 16); }
__device__ __forceinline__ float bf_hi(uint_t v) { return __uint_as_float(v & 0xffff0000u); }

// ---------------------------------------------------------------------------
// Weight prep: WT[c*128 + k] = bf16(W[k*C + c]) for the 4 GEMM weight matrices.
// ---------------------------------------------------------------------------
__global__ void prep_wt(const float* __restrict__ w_self1, const float* __restrict__ w_rel1,
                        const float* __restrict__ w_self2, const float* __restrict__ w_rel2,
                        ushort_t* __restrict__ wt) {
    int idx = blockIdx.x * 256 + threadIdx.x;
    if (idx >= 49152) return;
    const float* src; int base, Cc;
    if (idx < 16384)      { src = w_self1; base = 0;     Cc = 128; }
    else if (idx < 32768) { src = w_rel1;  base = 16384; Cc = 128; }
    else if (idx < 40960) { src = w_self2; base = 32768; Cc = 64;  }
    else                  { src = w_rel2;  base = 40960; Cc = 64;  }
    int l = idx - base;
    int c = l >> 7;
    int k = l & 127;
    wt[base + l] = bf_bits(src[k * Cc + c]);
}

// ---------------------------------------------------------------------------
// v_k = w_k @ a[:ATT], v_q = w_q @ a[ATT:] for both layers (fp32).
// ---------------------------------------------------------------------------
__global__ void prep_att_vecs(const float* __restrict__ w_q1, const float* __restrict__ w_k1,
                              const float* __restrict__ w_att1,
                              const float* __restrict__ w_q2, const float* __restrict__ w_k2,
                              const float* __restrict__ w_att2,
                              float* __restrict__ small) {
    int idx = blockIdx.x * blockDim.x + threadIdx.x;
    if (idx >= 384) return;
    float acc = 0.f;
    if (idx < 128) {
        int d = idx;
        for (int a = 0; a < ATTD; ++a) acc += w_k1[d * ATTD + a] * w_att1[a];
        small[0 + d] = acc;
    } else if (idx < 256) {
        int d = idx - 128;
        for (int a = 0; a < ATTD; ++a) acc += w_q1[d * ATTD + a] * w_att1[ATTD + a];
        small[128 + d] = acc;
    } else if (idx < 320) {
        int d = idx - 256;
        for (int a = 0; a < ATTD; ++a) acc += w_k2[d * ATTD + a] * w_att2[a];
        small[256 + d] = acc;
    } else {
        int d = idx - 320;
        for (int a = 0; a < ATTD; ++a) acc += w_q2[d * ATTD + a] * w_att2[ATTD + a];
        small[320 + d] = acc;
    }
}

// ---------------------------------------------------------------------------
// MFMA bf16 dual GEMM (verified).
// ---------------------------------------------------------------------------
template <int C, bool A32, bool OA_BF>
__global__ __launch_bounds__(256) void gemm_mfma(
        const void* __restrict__ A, int M,
        const ushort_t* __restrict__ WTa, const ushort_t* __restrict__ WTb,
        void* __restrict__ Oa, ushort_t* __restrict__ Ob) {
    constexpr int K = 128;
    constexpr int RS = K + 8;
    __shared__ ushort_t wt[C * RS];

    const ushort_t* WT = blockIdx.z ? WTb : WTa;
    for (int idx = threadIdx.x; idx < C * (K / 8); idx += 256) {
        int c  = idx / (K / 8);
        int kc = idx % (K / 8);
        *(uint4*)&wt[c * RS + kc * 8] = *(const uint4*)&WT[c * K + kc * 8];
    }
    __syncthreads();

    const int w    = threadIdx.x >> 6;
    const int lane = threadIdx.x & 63;
    const int row  = blockIdx.x * 64 + w * 16 + (lane & 15);
    const int rowc = row < M ? row : (M - 1);
    const int kb   = (lane >> 4) * 8;

    s16x8 afr[4];
    if (A32) {
        const float* Af = (const float*)A + (size_t)rowc * K + kb;
#pragma unroll
        for (int ks = 0; ks < 4; ++ks) {
            float4 f0 = *(const float4*)(Af + ks * 32);
            float4 f1 = *(const float4*)(Af + ks * 32 + 4);
            s16x8 a;
            a[0] = (short)bf_bits(f0.x); a[1] = (short)bf_bits(f0.y);
            a[2] = (short)bf_bits(f0.z); a[3] = (short)bf_bits(f0.w);
            a[4] = (short)bf_bits(f1.x); a[5] = (short)bf_bits(f1.y);
            a[6] = (short)bf_bits(f1.z); a[7] = (short)bf_bits(f1.w);
            afr[ks] = a;
        }
    } else {
        const ushort_t* Ab = (const ushort_t*)A + (size_t)rowc * K + kb;
#pragma unroll
        for (int ks = 0; ks < 4; ++ks) afr[ks] = *(const s16x8*)(Ab + ks * 32);
    }

    const int colc = lane & 15;
    const int r0   = blockIdx.x * 64 + w * 16 + (lane >> 4) * 4;

#pragma unroll
    for (int ct = 0; ct < C / 16; ++ct) {
        f32x4 acc = {0.f, 0.f, 0.f, 0.f};
        const int colb = ct * 16 + colc;
#pragma unroll
        for (int ks = 0; ks < 4; ++ks) {
            s16x8 b = *(const s16x8*)&wt[colb * RS + ks * 32 + kb];
            acc = __builtin_amdgcn_mfma_f32_16x16x32_bf16(afr[ks], b, acc, 0, 0, 0);
        }
        if (blockIdx.z == 0) {
            if (OA_BF) {
                ushort_t* O = (ushort_t*)Oa;
#pragma unroll
                for (int j = 0; j < 4; ++j)
                    if (r0 + j < M) O[(size_t)(r0 + j) * C + colb] = bf_bits(acc[j]);
            } else {
                float* O = (float*)Oa;
#pragma unroll
                for (int j = 0; j < 4; ++j)
                    if (r0 + j < M) O[(size_t)(r0 + j) * C + colb] = acc[j];
            }
        } else {
#pragma unroll
            for (int j = 0; j < 4; ++j)
                if (r0 + j < M) Ob[(size_t)(r0 + j) * C + colb] = bf_bits(acc[j]);
        }
    }
}

// ---------------------------------------------------------------------------
// Two-level counting sort of edges by dst.
// ---------------------------------------------------------------------------
__global__ __launch_bounds__(256) void part_hist(const int* __restrict__ dst, int E,
                                                 int chunk, int* __restrict__ bh) {
    __shared__ int h[NB];
    h[threadIdx.x] = 0;
    __syncthreads();
    int beg = blockIdx.x * chunk;
    int end = min(E, beg + chunk);
    for (int i = beg + threadIdx.x; i < end; i += 256)
        atomicAdd(&h[dst[i] >> BSHIFT], 1);
    __syncthreads();
    bh[threadIdx.x * NBLK + blockIdx.x] = h[threadIdx.x];
}

// single block, 256 threads
__global__ void part_scan(int* __restrict__ bh, int* __restrict__ bb, int E) {
    __shared__ int wsum[4];
    int t = threadIdx.x;
    int run = 0;
    for (int blk = 0; blk < NBLK; ++blk) {
        int v = bh[t * NBLK + blk];
        bh[t * NBLK + blk] = run;
        run += v;
    }
    int lane = t & 63, w = t >> 6;
    int incl = run;
#pragma unroll
    for (int off = 1; off < 64; off <<= 1) {
        int u = __shfl_up(incl, off);
        if (lane >= off) incl += u;
    }
    if (lane == 63) wsum[w] = incl;
    __syncthreads();
    int wbase = 0;
#pragma unroll
    for (int i = 0; i < 4; ++i) if (i < w) wbase += wsum[i];
    int base = wbase + incl - run;   // exclusive bucket base
    bb[t] = base;
    if (t == 255) bb[256] = base + run;   // == E
    for (int blk = 0; blk < NBLK; ++blk)
        bh[t * NBLK + blk] += base;
}

__global__ __launch_bounds__(256) void part_scatter(const int* __restrict__ src,
        const int* __restrict__ dst, const float* __restrict__ ew, int E, int chunk,
        const int* __restrict__ bh, uint2* __restrict__ part) {
    __shared__ int ofs[NB];
    ofs[threadIdx.x] = bh[threadIdx.x * NBLK + blockIdx.x];
    __syncthreads();
    int beg = blockIdx.x * chunk;
    int end = min(E, beg + chunk);
    for (int i = beg + threadIdx.x; i < end; i += 256) {
        int d = dst[i];
        int b = d >> BSHIFT;
        int pos = atomicAdd(&ofs[b], 1);
        part[pos] = make_uint2((uint_t)src[i] | ((uint_t)(d & 511) << 20),
                               __float_as_uint(ew[i]));
    }
}

// one block per bucket: LDS fine hist + scan -> rowptr + scatter
__global__ __launch_bounds__(256) void bucket_sort(const uint2* __restrict__ part,
        const int* __restrict__ bb, int* __restrict__ rowptr,
        float2* __restrict__ sorted, int N_) {
    __shared__ int hist[512];
    __shared__ int wsum[4];
    int b = blockIdx.x;
    int t = threadIdx.x;
    int start = bb[b], end = bb[b + 1];
    hist[t] = 0; hist[t + 256] = 0;
    __syncthreads();
    for (int i = start + t; i < end; i += 256)
        atomicAdd(&hist[part[i].x >> 20], 1);
    __syncthreads();
    int v0 = hist[2 * t], v1 = hist[2 * t + 1];
    int pair = v0 + v1;
    int lane = t & 63, w = t >> 6;
    int incl = pair;
#pragma unroll
    for (int off = 1; off < 64; off <<= 1) {
        int u = __shfl_up(incl, off);
        if (lane >= off) incl += u;
    }
    if (lane == 63) wsum[w] = incl;
    __syncthreads();
    int wbase = 0;
#pragma unroll
    for (int i = 0; i < 4; ++i) if (i < w) wbase += wsum[i];
    int excl = wbase + incl - pair;
    __syncthreads();
    hist[2 * t]     = start + excl;
    hist[2 * t + 1] = start + excl + v0;
    int dst0 = (b << BSHIFT) + 2 * t;
    if (dst0 < N_)     rowptr[dst0]     = start + excl + v0;
    if (dst0 + 1 < N_) rowptr[dst0 + 1] = start + excl + v0 + v1;
    __syncthreads();
    for (int i = start + t; i < end; i += 256) {
        uint2 r = part[i];
        int dl = r.x >> 20;
        int s  = r.x & 0xFFFFF;
        int pos = atomicAdd(&hist[dl], 1);
        sorted[pos] = make_float2(__int_as_float(s), __uint_as_float(r.y));
    }
}

// ---------------------------------------------------------------------------
// Fused gather-SpMM + attention, layer 1 (D=128).
// Quarter-wave edge parallelism: 4 edges in flight, 16 lanes x 8 feats each.
// selfft bf16 in, h out bf16 + elu.
// ---------------------------------------------------------------------------
__global__ __launch_bounds__(256) void fused1(
        const uint_t* __restrict__ selfp, const ushort_t* __restrict__ relft,
        const int* __restrict__ rowptr, const float2* __restrict__ sorted,
        const float* __restrict__ vk, const float* __restrict__ vq,
        const float* __restrict__ bias,
        uint_t* __restrict__ hout, float* __restrict__ attout, int M) {
    int wave = threadIdx.x >> 6;
    int lane = threadIdx.x & 63;
    int n = blockIdx.x * 4 + wave;
    if (n >= M) return;
    const int q  = lane >> 4;        // edge slot 0..3
    const int fl = lane & 15;        // feat group: feats 8*fl .. 8*fl+7

    // self features (8 per lane, duplicated across quarters)
    uint4 s4 = *(const uint4*)(selfp + (size_t)n * 64 + fl * 4);
    float sv[8] = { bf_lo(s4.x), bf_hi(s4.x), bf_lo(s4.y), bf_hi(s4.y),
                    bf_lo(s4.z), bf_hi(s4.z), bf_lo(s4.w), bf_hi(s4.w) };
    float nb[8] = {0,0,0,0,0,0,0,0};

    const int beg = (n > 0) ? rowptr[n - 1] : 0;
    const int end = rowptr[n];
    const int len = end - beg;
    const char* base = (const char*)relft;
    const uint_t flb = (uint_t)fl << 4;   // fl*16 bytes

    int e = beg;
    const int efull = beg + (len & ~7);
    for (; e < efull; e += 8) {
        float2 swa = sorted[e + q];
        float2 swb = sorted[e + 4 + q];
        uint_t offa = ((uint_t)__float_as_uint(swa.x) << 8) | flb;
        uint_t offb = ((uint_t)__float_as_uint(swb.x) << 8) | flb;
        uint4 va = *(const uint4*)(base + offa);
        uint4 vb = *(const uint4*)(base + offb);
        float wa = swa.y, wb = swb.y;
        nb[0] = fmaf(wa, bf_lo(va.x), nb[0]); nb[1] = fmaf(wa, bf_hi(va.x), nb[1]);
        nb[2] = fmaf(wa, bf_lo(va.y), nb[2]); nb[3] = fmaf(wa, bf_hi(va.y), nb[3]);
        nb[4] = fmaf(wa, bf_lo(va.z), nb[4]); nb[5] = fmaf(wa, bf_hi(va.z), nb[5]);
        nb[6] = fmaf(wa, bf_lo(va.w), nb[6]); nb[7] = fmaf(wa, bf_hi(va.w), nb[7]);
        nb[0] = fmaf(wb, bf_lo(vb.x), nb[0]); nb[1] = fmaf(wb, bf_hi(vb.x), nb[1]);
        nb[2] = fmaf(wb, bf_lo(vb.y), nb[2]); nb[3] = fmaf(wb, bf_hi(vb.y), nb[3]);
        nb[4] = fmaf(wb, bf_lo(vb.z), nb[4]); nb[5] = fmaf(wb, bf_hi(vb.z), nb[5]);
        nb[6] = fmaf(wb, bf_lo(vb.w), nb[6]); nb[7] = fmaf(wb, bf_hi(vb.w), nb[7]);
    }
    if (e < end) {   // masked tail block (1..7 edges)
        int ia = e + q, ib = e + 4 + q;
        int ca = ia < end ? ia : e;
        int cb = ib < end ? ib : e;
        float2 swa = sorted[ca];
        float2 swb = sorted[cb];
        float wa = ia < end ? swa.y : 0.f;
        float wb = ib < end ? swb.y : 0.f;
        uint_t offa = ((uint_t)__float_as_uint(swa.x) << 8) | flb;
        uint_t offb = ((uint_t)__float_as_uint(swb.x) << 8) | flb;
        uint4 va = *(const uint4*)(base + offa);
        uint4 vb = *(const uint4*)(base + offb);
        nb[0] = fmaf(wa, bf_lo(va.x), nb[0]); nb[1] = fmaf(wa, bf_hi(va.x), nb[1]);
        nb[2] = fmaf(wa, bf_lo(va.y), nb[2]); nb[3] = fmaf(wa, bf_hi(va.y), nb[3]);
        nb[4] = fmaf(wa, bf_lo(va.z), nb[4]); nb[5] = fmaf(wa, bf_hi(va.z), nb[5]);
        nb[6] = fmaf(wa, bf_lo(va.w), nb[6]); nb[7] = fmaf(wa, bf_hi(va.w), nb[7]);
        nb[0] = fmaf(wb, bf_lo(vb.x), nb[0]); nb[1] = fmaf(wb, bf_hi(vb.x), nb[1]);
        nb[2] = fmaf(wb, bf_lo(vb.y), nb[2]); nb[3] = fmaf(wb, bf_hi(vb.y), nb[3]);
        nb[4] = fmaf(wb, bf_lo(vb.z), nb[4]); nb[5] = fmaf(wb, bf_hi(vb.z), nb[5]);
        nb[6] = fmaf(wb, bf_lo(vb.w), nb[6]); nb[7] = fmaf(wb, bf_hi(vb.w), nb[7]);
    }

    // combine edge-quarters
#pragma unroll
    for (int i = 0; i < 8; ++i) {
        nb[i] += __shfl_xor(nb[i], 16);
        nb[i] += __shfl_xor(nb[i], 32);
    }

    // attention (per-quarter complete: 16 lanes x 8 feats = 128)
    float4 k0 = *(const float4*)(vk + fl * 8), k1 = *(const float4*)(vk + fl * 8 + 4);
    float4 q0 = *(const float4*)(vq + fl * 8), q1 = *(const float4*)(vq + fl * 8 + 4);
    float kk[8] = {k0.x,k0.y,k0.z,k0.w,k1.x,k1.y,k1.z,k1.w};
    float qq[8] = {q0.x,q0.y,q0.z,q0.w,q1.x,q1.y,q1.z,q1.w};
    float sk = 0.f, sq = 0.f, nk = 0.f;
#pragma unroll
    for (int i = 0; i < 8; ++i) {
        sk = fmaf(sv[i], kk[i], sk);
        sq = fmaf(sv[i], qq[i], sq);
        nk = fmaf(nb[i], kk[i], nk);
    }
#pragma unroll
    for (int off = 8; off; off >>= 1) {
        sk += __shfl_xor(sk, off);
        sq += __shfl_xor(sq, off);
        nk += __shfl_xor(nk, off);
    }
    float e0 = sk + sq;
    float e1 = nk + sq;
    e0 = e0 > 0.f ? e0 : expm1f(e0);
    e1 = e1 > 0.f ? e1 : expm1f(e1);
    float m = fmaxf(e0, e1);
    float a0 = expf(e0 - m);
    float a1 = expf(e1 - m);
    float inv = 1.f / (a0 + a1);
    a0 *= inv; a1 *= inv;

    if (lane < 16) {
        float4 b0 = *(const float4*)(bias + fl * 8), b1 = *(const float4*)(bias + fl * 8 + 4);
        float bb[8] = {b0.x,b0.y,b0.z,b0.w,b1.x,b1.y,b1.z,b1.w};
        uint_t od[4];
#pragma unroll
        for (int i = 0; i < 4; ++i) {
            float o0 = fmaf(a0, sv[2*i],   fmaf(a1, nb[2*i],   bb[2*i]));
            float o1 = fmaf(a0, sv[2*i+1], fmaf(a1, nb[2*i+1], bb[2*i+1]));
            o0 = o0 > 0.f ? o0 : expm1f(o0);
            o1 = o1 > 0.f ? o1 : expm1f(o1);
            od[i] = (uint_t)bf_bits(o0) | ((uint_t)bf_bits(o1) << 16);
        }
        *(uint4*)(hout + (size_t)n * 64 + fl * 4) = make_uint4(od[0], od[1], od[2], od[3]);
    }
    if (lane == 0) {
        attout[2 * (size_t)n + 0] = a0;
        attout[2 * (size_t)n + 1] = a1;
    }
}

// ---------------------------------------------------------------------------
// Fused gather-SpMM + attention, layer 2 (D=64).
// Quarter-wave: 4 edges, 16 lanes x 4 feats. selfft fp32 in, h out fp32.
// ---------------------------------------------------------------------------
__global__ __launch_bounds__(256) void fused2(
        const float* __restrict__ selfp, const ushort_t* __restrict__ relft,
        const int* __restrict__ rowptr, const float2* __restrict__ sorted,
        const float* __restrict__ vk, const float* __restrict__ vq,
        const float* __restrict__ bias,
        float* __restrict__ hout, float* __restrict__ attout, int M) {
    int wave = threadIdx.x >> 6;
    int lane = threadIdx.x & 63;
    int n = blockIdx.x * 4 + wave;
    if (n >= M) return;
    const int q  = lane >> 4;
    const int fl = lane & 15;        // feats 4*fl .. 4*fl+3

    float4 s4 = *(const float4*)(selfp + (size_t)n * 64 + fl * 4);
    float sv[4] = {s4.x, s4.y, s4.z, s4.w};
    float nb[4] = {0,0,0,0};

    const int beg = (n > 0) ? rowptr[n - 1] : 0;
    const int end = rowptr[n];
    const int len = end - beg;
    const char* base = (const char*)relft;
    const uint_t flb = (uint_t)fl << 3;   // fl*8 bytes

    int e = beg;
    const int efull = beg + (len & ~7);
    for (; e < efull; e += 8) {
        float2 swa = sorted[e + q];
        float2 swb = sorted[e + 4 + q];
        uint_t offa = ((uint_t)__float_as_uint(swa.x) << 7) | flb;
        uint_t offb = ((uint_t)__float_as_uint(swb.x) << 7) | flb;
        uint2 va = *(const uint2*)(base + offa);
        uint2 vb = *(const uint2*)(base + offb);
        float wa = swa.y, wb = swb.y;
        nb[0] = fmaf(wa, bf_lo(va.x), nb[0]); nb[1] = fmaf(wa, bf_hi(va.x), nb[1]);
        nb[2] = fmaf(wa, bf_lo(va.y), nb[2]); nb[3] = fmaf(wa, bf_hi(va.y), nb[3]);
        nb[0] = fmaf(wb, bf_lo(vb.x), nb[0]); nb[1] = fmaf(wb, bf_hi(vb.x), nb[1]);
        nb[2] = fmaf(wb, bf_lo(vb.y), nb[2]); nb[3] = fmaf(wb, bf_hi(vb.y), nb[3]);
    }
    if (e < end) {
        int ia = e + q, ib = e + 4 + q;
        int ca = ia < end ? ia : e;
        int cb = ib < end ? ib : e;
        float2 swa = sorted[ca];
        float2 swb = sorted[cb];
        float wa = ia < end ? swa.y : 0.f;
        float wb = ib < end ? swb.y : 0.f;
        uint_t offa = ((uint_t)__float_as_uint(swa.x) << 7) | flb;
        uint_t offb = ((uint_t)__float_as_uint(swb.x) << 7) | flb;
        uint2 va = *(const uint2*)(base + offa);
        uint2 vb = *(const uint2*)(base + offb);
        nb[0] = fmaf(wa, bf_lo(va.x), nb[0]); nb[1] = fmaf(wa, bf_hi(va.x), nb[1]);
        nb[2] = fmaf(wa, bf_lo(va.y), nb[2]); nb[3] = fmaf(wa, bf_hi(va.y), nb[3]);
        nb[0] = fmaf(wb, bf_lo(vb.x), nb[0]); nb[1] = fmaf(wb, bf_hi(vb.x), nb[1]);
        nb[2] = fmaf(wb, bf_lo(vb.y), nb[2]); nb[3] = fmaf(wb, bf_hi(vb.y), nb[3]);
    }

#pragma unroll
    for (int i = 0; i < 4; ++i) {
        nb[i] += __shfl_xor(nb[i], 16);
        nb[i] += __shfl_xor(nb[i], 32);
    }

    float4 k4 = *(const float4*)(vk + fl * 4);
    float4 q4 = *(const float4*)(vq + fl * 4);
    float kk[4] = {k4.x,k4.y,k4.z,k4.w};
    float qq[4] = {q4.x,q4.y,q4.z,q4.w};
    float sk = 0.f, sq = 0.f, nk = 0.f;
#pragma unroll
    for (int i = 0; i < 4; ++i) {
        sk = fmaf(sv[i], kk[i], sk);
        sq = fmaf(sv[i], qq[i], sq);
        nk = fmaf(nb[i], kk[i], nk);
    }
#pragma unroll
    for (int off = 8; off; off >>= 1) {
        sk += __shfl_xor(sk, off);
        sq += __shfl_xor(sq, off);
        nk += __shfl_xor(nk, off);
    }
    float e0 = sk + sq;
    float e1 = nk + sq;
    e0 = e0 > 0.f ? e0 : expm1f(e0);
    e1 = e1 > 0.f ? e1 : expm1f(e1);
    float m = fmaxf(e0, e1);
    float a0 = expf(e0 - m);
    float a1 = expf(e1 - m);
    float inv = 1.f / (a0 + a1);
    a0 *= inv; a1 *= inv;

    if (lane < 16) {
        float4 b4 = *(const float4*)(bias + fl * 4);
        float bb[4] = {b4.x,b4.y,b4.z,b4.w};
        float4 o;
        o.x = fmaf(a0, sv[0], fmaf(a1, nb[0], bb[0]));
        o.y = fmaf(a0, sv[1], fmaf(a1, nb[1], bb[1]));
        o.z = fmaf(a0, sv[2], fmaf(a1, nb[2], bb[2]));
        o.w = fmaf(a0, sv[3], fmaf(a1, nb[3], bb[3]));
        *(float4*)(hout + (size_t)n * 64 + fl * 4) = o;
    }
    if (lane == 0) {
        attout[2 * (size_t)n + 0] = a0;
        attout[2 * (size_t)n + 1] = a1;
    }
}

// ---------------------------------------------------------------------------
// Pool: register accumulation over sorted gid, flush on graph change.
// ---------------------------------------------------------------------------
__global__ __launch_bounds__(256) void pool_sum_v2(
        const float* __restrict__ h, const int* __restrict__ gid,
        float* __restrict__ sums, float* __restrict__ cnt, int M, int chunk) {
    int wave = threadIdx.x >> 6;
    int lane = threadIdx.x & 63;
    int wid  = blockIdx.x * 4 + wave;
    int beg  = wid * chunk;
    int end  = min(M, beg + chunk);
    if (beg >= end) return;

    int   cur_g = gid[beg];
    float acc   = 0.f;
    int   cl    = 0;
    for (int n = beg; n < end; ++n) {
        int g = gid[n];
        if (g != cur_g) {
            atomicAdd(&sums[(size_t)cur_g * D_OUT + lane], acc);
            if (lane == 0) atomicAdd(&cnt[cur_g], (float)cl);
            cur_g = g; acc = 0.f; cl = 0;
        }
        acc += h[(size_t)n * D_OUT + lane];
        ++cl;
    }
    atomicAdd(&sums[(size_t)cur_g * D_OUT + lane], acc);
    if (lane == 0) atomicAdd(&cnt[cur_g], (float)cl);
}

__global__ void pool_mlp(const float* __restrict__ sums, const float* __restrict__ cnt,
                         const float* __restrict__ w1, const float* __restrict__ b1,
                         const float* __restrict__ w2, const float* __restrict__ b2,
                         float* __restrict__ out) {
    int g = threadIdx.x;
    if (g >= NG) return;
    float c = fmaxf(cnt[g], 1.0f);
    float inv = 1.0f / c;
    float hg[D_OUT];
#pragma unroll
    for (int d = 0; d < D_OUT; ++d) hg[d] = sums[g * D_OUT + d] * inv;
    float acc = b2[0];
    for (int j = 0; j < D_OUT / 2; ++j) {
        float hid = b1[j];
#pragma unroll 8
        for (int d = 0; d < D_OUT; ++d) hid = fmaf(hg[d], w1[d * (D_OUT / 2) + j], hid);
        hid = fmaxf(hid, 0.f);
        acc = fmaf(hid, w2[j], acc);
    }
    out[g] = acc;
}

// ---------------------------------------------------------------------------
extern "C" void kernel_launch(void* const* d_in, const int* in_sizes, int n_in,
                              void* d_out, int out_size, void* d_ws, size_t ws_size,
                              hipStream_t stream) {
    const float* x       = (const float*)d_in[0];
    const int*   esrc    = (const int*)  d_in[1];
    const int*   edst    = (const int*)  d_in[2];
    const float* ew      = (const float*)d_in[3];
    const int*   gid     = (const int*)  d_in[4];
    const float* w_self1 = (const float*)d_in[5];
    const float* w_rel1  = (const float*)d_in[6];
    const float* bias1   = (const float*)d_in[7];
    const float* w_q1    = (const float*)d_in[8];
    const float* w_k1    = (const float*)d_in[9];
    const float* w_att1  = (const float*)d_in[10];
    const float* w_self2 = (const float*)d_in[11];
    const float* w_rel2  = (const float*)d_in[12];
    const float* bias2   = (const float*)d_in[13];
    const float* w_q2    = (const float*)d_in[14];
    const float* w_k2    = (const float*)d_in[15];
    const float* w_att2  = (const float*)d_in[16];
    const float* mlp_w1  = (const float*)d_in[17];
    const float* mlp_b1  = (const float*)d_in[18];
    const float* mlp_w2  = (const float*)d_in[19];
    const float* mlp_b2  = (const float*)d_in[20];

    const int N = in_sizes[0] / D_IN;
    const int E = in_sizes[1];

    float* out = (float*)d_out;
    float* out_embd = out;
    float* out_att1 = out + NG;
    float* out_att2 = out + NG + 2 * (size_t)N;

    // ---- Workspace layout (float units) ----
    float* ws = (float*)d_ws;
    size_t nf = (size_t)N;
    float* bufS = ws;                  // selfft1 bf16 (Nx128) -> selfft2 fp32 (Nx64)
    float* bufR = ws + nf * 64;        // relft1 bf16 (Nx128) -> relft2 bf16 (Nx64)
    float* bufH = ws + nf * 128;       // part[] during sort -> h1 bf16 -> h2 fp32
    uint2* part = (uint2*)bufH;        // E uint2, dead before fused1
    int* ip     = (int*)(ws + nf * 192);
    int* rowptr = ip;                  // N
    int* bb     = ip + N;              // 257
    int* bh     = ip + N + 257;        // NB*NBLK = 65536
    size_t int_end = nf * 192 + nf + 257 + (size_t)NB * NBLK;
    int_end = (int_end + 1) & ~(size_t)1;
    float2* sorted = (float2*)(ws + int_end);     // E float2
    float* small = ws + int_end + 2 * (size_t)E;
    float* vk1 = small + 0;
    float* vq1 = small + 128;
    float* vk2 = small + 256;
    float* vq2 = small + 320;
    float* sums = small + 384;
    float* cnt  = small + 384 + NG * D_OUT;
    ushort_t* wtb = (ushort_t*)(small + 384 + NG * D_OUT + NG);
    ushort_t* wt_s1 = wtb;
    ushort_t* wt_r1 = wtb + 16384;
    ushort_t* wt_s2 = wtb + 32768;
    ushort_t* wt_r2 = wtb + 40960;

    hipMemsetAsync(sums, 0, (NG * D_OUT + NG) * sizeof(float), stream);

    prep_wt<<<192, 256, 0, stream>>>(w_self1, w_rel1, w_self2, w_rel2, wtb);
    prep_att_vecs<<<2, 256, 0, stream>>>(w_q1, w_k1, w_att1, w_q2, w_k2, w_att2, small);

    // ---- Edge sort (two-level counting sort, shared by both layers) ----
    const int chunk = (E + NBLK - 1) / NBLK;
    const int nbuck = (N + (1 << BSHIFT) - 1) >> BSHIFT;
    part_hist<<<NBLK, 256, 0, stream>>>(edst, E, chunk, bh);
    part_scan<<<1, 256, 0, stream>>>(bh, bb, E);
    part_scatter<<<NBLK, 256, 0, stream>>>(esrc, edst, ew, E, chunk, bh, part);
    bucket_sort<<<nbuck, 256, 0, stream>>>(part, bb, rowptr, sorted, N);

    // ---- Layer 1 ----
    {
        dim3 grid((N + 63) / 64, 1, 2);
        gemm_mfma<128, true, true><<<grid, 256, 0, stream>>>(
            x, N, wt_s1, wt_r1, (void*)bufS, (ushort_t*)bufR);
    }
    fused1<<<(N + 3) / 4, 256, 0, stream>>>(
        (const uint_t*)bufS, (const ushort_t*)bufR, rowptr, sorted,
        vk1, vq1, bias1, (uint_t*)bufH, out_att1, N);

    // ---- Layer 2 ----
    {
        dim3 grid((N + 63) / 64, 1, 2);
        gemm_mfma<64, false, false><<<grid, 256, 0, stream>>>(
            (const void*)bufH, N, wt_s2, wt_r2, (void*)bufS, (ushort_t*)bufR);
    }
    fused2<<<(N + 3) / 4, 256, 0, stream>>>(
        bufS, (const ushort_t*)bufR, rowptr, sorted,
        vk2, vq2, bias2, bufH, out_att2, N);

    // ---- Pool + MLP ----
    {
        int pblocks = 1024;
        int pchunk  = (N + pblocks * 4 - 1) / (pblocks * 4);
        pool_sum_v2<<<pblocks, 256, 0, stream>>>(bufH, gid, sums, cnt, N, pchunk);
    }
    pool_mlp<<<1, 64, 0, stream>>>(sums, cnt, mlp_w1, mlp_b1, mlp_w2, mlp_b2, out_embd);
}

// Round 8
// 326.624 us; speedup vs baseline: 13.5184x; 1.0710x over previous
//
#include <hip/hip_runtime.h>
#include <hip/hip_bf16.h>
#include <cstdint>
#include <cstddef>

static constexpr int D_IN  = 128;
static constexpr int D_HID = 128;
static constexpr int D_OUT = 64;
static constexpr int ATTD  = 64;
static constexpr int NG    = 64;
static constexpr int NB    = 256;   // coarse buckets (dst >> 9)
static constexpr int NBLK  = 256;   // partition blocks
static constexpr int BSHIFT = 9;    // 512 dst per bucket

typedef __attribute__((ext_vector_type(8))) short s16x8;
typedef __attribute__((ext_vector_type(4))) float f32x4;
typedef unsigned short ushort_t;
typedef unsigned int uint_t;

__device__ __forceinline__ unsigned short bf_bits(float f) {
    union { __hip_bfloat16 h; unsigned short u; } cv;
    cv.h = __float2bfloat16(f);
    return cv.u;
}
__device__ __forceinline__ float bf_lo(uint_t v) { return __uint_as_float(v << 16); }
__device__ __forceinline__ float bf_hi(uint_t v) { return __uint_as_float(v & 0xffff0000u); }
__device__ __forceinline__ float bf_one(unsigned short u) { return __uint_as_float(((uint_t)u) << 16); }

// ---------------------------------------------------------------------------
// MFMA bf16 dual GEMM body (verified since round 3), parameterized on block id.
// ---------------------------------------------------------------------------
template <int C, bool A32, bool OA_BF>
__device__ __forceinline__ void gemm_body(ushort_t* wt, int bx, int bz,
        const void* __restrict__ A, int M,
        const ushort_t* __restrict__ WTa, const ushort_t* __restrict__ WTb,
        void* __restrict__ Oa, ushort_t* __restrict__ Ob) {
    constexpr int K = 128;
    constexpr int RS = K + 8;

    const ushort_t* WT = bz ? WTb : WTa;
    for (int idx = threadIdx.x; idx < C * (K / 8); idx += 256) {
        int c  = idx / (K / 8);
        int kc = idx % (K / 8);
        *(uint4*)&wt[c * RS + kc * 8] = *(const uint4*)&WT[c * K + kc * 8];
    }
    __syncthreads();

    const int w    = threadIdx.x >> 6;
    const int lane = threadIdx.x & 63;
    const int row  = bx * 64 + w * 16 + (lane & 15);
    const int rowc = row < M ? row : (M - 1);
    const int kb   = (lane >> 4) * 8;

    s16x8 afr[4];
    if (A32) {
        const float* Af = (const float*)A + (size_t)rowc * K + kb;
#pragma unroll
        for (int ks = 0; ks < 4; ++ks) {
            float4 f0 = *(const float4*)(Af + ks * 32);
            float4 f1 = *(const float4*)(Af + ks * 32 + 4);
            s16x8 a;
            a[0] = (short)bf_bits(f0.x); a[1] = (short)bf_bits(f0.y);
            a[2] = (short)bf_bits(f0.z); a[3] = (short)bf_bits(f0.w);
            a[4] = (short)bf_bits(f1.x); a[5] = (short)bf_bits(f1.y);
            a[6] = (short)bf_bits(f1.z); a[7] = (short)bf_bits(f1.w);
            afr[ks] = a;
        }
    } else {
        const ushort_t* Ab = (const ushort_t*)A + (size_t)rowc * K + kb;
#pragma unroll
        for (int ks = 0; ks < 4; ++ks) afr[ks] = *(const s16x8*)(Ab + ks * 32);
    }

    const int colc = lane & 15;
    const int r0   = bx * 64 + w * 16 + (lane >> 4) * 4;

#pragma unroll
    for (int ct = 0; ct < C / 16; ++ct) {
        f32x4 acc = {0.f, 0.f, 0.f, 0.f};
        const int colb = ct * 16 + colc;
#pragma unroll
        for (int ks = 0; ks < 4; ++ks) {
            s16x8 b = *(const s16x8*)&wt[colb * RS + ks * 32 + kb];
            acc = __builtin_amdgcn_mfma_f32_16x16x32_bf16(afr[ks], b, acc, 0, 0, 0);
        }
        if (bz == 0) {
            if (OA_BF) {
                ushort_t* O = (ushort_t*)Oa;
#pragma unroll
                for (int j = 0; j < 4; ++j)
                    if (r0 + j < M) O[(size_t)(r0 + j) * C + colb] = bf_bits(acc[j]);
            } else {
                float* O = (float*)Oa;
#pragma unroll
                for (int j = 0; j < 4; ++j)
                    if (r0 + j < M) O[(size_t)(r0 + j) * C + colb] = acc[j];
            }
        } else {
#pragma unroll
            for (int j = 0; j < 4; ++j)
                if (r0 + j < M) Ob[(size_t)(r0 + j) * C + colb] = bf_bits(acc[j]);
        }
    }
}

// Standalone GEMM (layer 2)
__global__ __launch_bounds__(256) void gemm2_kernel(
        const void* __restrict__ A, int M,
        const ushort_t* __restrict__ WTa, const ushort_t* __restrict__ WTb,
        void* __restrict__ Oa, ushort_t* __restrict__ Ob) {
    __shared__ ushort_t wt[64 * 136];
    gemm_body<64, false, false>(wt, blockIdx.x, blockIdx.z, A, M, WTa, WTb, Oa, Ob);
}

// ---------------------------------------------------------------------------
// Phase A: [0,NBLK) part_hist | [NBLK,NBLK+192) prep_wt | +2 prep_att | +1 zero
// ---------------------------------------------------------------------------
__global__ __launch_bounds__(256) void phaseA(
        const int* __restrict__ edst, int E, int chunk, int* __restrict__ bh,
        const float* __restrict__ w_self1, const float* __restrict__ w_rel1,
        const float* __restrict__ w_self2, const float* __restrict__ w_rel2,
        ushort_t* __restrict__ wtb,
        const float* __restrict__ w_q1, const float* __restrict__ w_k1,
        const float* __restrict__ w_att1,
        const float* __restrict__ w_q2, const float* __restrict__ w_k2,
        const float* __restrict__ w_att2,
        float* __restrict__ small, float* __restrict__ zero_region) {
    __shared__ int h[NB];
    int bid = blockIdx.x;
    if (bid < NBLK) {
        // part_hist
        h[threadIdx.x] = 0;
        __syncthreads();
        int beg = bid * chunk;
        int end = min(E, beg + chunk);
        for (int i = beg + threadIdx.x; i < end; i += 256)
            atomicAdd(&h[edst[i] >> BSHIFT], 1);
        __syncthreads();
        bh[threadIdx.x * NBLK + bid] = h[threadIdx.x];
    } else if (bid < NBLK + 192) {
        // prep_wt
        int idx = (bid - NBLK) * 256 + threadIdx.x;
        const float* src; int base, Cc;
        if (idx < 16384)      { src = w_self1; base = 0;     Cc = 128; }
        else if (idx < 32768) { src = w_rel1;  base = 16384; Cc = 128; }
        else if (idx < 40960) { src = w_self2; base = 32768; Cc = 64;  }
        else                  { src = w_rel2;  base = 40960; Cc = 64;  }
        int l = idx - base;
        int c = l >> 7;
        int k = l & 127;
        wtb[base + l] = bf_bits(src[k * Cc + c]);
    } else if (bid < NBLK + 194) {
        // prep_att_vecs
        int idx = (bid - NBLK - 192) * 256 + threadIdx.x;
        if (idx < 384) {
            float acc = 0.f;
            if (idx < 128) {
                int d = idx;
                for (int a = 0; a < ATTD; ++a) acc += w_k1[d * ATTD + a] * w_att1[a];
                small[0 + d] = acc;
            } else if (idx < 256) {
                int d = idx - 128;
                for (int a = 0; a < ATTD; ++a) acc += w_q1[d * ATTD + a] * w_att1[ATTD + a];
                small[128 + d] = acc;
            } else if (idx < 320) {
                int d = idx - 256;
                for (int a = 0; a < ATTD; ++a) acc += w_k2[d * ATTD + a] * w_att2[a];
                small[256 + d] = acc;
            } else {
                int d = idx - 320;
                for (int a = 0; a < ATTD; ++a) acc += w_q2[d * ATTD + a] * w_att2[ATTD + a];
                small[320 + d] = acc;
            }
        }
    } else {
        // zero sums + cnt (NG*D_OUT + NG floats)
        for (int i = threadIdx.x; i < NG * D_OUT + NG; i += 256) zero_region[i] = 0.f;
    }
}

// single block, 256 threads
__global__ void part_scan(int* __restrict__ bh, int* __restrict__ bb, int E) {
    __shared__ int wsum[4];
    int t = threadIdx.x;
    int run = 0;
    for (int blk = 0; blk < NBLK; ++blk) {
        int v = bh[t * NBLK + blk];
        bh[t * NBLK + blk] = run;
        run += v;
    }
    int lane = t & 63, w = t >> 6;
    int incl = run;
#pragma unroll
    for (int off = 1; off < 64; off <<= 1) {
        int u = __shfl_up(incl, off);
        if (lane >= off) incl += u;
    }
    if (lane == 63) wsum[w] = incl;
    __syncthreads();
    int wbase = 0;
#pragma unroll
    for (int i = 0; i < 4; ++i) if (i < w) wbase += wsum[i];
    int base = wbase + incl - run;   // exclusive bucket base
    bb[t] = base;
    if (t == 255) bb[256] = base + run;   // == E
    for (int blk = 0; blk < NBLK; ++blk)
        bh[t * NBLK + blk] += base;
}

// ---------------------------------------------------------------------------
// Phase B: [0,NBLK) part_scatter | [NBLK, NBLK+2*nx) gemm1 (z = (bid-NBLK)/nx)
// ---------------------------------------------------------------------------
__global__ __launch_bounds__(256) void phaseB(
        const int* __restrict__ src, const int* __restrict__ dst,
        const float* __restrict__ ew, int E, int chunk,
        const int* __restrict__ bh, uint2* __restrict__ part,
        const float* __restrict__ x, int M, int nx,
        const ushort_t* __restrict__ wt_s1, const ushort_t* __restrict__ wt_r1,
        void* __restrict__ Oa, ushort_t* __restrict__ Ob) {
    __shared__ ushort_t smem[128 * 136];
    int bid = blockIdx.x;
    if (bid < NBLK) {
        int* ofs = (int*)smem;
        ofs[threadIdx.x] = bh[threadIdx.x * NBLK + bid];
        __syncthreads();
        int beg = bid * chunk;
        int end = min(E, beg + chunk);
        for (int i = beg + threadIdx.x; i < end; i += 256) {
            int d = dst[i];
            int b = d >> BSHIFT;
            int pos = atomicAdd(&ofs[b], 1);
            part[pos] = make_uint2((uint_t)src[i] | ((uint_t)(d & 511) << 20),
                                   __float_as_uint(ew[i]));
        }
    } else {
        int gb = bid - NBLK;
        int bz = gb / nx;
        int bx = gb - bz * nx;
        gemm_body<128, true, true>(smem, bx, bz, x, M, wt_s1, wt_r1, Oa, Ob);
    }
}

// one block per bucket: LDS fine hist + scan -> rowptr + scatter
__global__ __launch_bounds__(256) void bucket_sort(const uint2* __restrict__ part,
        const int* __restrict__ bb, int* __restrict__ rowptr,
        float2* __restrict__ sorted, int N_) {
    __shared__ int hist[512];
    __shared__ int wsum[4];
    int b = blockIdx.x;
    int t = threadIdx.x;
    int start = bb[b], end = bb[b + 1];
    hist[t] = 0; hist[t + 256] = 0;
    __syncthreads();
    for (int i = start + t; i < end; i += 256)
        atomicAdd(&hist[part[i].x >> 20], 1);
    __syncthreads();
    int v0 = hist[2 * t], v1 = hist[2 * t + 1];
    int pair = v0 + v1;
    int lane = t & 63, w = t >> 6;
    int incl = pair;
#pragma unroll
    for (int off = 1; off < 64; off <<= 1) {
        int u = __shfl_up(incl, off);
        if (lane >= off) incl += u;
    }
    if (lane == 63) wsum[w] = incl;
    __syncthreads();
    int wbase = 0;
#pragma unroll
    for (int i = 0; i < 4; ++i) if (i < w) wbase += wsum[i];
    int excl = wbase + incl - pair;
    __syncthreads();
    hist[2 * t]     = start + excl;
    hist[2 * t + 1] = start + excl + v0;
    int dst0 = (b << BSHIFT) + 2 * t;
    if (dst0 < N_)     rowptr[dst0]     = start + excl + v0;
    if (dst0 + 1 < N_) rowptr[dst0 + 1] = start + excl + v0 + v1;
    __syncthreads();
    for (int i = start + t; i < end; i += 256) {
        uint2 r = part[i];
        int dl = r.x >> 20;
        int s  = r.x & 0xFFFFF;
        int pos = atomicAdd(&hist[dl], 1);
        sorted[pos] = make_float2(__int_as_float(s), __uint_as_float(r.y));
    }
}

// ---------------------------------------------------------------------------
// Fused gather-SpMM + attention, layer 1 (D=128). Round-6 shape:
// whole wave per edge (64 lanes x 2 feats), 8-edge batches, clamp-free main
// loop + masked tail batch, 32-bit byte offsets.
// ---------------------------------------------------------------------------
__global__ __launch_bounds__(256) void fused1(
        const uint_t* __restrict__ selfp, const ushort_t* __restrict__ relft,
        const int* __restrict__ rowptr, const float2* __restrict__ sorted,
        const float* __restrict__ vk, const float* __restrict__ vq,
        const float* __restrict__ bias,
        uint_t* __restrict__ hout, float* __restrict__ attout, int M) {
    int wave = threadIdx.x >> 6;
    int lane = threadIdx.x & 63;
    int n = blockIdx.x * 4 + wave;
    if (n >= M) return;

    uint_t s2 = selfp[(size_t)n * 64 + lane];
    float sv0 = bf_lo(s2), sv1 = bf_hi(s2);
    float nb0 = 0.f, nb1 = 0.f;

    const int beg = (n > 0) ? rowptr[n - 1] : 0;
    const int end = rowptr[n];
    const int len = end - beg;
    const char* base = (const char*)relft;
    const uint_t lb = (uint_t)lane << 2;

    int e = beg;
    const int efull = beg + (len & ~7);
    for (; e < efull; e += 8) {
        float2 swb[8];
#pragma unroll
        for (int j = 0; j < 8; ++j) swb[j] = sorted[e + j];
        uint_t vv[8];
#pragma unroll
        for (int j = 0; j < 8; ++j)
            vv[j] = *(const uint_t*)(base + (((uint_t)__float_as_uint(swb[j].x) << 8) | lb));
#pragma unroll
        for (int j = 0; j < 8; ++j) {
            nb0 = fmaf(swb[j].y, bf_lo(vv[j]), nb0);
            nb1 = fmaf(swb[j].y, bf_hi(vv[j]), nb1);
        }
    }
    if (e < end) {   // masked tail batch (1..7 edges)
        float2 swb[8];
        float  wb[8];
#pragma unroll
        for (int j = 0; j < 8; ++j) {
            int idx = e + j;
            int cl  = idx < end ? idx : e;
            swb[j] = sorted[cl];
            wb[j]  = idx < end ? swb[j].y : 0.f;
        }
        uint_t vv[8];
#pragma unroll
        for (int j = 0; j < 8; ++j)
            vv[j] = *(const uint_t*)(base + (((uint_t)__float_as_uint(swb[j].x) << 8) | lb));
#pragma unroll
        for (int j = 0; j < 8; ++j) {
            nb0 = fmaf(wb[j], bf_lo(vv[j]), nb0);
            nb1 = fmaf(wb[j], bf_hi(vv[j]), nb1);
        }
    }

    float2 k2 = ((const float2*)vk)[lane];
    float2 q2 = ((const float2*)vq)[lane];
    float sk = sv0 * k2.x + sv1 * k2.y;
    float sq = sv0 * q2.x + sv1 * q2.y;
    float nk = nb0 * k2.x + nb1 * k2.y;
#pragma unroll
    for (int off = 32; off; off >>= 1) {
        sk += __shfl_xor(sk, off);
        sq += __shfl_xor(sq, off);
        nk += __shfl_xor(nk, off);
    }
    float e0 = sk + sq;
    float e1 = nk + sq;
    e0 = e0 > 0.f ? e0 : expm1f(e0);
    e1 = e1 > 0.f ? e1 : expm1f(e1);
    float m = fmaxf(e0, e1);
    float a0 = expf(e0 - m);
    float a1 = expf(e1 - m);
    float inv = 1.f / (a0 + a1);
    a0 *= inv; a1 *= inv;

    float2 b2 = ((const float2*)bias)[lane];
    float o0 = fmaf(a0, sv0, fmaf(a1, nb0, b2.x));
    float o1 = fmaf(a0, sv1, fmaf(a1, nb1, b2.y));
    o0 = o0 > 0.f ? o0 : expm1f(o0);
    o1 = o1 > 0.f ? o1 : expm1f(o1);
    hout[(size_t)n * 64 + lane] = (uint_t)bf_bits(o0) | ((uint_t)bf_bits(o1) << 16);
    if (lane == 0) {
        attout[2 * (size_t)n + 0] = a0;
        attout[2 * (size_t)n + 1] = a1;
    }
}

// ---------------------------------------------------------------------------
// Fused gather-SpMM + attention, layer 2 (D=64). Same structure, 1 feat/lane.
// ---------------------------------------------------------------------------
__global__ __launch_bounds__(256) void fused2(
        const float* __restrict__ selfp, const ushort_t* __restrict__ relft,
        const int* __restrict__ rowptr, const float2* __restrict__ sorted,
        const float* __restrict__ vk, const float* __restrict__ vq,
        const float* __restrict__ bias,
        float* __restrict__ hout, float* __restrict__ attout, int M) {
    int wave = threadIdx.x >> 6;
    int lane = threadIdx.x & 63;
    int n = blockIdx.x * 4 + wave;
    if (n >= M) return;

    float sv = selfp[(size_t)n * 64 + lane];
    float nb = 0.f;

    const int beg = (n > 0) ? rowptr[n - 1] : 0;
    const int end = rowptr[n];
    const int len = end - beg;
    const char* base = (const char*)relft;
    const uint_t lb = (uint_t)lane << 1;

    int e = beg;
    const int efull = beg + (len & ~7);
    for (; e < efull; e += 8) {
        float2 swb[8];
#pragma unroll
        for (int j = 0; j < 8; ++j) swb[j] = sorted[e + j];
        ushort_t vv[8];
#pragma unroll
        for (int j = 0; j < 8; ++j)
            vv[j] = *(const ushort_t*)(base + (((uint_t)__float_as_uint(swb[j].x) << 7) | lb));
#pragma unroll
        for (int j = 0; j < 8; ++j) nb = fmaf(swb[j].y, bf_one(vv[j]), nb);
    }
    if (e < end) {
        float2 swb[8];
        float  wb[8];
#pragma unroll
        for (int j = 0; j < 8; ++j) {
            int idx = e + j;
            int cl  = idx < end ? idx : e;
            swb[j] = sorted[cl];
            wb[j]  = idx < end ? swb[j].y : 0.f;
        }
        ushort_t vv[8];
#pragma unroll
        for (int j = 0; j < 8; ++j)
            vv[j] = *(const ushort_t*)(base + (((uint_t)__float_as_uint(swb[j].x) << 7) | lb));
#pragma unroll
        for (int j = 0; j < 8; ++j) nb = fmaf(wb[j], bf_one(vv[j]), nb);
    }

    float kk = vk[lane], qq = vq[lane];
    float sk = sv * kk;
    float sq = sv * qq;
    float nk = nb * kk;
#pragma unroll
    for (int off = 32; off; off >>= 1) {
        sk += __shfl_xor(sk, off);
        sq += __shfl_xor(sq, off);
        nk += __shfl_xor(nk, off);
    }
    float e0 = sk + sq;
    float e1 = nk + sq;
    e0 = e0 > 0.f ? e0 : expm1f(e0);
    e1 = e1 > 0.f ? e1 : expm1f(e1);
    float m = fmaxf(e0, e1);
    float a0 = expf(e0 - m);
    float a1 = expf(e1 - m);
    float inv = 1.f / (a0 + a1);
    a0 *= inv; a1 *= inv;

    hout[(size_t)n * 64 + lane] = fmaf(a0, sv, fmaf(a1, nb, bias[lane]));
    if (lane == 0) {
        attout[2 * (size_t)n + 0] = a0;
        attout[2 * (size_t)n + 1] = a1;
    }
}

// ---------------------------------------------------------------------------
// Pool: register accumulation over sorted gid, flush on graph change.
// ---------------------------------------------------------------------------
__global__ __launch_bounds__(256) void pool_sum_v2(
        const float* __restrict__ h, const int* __restrict__ gid,
        float* __restrict__ sums, float* __restrict__ cnt, int M, int chunk) {
    int wave = threadIdx.x >> 6;
    int lane = threadIdx.x & 63;
    int wid  = blockIdx.x * 4 + wave;
    int beg  = wid * chunk;
    int end  = min(M, beg + chunk);
    if (beg >= end) return;

    int   cur_g = gid[beg];
    float acc   = 0.f;
    int   cl    = 0;
    for (int n = beg; n < end; ++n) {
        int g = gid[n];
        if (g != cur_g) {
            atomicAdd(&sums[(size_t)cur_g * D_OUT + lane], acc);
            if (lane == 0) atomicAdd(&cnt[cur_g], (float)cl);
            cur_g = g; acc = 0.f; cl = 0;
        }
        acc += h[(size_t)n * D_OUT + lane];
        ++cl;
    }
    atomicAdd(&sums[(size_t)cur_g * D_OUT + lane], acc);
    if (lane == 0) atomicAdd(&cnt[cur_g], (float)cl);
}

__global__ void pool_mlp(const float* __restrict__ sums, const float* __restrict__ cnt,
                         const float* __restrict__ w1, const float* __restrict__ b1,
                         const float* __restrict__ w2, const float* __restrict__ b2,
                         float* __restrict__ out) {
    int g = threadIdx.x;
    if (g >= NG) return;
    float c = fmaxf(cnt[g], 1.0f);
    float inv = 1.0f / c;
    float hg[D_OUT];
#pragma unroll
    for (int d = 0; d < D_OUT; ++d) hg[d] = sums[g * D_OUT + d] * inv;
    float acc = b2[0];
    for (int j = 0; j < D_OUT / 2; ++j) {
        float hid = b1[j];
#pragma unroll 8
        for (int d = 0; d < D_OUT; ++d) hid = fmaf(hg[d], w1[d * (D_OUT / 2) + j], hid);
        hid = fmaxf(hid, 0.f);
        acc = fmaf(hid, w2[j], acc);
    }
    out[g] = acc;
}

// ---------------------------------------------------------------------------
extern "C" void kernel_launch(void* const* d_in, const int* in_sizes, int n_in,
                              void* d_out, int out_size, void* d_ws, size_t ws_size,
                              hipStream_t stream) {
    const float* x       = (const float*)d_in[0];
    const int*   esrc    = (const int*)  d_in[1];
    const int*   edst    = (const int*)  d_in[2];
    const float* ew      = (const float*)d_in[3];
    const int*   gid     = (const int*)  d_in[4];
    const float* w_self1 = (const float*)d_in[5];
    const float* w_rel1  = (const float*)d_in[6];
    const float* bias1   = (const float*)d_in[7];
    const float* w_q1    = (const float*)d_in[8];
    const float* w_k1    = (const float*)d_in[9];
    const float* w_att1  = (const float*)d_in[10];
    const float* w_self2 = (const float*)d_in[11];
    const float* w_rel2  = (const float*)d_in[12];
    const float* bias2   = (const float*)d_in[13];
    const float* w_q2    = (const float*)d_in[14];
    const float* w_k2    = (const float*)d_in[15];
    const float* w_att2  = (const float*)d_in[16];
    const float* mlp_w1  = (const float*)d_in[17];
    const float* mlp_b1  = (const float*)d_in[18];
    const float* mlp_w2  = (const float*)d_in[19];
    const float* mlp_b2  = (const float*)d_in[20];

    const int N = in_sizes[0] / D_IN;
    const int E = in_sizes[1];

    float* out = (float*)d_out;
    float* out_embd = out;
    float* out_att1 = out + NG;
    float* out_att2 = out + NG + 2 * (size_t)N;

    // ---- Workspace layout (float units) ----
    float* ws = (float*)d_ws;
    size_t nf = (size_t)N;
    float* bufS = ws;                  // selfft1 bf16 (Nx128) -> selfft2 fp32 (Nx64)
    float* bufR = ws + nf * 64;        // relft1 bf16 (Nx128) -> relft2 bf16 (Nx64)
    float* bufH = ws + nf * 128;       // part[] during sort -> h1 bf16 -> h2 fp32
    uint2* part = (uint2*)bufH;        // E uint2, dead before fused1
    int* ip     = (int*)(ws + nf * 192);
    int* rowptr = ip;                  // N
    int* bb     = ip + N;              // 257
    int* bh     = ip + N + 257;        // NB*NBLK = 65536
    size_t int_end = nf * 192 + nf + 257 + (size_t)NB * NBLK;
    int_end = (int_end + 1) & ~(size_t)1;
    float2* sorted = (float2*)(ws + int_end);     // E float2
    float* small = ws + int_end + 2 * (size_t)E;
    float* vk1 = small + 0;
    float* vq1 = small + 128;
    float* vk2 = small + 256;
    float* vq2 = small + 320;
    float* sums = small + 384;
    float* cnt  = small + 384 + NG * D_OUT;
    ushort_t* wtb = (ushort_t*)(small + 384 + NG * D_OUT + NG);
    ushort_t* wt_s1 = wtb;
    ushort_t* wt_r1 = wtb + 16384;
    ushort_t* wt_s2 = wtb + 32768;
    ushort_t* wt_r2 = wtb + 40960;

    const int chunk = (E + NBLK - 1) / NBLK;
    const int nbuck = (N + (1 << BSHIFT) - 1) >> BSHIFT;
    const int nx    = (N + 63) / 64;

    // Phase A: part_hist ∥ prep_wt ∥ prep_att ∥ zero accumulators
    phaseA<<<NBLK + 192 + 2 + 1, 256, 0, stream>>>(
        edst, E, chunk, bh,
        w_self1, w_rel1, w_self2, w_rel2, wtb,
        w_q1, w_k1, w_att1, w_q2, w_k2, w_att2, small, sums);

    part_scan<<<1, 256, 0, stream>>>(bh, bb, E);

    // Phase B: part_scatter ∥ gemm1
    phaseB<<<NBLK + 2 * nx, 256, 0, stream>>>(
        esrc, edst, ew, E, chunk, bh, part,
        x, N, nx, wt_s1, wt_r1, (void*)bufS, (ushort_t*)bufR);

    bucket_sort<<<nbuck, 256, 0, stream>>>(part, bb, rowptr, sorted, N);

    fused1<<<(N + 3) / 4, 256, 0, stream>>>(
        (const uint_t*)bufS, (const ushort_t*)bufR, rowptr, sorted,
        vk1, vq1, bias1, (uint_t*)bufH, out_att1, N);

    {
        dim3 grid(nx, 1, 2);
        gemm2_kernel<<<grid, 256, 0, stream>>>(
            (const void*)bufH, N, wt_s2, wt_r2, (void*)bufS, (ushort_t*)bufR);
    }

    fused2<<<(N + 3) / 4, 256, 0, stream>>>(
        bufS, (const ushort_t*)bufR, rowptr, sorted,
        vk2, vq2, bias2, bufH, out_att2, N);

    {
        int pblocks = 1024;
        int pchunk  = (N + pblocks * 4 - 1) / (pblocks * 4);
        pool_sum_v2<<<pblocks, 256, 0, stream>>>(bufH, gid, sums, cnt, N, pchunk);
    }
    pool_mlp<<<1, 64, 0, stream>>>(sums, cnt, mlp_w1, mlp_b1, mlp_w2, mlp_b2, out_embd);
}

// Round 9
// 324.193 us; speedup vs baseline: 13.6197x; 1.0075x over previous
//
#include <hip/hip_runtime.h>
#include <hip/hip_bf16.h>
#include <cstdint>
#include <cstddef>

static constexpr int D_IN  = 128;
static constexpr int D_HID = 128;
static constexpr int D_OUT = 64;
static constexpr int ATTD  = 64;
static constexpr int NG    = 64;
static constexpr int NB    = 256;   // coarse buckets (dst >> 9)
static constexpr int NBLK  = 256;   // partition blocks
static constexpr int BSHIFT = 9;    // 512 dst per bucket

typedef __attribute__((ext_vector_type(8))) short s16x8;
typedef __attribute__((ext_vector_type(4))) float f32x4;
typedef unsigned short ushort_t;
typedef unsigned int uint_t;

__device__ __forceinline__ unsigned short bf_bits(float f) {
    union { __hip_bfloat16 h; unsigned short u; } cv;
    cv.h = __float2bfloat16(f);
    return cv.u;
}
__device__ __forceinline__ float bf_lo(uint_t v) { return __uint_as_float(v << 16); }
__device__ __forceinline__ float bf_hi(uint_t v) { return __uint_as_float(v & 0xffff0000u); }
__device__ __forceinline__ float bf_one(unsigned short u) { return __uint_as_float(((uint_t)u) << 16); }

// ---------------------------------------------------------------------------
// MFMA bf16 dual GEMM body: ONE block computes both Oa = A@Wa and Ob = A@Wb
// (A-fragments loaded once). wt must hold 2*C*(K+8) ushorts.
// ---------------------------------------------------------------------------
template <int C, bool A32, bool OA_BF>
__device__ __forceinline__ void gemm_dual_body(ushort_t* wt, int bx,
        const void* __restrict__ A, int M,
        const ushort_t* __restrict__ WTa, const ushort_t* __restrict__ WTb,
        void* __restrict__ Oa, ushort_t* __restrict__ Ob) {
    constexpr int K = 128;
    constexpr int RS = K + 8;

    for (int idx = threadIdx.x; idx < 2 * C * (K / 8); idx += 256) {
        int half = idx >= C * (K / 8);
        int l = idx - half * C * (K / 8);
        int c  = l >> 4;          // K/8 == 16
        int kc = l & 15;
        const ushort_t* W = half ? WTb : WTa;
        *(uint4*)&wt[half * C * RS + c * RS + kc * 8] = *(const uint4*)&W[c * K + kc * 8];
    }
    __syncthreads();

    const int w    = threadIdx.x >> 6;
    const int lane = threadIdx.x & 63;
    const int row  = bx * 64 + w * 16 + (lane & 15);
    const int rowc = row < M ? row : (M - 1);
    const int kb   = (lane >> 4) * 8;

    s16x8 afr[4];
    if (A32) {
        const float* Af = (const float*)A + (size_t)rowc * K + kb;
#pragma unroll
        for (int ks = 0; ks < 4; ++ks) {
            float4 f0 = *(const float4*)(Af + ks * 32);
            float4 f1 = *(const float4*)(Af + ks * 32 + 4);
            s16x8 a;
            a[0] = (short)bf_bits(f0.x); a[1] = (short)bf_bits(f0.y);
            a[2] = (short)bf_bits(f0.z); a[3] = (short)bf_bits(f0.w);
            a[4] = (short)bf_bits(f1.x); a[5] = (short)bf_bits(f1.y);
            a[6] = (short)bf_bits(f1.z); a[7] = (short)bf_bits(f1.w);
            afr[ks] = a;
        }
    } else {
        const ushort_t* Ab = (const ushort_t*)A + (size_t)rowc * K + kb;
#pragma unroll
        for (int ks = 0; ks < 4; ++ks) afr[ks] = *(const s16x8*)(Ab + ks * 32);
    }

    const int colc = lane & 15;
    const int r0   = bx * 64 + w * 16 + (lane >> 4) * 4;

#pragma unroll
    for (int z = 0; z < 2; ++z) {
        const ushort_t* wz = wt + z * C * RS;
#pragma unroll
        for (int ct = 0; ct < C / 16; ++ct) {
            f32x4 acc = {0.f, 0.f, 0.f, 0.f};
            const int colb = ct * 16 + colc;
#pragma unroll
            for (int ks = 0; ks < 4; ++ks) {
                s16x8 b = *(const s16x8*)&wz[colb * RS + ks * 32 + kb];
                acc = __builtin_amdgcn_mfma_f32_16x16x32_bf16(afr[ks], b, acc, 0, 0, 0);
            }
            if (z == 0) {
                if (OA_BF) {
                    ushort_t* O = (ushort_t*)Oa;
#pragma unroll
                    for (int j = 0; j < 4; ++j)
                        if (r0 + j < M) O[(size_t)(r0 + j) * C + colb] = bf_bits(acc[j]);
                } else {
                    float* O = (float*)Oa;
#pragma unroll
                    for (int j = 0; j < 4; ++j)
                        if (r0 + j < M) O[(size_t)(r0 + j) * C + colb] = acc[j];
                }
            } else {
#pragma unroll
                for (int j = 0; j < 4; ++j)
                    if (r0 + j < M) Ob[(size_t)(r0 + j) * C + colb] = bf_bits(acc[j]);
            }
        }
    }
}

// Standalone dual GEMM (layer 2, C=64)
__global__ __launch_bounds__(256) void gemm2_kernel(
        const void* __restrict__ A, int M,
        const ushort_t* __restrict__ WTa, const ushort_t* __restrict__ WTb,
        void* __restrict__ Oa, ushort_t* __restrict__ Ob) {
    __shared__ ushort_t wt[2 * 64 * 136];
    gemm_dual_body<64, false, false>(wt, blockIdx.x, A, M, WTa, WTb, Oa, Ob);
}

// ---------------------------------------------------------------------------
// Phase A: [0,NBLK) part_hist | [NBLK,NBLK+192) prep_wt | +2 prep_att | +1 zero
// ---------------------------------------------------------------------------
__global__ __launch_bounds__(256) void phaseA(
        const int* __restrict__ edst, int E, int chunk, int* __restrict__ bh,
        const float* __restrict__ w_self1, const float* __restrict__ w_rel1,
        const float* __restrict__ w_self2, const float* __restrict__ w_rel2,
        ushort_t* __restrict__ wtb,
        const float* __restrict__ w_q1, const float* __restrict__ w_k1,
        const float* __restrict__ w_att1,
        const float* __restrict__ w_q2, const float* __restrict__ w_k2,
        const float* __restrict__ w_att2,
        float* __restrict__ small, float* __restrict__ zero_region) {
    __shared__ int h[NB];
    int bid = blockIdx.x;
    if (bid < NBLK) {
        h[threadIdx.x] = 0;
        __syncthreads();
        int beg = bid * chunk;
        int end = min(E, beg + chunk);
        for (int i = beg + threadIdx.x; i < end; i += 256)
            atomicAdd(&h[edst[i] >> BSHIFT], 1);
        __syncthreads();
        bh[threadIdx.x * NBLK + bid] = h[threadIdx.x];
    } else if (bid < NBLK + 192) {
        int idx = (bid - NBLK) * 256 + threadIdx.x;
        const float* src; int base, Cc;
        if (idx < 16384)      { src = w_self1; base = 0;     Cc = 128; }
        else if (idx < 32768) { src = w_rel1;  base = 16384; Cc = 128; }
        else if (idx < 40960) { src = w_self2; base = 32768; Cc = 64;  }
        else                  { src = w_rel2;  base = 40960; Cc = 64;  }
        int l = idx - base;
        int c = l >> 7;
        int k = l & 127;
        wtb[base + l] = bf_bits(src[k * Cc + c]);
    } else if (bid < NBLK + 194) {
        int idx = (bid - NBLK - 192) * 256 + threadIdx.x;
        if (idx < 384) {
            float acc = 0.f;
            if (idx < 128) {
                int d = idx;
                for (int a = 0; a < ATTD; ++a) acc += w_k1[d * ATTD + a] * w_att1[a];
                small[0 + d] = acc;
            } else if (idx < 256) {
                int d = idx - 128;
                for (int a = 0; a < ATTD; ++a) acc += w_q1[d * ATTD + a] * w_att1[ATTD + a];
                small[128 + d] = acc;
            } else if (idx < 320) {
                int d = idx - 256;
                for (int a = 0; a < ATTD; ++a) acc += w_k2[d * ATTD + a] * w_att2[a];
                small[256 + d] = acc;
            } else {
                int d = idx - 320;
                for (int a = 0; a < ATTD; ++a) acc += w_q2[d * ATTD + a] * w_att2[ATTD + a];
                small[320 + d] = acc;
            }
        }
    } else {
        for (int i = threadIdx.x; i < NG * D_OUT + NG; i += 256) zero_region[i] = 0.f;
    }
}

// single block, 256 threads. bh is 16B-aligned; each thread owns a contiguous
// NBLK-int row. int4-vectorized two-pass (exclusive prefix, then +base).
__global__ void part_scan(int* __restrict__ bh, int* __restrict__ bb, int E) {
    __shared__ int wsum[4];
    int t = threadIdx.x;
    int4* row = (int4*)&bh[t * NBLK];
    int run = 0;
#pragma unroll 8
    for (int q = 0; q < NBLK / 4; ++q) {
        int4 v = row[q];
        int4 o;
        o.x = run;
        o.y = run + v.x;
        o.z = o.y + v.y;
        o.w = o.z + v.z;
        run = o.w + v.w;
        row[q] = o;
    }
    int lane = t & 63, w = t >> 6;
    int incl = run;
#pragma unroll
    for (int off = 1; off < 64; off <<= 1) {
        int u = __shfl_up(incl, off);
        if (lane >= off) incl += u;
    }
    if (lane == 63) wsum[w] = incl;
    __syncthreads();
    int wbase = 0;
#pragma unroll
    for (int i = 0; i < 4; ++i) if (i < w) wbase += wsum[i];
    int base = wbase + incl - run;   // exclusive bucket base
    bb[t] = base;
    if (t == 255) bb[256] = base + run;   // == E
#pragma unroll 8
    for (int q = 0; q < NBLK / 4; ++q) {
        int4 v = row[q];
        v.x += base; v.y += base; v.z += base; v.w += base;
        row[q] = v;
    }
}

// ---------------------------------------------------------------------------
// Phase B: [0,NBLK) part_scatter | [NBLK, NBLK+nx) dual gemm1
// ---------------------------------------------------------------------------
__global__ __launch_bounds__(256) void phaseB(
        const int* __restrict__ src, const int* __restrict__ dst,
        const float* __restrict__ ew, int E, int chunk,
        const int* __restrict__ bh, uint2* __restrict__ part,
        const float* __restrict__ x, int M,
        const ushort_t* __restrict__ wt_s1, const ushort_t* __restrict__ wt_r1,
        void* __restrict__ Oa, ushort_t* __restrict__ Ob) {
    __shared__ ushort_t smem[2 * 128 * 136];
    int bid = blockIdx.x;
    if (bid < NBLK) {
        int* ofs = (int*)smem;
        ofs[threadIdx.x] = bh[threadIdx.x * NBLK + bid];
        __syncthreads();
        int beg = bid * chunk;
        int end = min(E, beg + chunk);
        for (int i = beg + threadIdx.x; i < end; i += 256) {
            int d = dst[i];
            int b = d >> BSHIFT;
            int pos = atomicAdd(&ofs[b], 1);
            part[pos] = make_uint2((uint_t)src[i] | ((uint_t)(d & 511) << 20),
                                   __float_as_uint(ew[i]));
        }
    } else {
        gemm_dual_body<128, true, true>(smem, bid - NBLK, x, M, wt_s1, wt_r1, Oa, Ob);
    }
}

// one block per bucket: LDS fine hist + scan -> rowptr + scatter.
// 8-deep load batching in both passes (blocks are ~1/CU, latency-bound).
__global__ __launch_bounds__(256) void bucket_sort(const uint2* __restrict__ part,
        const int* __restrict__ bb, int* __restrict__ rowptr,
        float2* __restrict__ sorted, int N_) {
    __shared__ int hist[512];
    __shared__ int wsum[4];
    int b = blockIdx.x;
    int t = threadIdx.x;
    int start = bb[b], end = bb[b + 1];
    hist[t] = 0; hist[t + 256] = 0;
    __syncthreads();
    {
        int i = start + t;
        for (; i + 1792 < end; i += 2048) {
            int k[8];
#pragma unroll
            for (int j = 0; j < 8; ++j) k[j] = part[i + j * 256].x >> 20;
#pragma unroll
            for (int j = 0; j < 8; ++j) atomicAdd(&hist[k[j]], 1);
        }
        for (; i < end; i += 256) atomicAdd(&hist[part[i].x >> 20], 1);
    }
    __syncthreads();
    int v0 = hist[2 * t], v1 = hist[2 * t + 1];
    int pair = v0 + v1;
    int lane = t & 63, w = t >> 6;
    int incl = pair;
#pragma unroll
    for (int off = 1; off < 64; off <<= 1) {
        int u = __shfl_up(incl, off);
        if (lane >= off) incl += u;
    }
    if (lane == 63) wsum[w] = incl;
    __syncthreads();
    int wbase = 0;
#pragma unroll
    for (int i = 0; i < 4; ++i) if (i < w) wbase += wsum[i];
    int excl = wbase + incl - pair;
    __syncthreads();
    hist[2 * t]     = start + excl;
    hist[2 * t + 1] = start + excl + v0;
    int dst0 = (b << BSHIFT) + 2 * t;
    if (dst0 < N_)     rowptr[dst0]     = start + excl + v0;
    if (dst0 + 1 < N_) rowptr[dst0 + 1] = start + excl + v0 + v1;
    __syncthreads();
    {
        int i = start + t;
        for (; i + 1792 < end; i += 2048) {
            uint2 r[8];
#pragma unroll
            for (int j = 0; j < 8; ++j) r[j] = part[i + j * 256];
#pragma unroll
            for (int j = 0; j < 8; ++j) {
                int dl = r[j].x >> 20;
                int pos = atomicAdd(&hist[dl], 1);
                sorted[pos] = make_float2(__int_as_float((int)(r[j].x & 0xFFFFF)),
                                          __uint_as_float(r[j].y));
            }
        }
        for (; i < end; i += 256) {
            uint2 r = part[i];
            int dl = r.x >> 20;
            int pos = atomicAdd(&hist[dl], 1);
            sorted[pos] = make_float2(__int_as_float((int)(r.x & 0xFFFFF)),
                                      __uint_as_float(r.y));
        }
    }
}

// ---------------------------------------------------------------------------
// Fused gather-SpMM + attention, layer 1 (D=128). Wave per node,
// 16-deep main batches + looped masked 8-batch tail, 32-bit byte offsets.
// ---------------------------------------------------------------------------
__global__ __launch_bounds__(256) void fused1(
        const uint_t* __restrict__ selfp, const ushort_t* __restrict__ relft,
        const int* __restrict__ rowptr, const float2* __restrict__ sorted,
        const float* __restrict__ vk, const float* __restrict__ vq,
        const float* __restrict__ bias,
        uint_t* __restrict__ hout, float* __restrict__ attout, int M) {
    int wave = threadIdx.x >> 6;
    int lane = threadIdx.x & 63;
    int n = blockIdx.x * 4 + wave;
    if (n >= M) return;

    uint_t s2 = selfp[(size_t)n * 64 + lane];
    float sv0 = bf_lo(s2), sv1 = bf_hi(s2);
    float nb0 = 0.f, nb1 = 0.f;

    const int beg = (n > 0) ? rowptr[n - 1] : 0;
    const int end = rowptr[n];
    const int len = end - beg;
    const char* base = (const char*)relft;
    const uint_t lb = (uint_t)lane << 2;

    int e = beg;
    const int e16 = beg + (len & ~15);
    for (; e < e16; e += 16) {
        float2 swb[16];
#pragma unroll
        for (int j = 0; j < 16; ++j) swb[j] = sorted[e + j];
        uint_t vv[16];
#pragma unroll
        for (int j = 0; j < 16; ++j)
            vv[j] = *(const uint_t*)(base + (((uint_t)__float_as_uint(swb[j].x) << 8) | lb));
#pragma unroll
        for (int j = 0; j < 16; ++j) {
            nb0 = fmaf(swb[j].y, bf_lo(vv[j]), nb0);
            nb1 = fmaf(swb[j].y, bf_hi(vv[j]), nb1);
        }
    }
    for (; e < end; e += 8) {   // masked 8-batches (tail < 16 edges)
        float2 swb[8];
        float  wb[8];
#pragma unroll
        for (int j = 0; j < 8; ++j) {
            int idx = e + j;
            int cl  = idx < end ? idx : e;
            swb[j] = sorted[cl];
            wb[j]  = idx < end ? swb[j].y : 0.f;
        }
        uint_t vv[8];
#pragma unroll
        for (int j = 0; j < 8; ++j)
            vv[j] = *(const uint_t*)(base + (((uint_t)__float_as_uint(swb[j].x) << 8) | lb));
#pragma unroll
        for (int j = 0; j < 8; ++j) {
            nb0 = fmaf(wb[j], bf_lo(vv[j]), nb0);
            nb1 = fmaf(wb[j], bf_hi(vv[j]), nb1);
        }
    }

    float2 k2 = ((const float2*)vk)[lane];
    float2 q2 = ((const float2*)vq)[lane];
    float sk = sv0 * k2.x + sv1 * k2.y;
    float sq = sv0 * q2.x + sv1 * q2.y;
    float nk = nb0 * k2.x + nb1 * k2.y;
#pragma unroll
    for (int off = 32; off; off >>= 1) {
        sk += __shfl_xor(sk, off);
        sq += __shfl_xor(sq, off);
        nk += __shfl_xor(nk, off);
    }
    float e0 = sk + sq;
    float e1 = nk + sq;
    e0 = e0 > 0.f ? e0 : expm1f(e0);
    e1 = e1 > 0.f ? e1 : expm1f(e1);
    float m = fmaxf(e0, e1);
    float a0 = expf(e0 - m);
    float a1 = expf(e1 - m);
    float inv = 1.f / (a0 + a1);
    a0 *= inv; a1 *= inv;

    float2 b2 = ((const float2*)bias)[lane];
    float o0 = fmaf(a0, sv0, fmaf(a1, nb0, b2.x));
    float o1 = fmaf(a0, sv1, fmaf(a1, nb1, b2.y));
    o0 = o0 > 0.f ? o0 : expm1f(o0);
    o1 = o1 > 0.f ? o1 : expm1f(o1);
    hout[(size_t)n * 64 + lane] = (uint_t)bf_bits(o0) | ((uint_t)bf_bits(o1) << 16);
    if (lane == 0) {
        attout[2 * (size_t)n + 0] = a0;
        attout[2 * (size_t)n + 1] = a1;
    }
}

// ---------------------------------------------------------------------------
// Fused gather-SpMM + attention, layer 2 (D=64). Same structure, 1 feat/lane.
// ---------------------------------------------------------------------------
__global__ __launch_bounds__(256) void fused2(
        const float* __restrict__ selfp, const ushort_t* __restrict__ relft,
        const int* __restrict__ rowptr, const float2* __restrict__ sorted,
        const float* __restrict__ vk, const float* __restrict__ vq,
        const float* __restrict__ bias,
        float* __restrict__ hout, float* __restrict__ attout, int M) {
    int wave = threadIdx.x >> 6;
    int lane = threadIdx.x & 63;
    int n = blockIdx.x * 4 + wave;
    if (n >= M) return;

    float sv = selfp[(size_t)n * 64 + lane];
    float nb = 0.f;

    const int beg = (n > 0) ? rowptr[n - 1] : 0;
    const int end = rowptr[n];
    const int len = end - beg;
    const char* base = (const char*)relft;
    const uint_t lb = (uint_t)lane << 1;

    int e = beg;
    const int e16 = beg + (len & ~15);
    for (; e < e16; e += 16) {
        float2 swb[16];
#pragma unroll
        for (int j = 0; j < 16; ++j) swb[j] = sorted[e + j];
        ushort_t vv[16];
#pragma unroll
        for (int j = 0; j < 16; ++j)
            vv[j] = *(const ushort_t*)(base + (((uint_t)__float_as_uint(swb[j].x) << 7) | lb));
#pragma unroll
        for (int j = 0; j < 16; ++j) nb = fmaf(swb[j].y, bf_one(vv[j]), nb);
    }
    for (; e < end; e += 8) {
        float2 swb[8];
        float  wb[8];
#pragma unroll
        for (int j = 0; j < 8; ++j) {
            int idx = e + j;
            int cl  = idx < end ? idx : e;
            swb[j] = sorted[cl];
            wb[j]  = idx < end ? swb[j].y : 0.f;
        }
        ushort_t vv[8];
#pragma unroll
        for (int j = 0; j < 8; ++j)
            vv[j] = *(const ushort_t*)(base + (((uint_t)__float_as_uint(swb[j].x) << 7) | lb));
#pragma unroll
        for (int j = 0; j < 8; ++j) nb = fmaf(wb[j], bf_one(vv[j]), nb);
    }

    float kk = vk[lane], qq = vq[lane];
    float sk = sv * kk;
    float sq = sv * qq;
    float nk = nb * kk;
#pragma unroll
    for (int off = 32; off; off >>= 1) {
        sk += __shfl_xor(sk, off);
        sq += __shfl_xor(sq, off);
        nk += __shfl_xor(nk, off);
    }
    float e0 = sk + sq;
    float e1 = nk + sq;
    e0 = e0 > 0.f ? e0 : expm1f(e0);
    e1 = e1 > 0.f ? e1 : expm1f(e1);
    float m = fmaxf(e0, e1);
    float a0 = expf(e0 - m);
    float a1 = expf(e1 - m);
    float inv = 1.f / (a0 + a1);
    a0 *= inv; a1 *= inv;

    hout[(size_t)n * 64 + lane] = fmaf(a0, sv, fmaf(a1, nb, bias[lane]));
    if (lane == 0) {
        attout[2 * (size_t)n + 0] = a0;
        attout[2 * (size_t)n + 1] = a1;
    }
}

// ---------------------------------------------------------------------------
// Pool: register accumulation over sorted gid, flush on graph change.
// ---------------------------------------------------------------------------
__global__ __launch_bounds__(256) void pool_sum_v2(
        const float* __restrict__ h, const int* __restrict__ gid,
        float* __restrict__ sums, float* __restrict__ cnt, int M, int chunk) {
    int wave = threadIdx.x >> 6;
    int lane = threadIdx.x & 63;
    int wid  = blockIdx.x * 4 + wave;
    int beg  = wid * chunk;
    int end  = min(M, beg + chunk);
    if (beg >= end) return;

    int   cur_g = gid[beg];
    float acc   = 0.f;
    int   cl    = 0;
    for (int n = beg; n < end; ++n) {
        int g = gid[n];
        if (g != cur_g) {
            atomicAdd(&sums[(size_t)cur_g * D_OUT + lane], acc);
            if (lane == 0) atomicAdd(&cnt[cur_g], (float)cl);
            cur_g = g; acc = 0.f; cl = 0;
        }
        acc += h[(size_t)n * D_OUT + lane];
        ++cl;
    }
    atomicAdd(&sums[(size_t)cur_g * D_OUT + lane], acc);
    if (lane == 0) atomicAdd(&cnt[cur_g], (float)cl);
}

__global__ void pool_mlp(const float* __restrict__ sums, const float* __restrict__ cnt,
                         const float* __restrict__ w1, const float* __restrict__ b1,
                         const float* __restrict__ w2, const float* __restrict__ b2,
                         float* __restrict__ out) {
    int g = threadIdx.x;
    if (g >= NG) return;
    float c = fmaxf(cnt[g], 1.0f);
    float inv = 1.0f / c;
    float hg[D_OUT];
#pragma unroll
    for (int d = 0; d < D_OUT; ++d) hg[d] = sums[g * D_OUT + d] * inv;
    float acc = b2[0];
    for (int j = 0; j < D_OUT / 2; ++j) {
        float hid = b1[j];
#pragma unroll 8
        for (int d = 0; d < D_OUT; ++d) hid = fmaf(hg[d], w1[d * (D_OUT / 2) + j], hid);
        hid = fmaxf(hid, 0.f);
        acc = fmaf(hid, w2[j], acc);
    }
    out[g] = acc;
}

// ---------------------------------------------------------------------------
extern "C" void kernel_launch(void* const* d_in, const int* in_sizes, int n_in,
                              void* d_out, int out_size, void* d_ws, size_t ws_size,
                              hipStream_t stream) {
    const float* x       = (const float*)d_in[0];
    const int*   esrc    = (const int*)  d_in[1];
    const int*   edst    = (const int*)  d_in[2];
    const float* ew      = (const float*)d_in[3];
    const int*   gid     = (const int*)  d_in[4];
    const float* w_self1 = (const float*)d_in[5];
    const float* w_rel1  = (const float*)d_in[6];
    const float* bias1   = (const float*)d_in[7];
    const float* w_q1    = (const float*)d_in[8];
    const float* w_k1    = (const float*)d_in[9];
    const float* w_att1  = (const float*)d_in[10];
    const float* w_self2 = (const float*)d_in[11];
    const float* w_rel2  = (const float*)d_in[12];
    const float* bias2   = (const float*)d_in[13];
    const float* w_q2    = (const float*)d_in[14];
    const float* w_k2    = (const float*)d_in[15];
    const float* w_att2  = (const float*)d_in[16];
    const float* mlp_w1  = (const float*)d_in[17];
    const float* mlp_b1  = (const float*)d_in[18];
    const float* mlp_w2  = (const float*)d_in[19];
    const float* mlp_b2  = (const float*)d_in[20];

    const int N = in_sizes[0] / D_IN;
    const int E = in_sizes[1];

    float* out = (float*)d_out;
    float* out_embd = out;
    float* out_att1 = out + NG;
    float* out_att2 = out + NG + 2 * (size_t)N;

    // ---- Workspace layout (float units) ----
    float* ws = (float*)d_ws;
    size_t nf = (size_t)N;
    float* bufS = ws;                  // selfft1 bf16 (Nx128) -> selfft2 fp32 (Nx64)
    float* bufR = ws + nf * 64;        // relft1 bf16 (Nx128) -> relft2 bf16 (Nx64)
    float* bufH = ws + nf * 128;       // part[] during sort -> h1 bf16 -> h2 fp32
    uint2* part = (uint2*)bufH;        // E uint2, dead before fused1
    int* ip     = (int*)(ws + nf * 192);   // 16B aligned (nf*192*4 % 16 == 0)
    int* bh     = ip;                  // NB*NBLK (16B aligned for int4)
    int* rowptr = ip + NB * NBLK;      // N
    int* bb     = rowptr + N;          // 257
    size_t int_end = nf * 192 + (size_t)NB * NBLK + nf + 257;
    int_end = (int_end + 1) & ~(size_t)1;
    float2* sorted = (float2*)(ws + int_end);     // E float2
    float* small = ws + int_end + 2 * (size_t)E;
    float* vk1 = small + 0;
    float* vq1 = small + 128;
    float* vk2 = small + 256;
    float* vq2 = small + 320;
    float* sums = small + 384;
    float* cnt  = small + 384 + NG * D_OUT;
    ushort_t* wtb = (ushort_t*)(small + 384 + NG * D_OUT + NG);
    ushort_t* wt_s1 = wtb;
    ushort_t* wt_r1 = wtb + 16384;
    ushort_t* wt_s2 = wtb + 32768;
    ushort_t* wt_r2 = wtb + 40960;

    const int chunk = (E + NBLK - 1) / NBLK;
    const int nbuck = (N + (1 << BSHIFT) - 1) >> BSHIFT;
    const int nx    = (N + 63) / 64;

    // Phase A: part_hist ∥ prep_wt ∥ prep_att ∥ zero accumulators
    phaseA<<<NBLK + 192 + 2 + 1, 256, 0, stream>>>(
        edst, E, chunk, bh,
        w_self1, w_rel1, w_self2, w_rel2, wtb,
        w_q1, w_k1, w_att1, w_q2, w_k2, w_att2, small, sums);

    part_scan<<<1, 256, 0, stream>>>(bh, bb, E);

    // Phase B: part_scatter ∥ dual gemm1
    phaseB<<<NBLK + nx, 256, 0, stream>>>(
        esrc, edst, ew, E, chunk, bh, part,
        x, N, wt_s1, wt_r1, (void*)bufS, (ushort_t*)bufR);

    bucket_sort<<<nbuck, 256, 0, stream>>>(part, bb, rowptr, sorted, N);

    fused1<<<(N + 3) / 4, 256, 0, stream>>>(
        (const uint_t*)bufS, (const ushort_t*)bufR, rowptr, sorted,
        vk1, vq1, bias1, (uint_t*)bufH, out_att1, N);

    gemm2_kernel<<<nx, 256, 0, stream>>>(
        (const void*)bufH, N, wt_s2, wt_r2, (void*)bufS, (ushort_t*)bufR);

    fused2<<<(N + 3) / 4, 256, 0, stream>>>(
        bufS, (const ushort_t*)bufR, rowptr, sorted,
        vk2, vq2, bias2, bufH, out_att2, N);

    {
        int pblocks = 1024;
        int pchunk  = (N + pblocks * 4 - 1) / (pblocks * 4);
        pool_sum_v2<<<pblocks, 256, 0, stream>>>(bufH, gid, sums, cnt, N, pchunk);
    }
    pool_mlp<<<1, 64, 0, stream>>>(sums, cnt, mlp_w1, mlp_b1, mlp_w2, mlp_b2, out_embd);
}

// Round 10
// 304.111 us; speedup vs baseline: 14.5191x; 1.0660x over previous
//
#include <hip/hip_runtime.h>
#include <hip/hip_bf16.h>
#include <cstdint>
#include <cstddef>

static constexpr int D_IN  = 128;
static constexpr int D_HID = 128;
static constexpr int D_OUT = 64;
static constexpr int ATTD  = 64;
static constexpr int NG    = 64;
static constexpr int NB    = 256;   // coarse buckets (dst >> 9)
static constexpr int NBLK  = 256;   // partition blocks
static constexpr int BSHIFT = 9;    // 512 dst per bucket

typedef __attribute__((ext_vector_type(8))) short s16x8;
typedef __attribute__((ext_vector_type(4))) float f32x4;
typedef unsigned short ushort_t;
typedef unsigned int uint_t;

__device__ __forceinline__ unsigned short bf_bits(float f) {
    union { __hip_bfloat16 h; unsigned short u; } cv;
    cv.h = __float2bfloat16(f);
    return cv.u;
}
__device__ __forceinline__ float bf_lo(uint_t v) { return __uint_as_float(v << 16); }
__device__ __forceinline__ float bf_hi(uint_t v) { return __uint_as_float(v & 0xffff0000u); }
__device__ __forceinline__ float bf_one(unsigned short u) { return __uint_as_float(((uint_t)u) << 16); }

// ---------------------------------------------------------------------------
// MFMA bf16 dual GEMM body: ONE block computes both Oa = A@Wa and Ob = A@Wb.
// wt must hold 2*C*(K+8) ushorts.
// ---------------------------------------------------------------------------
template <int C, bool A32, bool OA_BF>
__device__ __forceinline__ void gemm_dual_body(ushort_t* wt, int bx,
        const void* __restrict__ A, int M,
        const ushort_t* __restrict__ WTa, const ushort_t* __restrict__ WTb,
        void* __restrict__ Oa, ushort_t* __restrict__ Ob) {
    constexpr int K = 128;
    constexpr int RS = K + 8;

    for (int idx = threadIdx.x; idx < 2 * C * (K / 8); idx += 256) {
        int half = idx >= C * (K / 8);
        int l = idx - half * C * (K / 8);
        int c  = l >> 4;          // K/8 == 16
        int kc = l & 15;
        const ushort_t* W = half ? WTb : WTa;
        *(uint4*)&wt[half * C * RS + c * RS + kc * 8] = *(const uint4*)&W[c * K + kc * 8];
    }
    __syncthreads();

    const int w    = threadIdx.x >> 6;
    const int lane = threadIdx.x & 63;
    const int row  = bx * 64 + w * 16 + (lane & 15);
    const int rowc = row < M ? row : (M - 1);
    const int kb   = (lane >> 4) * 8;

    s16x8 afr[4];
    if (A32) {
        const float* Af = (const float*)A + (size_t)rowc * K + kb;
#pragma unroll
        for (int ks = 0; ks < 4; ++ks) {
            float4 f0 = *(const float4*)(Af + ks * 32);
            float4 f1 = *(const float4*)(Af + ks * 32 + 4);
            s16x8 a;
            a[0] = (short)bf_bits(f0.x); a[1] = (short)bf_bits(f0.y);
            a[2] = (short)bf_bits(f0.z); a[3] = (short)bf_bits(f0.w);
            a[4] = (short)bf_bits(f1.x); a[5] = (short)bf_bits(f1.y);
            a[6] = (short)bf_bits(f1.z); a[7] = (short)bf_bits(f1.w);
            afr[ks] = a;
        }
    } else {
        const ushort_t* Ab = (const ushort_t*)A + (size_t)rowc * K + kb;
#pragma unroll
        for (int ks = 0; ks < 4; ++ks) afr[ks] = *(const s16x8*)(Ab + ks * 32);
    }

    const int colc = lane & 15;
    const int r0   = bx * 64 + w * 16 + (lane >> 4) * 4;

#pragma unroll
    for (int z = 0; z < 2; ++z) {
        const ushort_t* wz = wt + z * C * RS;
#pragma unroll
        for (int ct = 0; ct < C / 16; ++ct) {
            f32x4 acc = {0.f, 0.f, 0.f, 0.f};
            const int colb = ct * 16 + colc;
#pragma unroll
            for (int ks = 0; ks < 4; ++ks) {
                s16x8 b = *(const s16x8*)&wz[colb * RS + ks * 32 + kb];
                acc = __builtin_amdgcn_mfma_f32_16x16x32_bf16(afr[ks], b, acc, 0, 0, 0);
            }
            if (z == 0) {
                if (OA_BF) {
                    ushort_t* O = (ushort_t*)Oa;
#pragma unroll
                    for (int j = 0; j < 4; ++j)
                        if (r0 + j < M) O[(size_t)(r0 + j) * C + colb] = bf_bits(acc[j]);
                } else {
                    float* O = (float*)Oa;
#pragma unroll
                    for (int j = 0; j < 4; ++j)
                        if (r0 + j < M) O[(size_t)(r0 + j) * C + colb] = acc[j];
                }
            } else {
#pragma unroll
                for (int j = 0; j < 4; ++j)
                    if (r0 + j < M) Ob[(size_t)(r0 + j) * C + colb] = bf_bits(acc[j]);
            }
        }
    }
}

// Standalone dual GEMM (layer 2, C=64)
__global__ __launch_bounds__(256) void gemm2_kernel(
        const void* __restrict__ A, int M,
        const ushort_t* __restrict__ WTa, const ushort_t* __restrict__ WTb,
        void* __restrict__ Oa, ushort_t* __restrict__ Ob) {
    __shared__ ushort_t wt[2 * 64 * 136];
    gemm_dual_body<64, false, false>(wt, blockIdx.x, A, M, WTa, WTb, Oa, Ob);
}

// ---------------------------------------------------------------------------
// Phase A: [0,NBLK) part_hist | [NBLK,NBLK+192) prep_wt | +2 prep_att | +1 zero
// ---------------------------------------------------------------------------
__global__ __launch_bounds__(256) void phaseA(
        const int* __restrict__ edst, int E, int chunk, int* __restrict__ bh,
        const float* __restrict__ w_self1, const float* __restrict__ w_rel1,
        const float* __restrict__ w_self2, const float* __restrict__ w_rel2,
        ushort_t* __restrict__ wtb,
        const float* __restrict__ w_q1, const float* __restrict__ w_k1,
        const float* __restrict__ w_att1,
        const float* __restrict__ w_q2, const float* __restrict__ w_k2,
        const float* __restrict__ w_att2,
        float* __restrict__ small, float* __restrict__ zero_region) {
    __shared__ int h[NB];
    int bid = blockIdx.x;
    if (bid < NBLK) {
        h[threadIdx.x] = 0;
        __syncthreads();
        int beg = bid * chunk;
        int end = min(E, beg + chunk);
        for (int i = beg + threadIdx.x; i < end; i += 256)
            atomicAdd(&h[edst[i] >> BSHIFT], 1);
        __syncthreads();
        bh[threadIdx.x * NBLK + bid] = h[threadIdx.x];
    } else if (bid < NBLK + 192) {
        int idx = (bid - NBLK) * 256 + threadIdx.x;
        const float* src; int base, Cc;
        if (idx < 16384)      { src = w_self1; base = 0;     Cc = 128; }
        else if (idx < 32768) { src = w_rel1;  base = 16384; Cc = 128; }
        else if (idx < 40960) { src = w_self2; base = 32768; Cc = 64;  }
        else                  { src = w_rel2;  base = 40960; Cc = 64;  }
        int l = idx - base;
        int c = l >> 7;
        int k = l & 127;
        wtb[base + l] = bf_bits(src[k * Cc + c]);
    } else if (bid < NBLK + 194) {
        int idx = (bid - NBLK - 192) * 256 + threadIdx.x;
        if (idx < 384) {
            float acc = 0.f;
            if (idx < 128) {
                int d = idx;
                for (int a = 0; a < ATTD; ++a) acc += w_k1[d * ATTD + a] * w_att1[a];
                small[0 + d] = acc;
            } else if (idx < 256) {
                int d = idx - 128;
                for (int a = 0; a < ATTD; ++a) acc += w_q1[d * ATTD + a] * w_att1[ATTD + a];
                small[128 + d] = acc;
            } else if (idx < 320) {
                int d = idx - 256;
                for (int a = 0; a < ATTD; ++a) acc += w_k2[d * ATTD + a] * w_att2[a];
                small[256 + d] = acc;
            } else {
                int d = idx - 320;
                for (int a = 0; a < ATTD; ++a) acc += w_q2[d * ATTD + a] * w_att2[ATTD + a];
                small[320 + d] = acc;
            }
        }
    } else {
        for (int i = threadIdx.x; i < NG * D_OUT + NG; i += 256) zero_region[i] = 0.f;
    }
}

// single block, 256 threads, int4-vectorized two-pass scan.
__global__ void part_scan(int* __restrict__ bh, int* __restrict__ bb, int E) {
    __shared__ int wsum[4];
    int t = threadIdx.x;
    int4* row = (int4*)&bh[t * NBLK];
    int run = 0;
#pragma unroll 8
    for (int q = 0; q < NBLK / 4; ++q) {
        int4 v = row[q];
        int4 o;
        o.x = run;
        o.y = run + v.x;
        o.z = o.y + v.y;
        o.w = o.z + v.z;
        run = o.w + v.w;
        row[q] = o;
    }
    int lane = t & 63, w = t >> 6;
    int incl = run;
#pragma unroll
    for (int off = 1; off < 64; off <<= 1) {
        int u = __shfl_up(incl, off);
        if (lane >= off) incl += u;
    }
    if (lane == 63) wsum[w] = incl;
    __syncthreads();
    int wbase = 0;
#pragma unroll
    for (int i = 0; i < 4; ++i) if (i < w) wbase += wsum[i];
    int base = wbase + incl - run;
    bb[t] = base;
    if (t == 255) bb[256] = base + run;
#pragma unroll 8
    for (int q = 0; q < NBLK / 4; ++q) {
        int4 v = row[q];
        v.x += base; v.y += base; v.z += base; v.w += base;
        row[q] = v;
    }
}

// ---------------------------------------------------------------------------
// Phase B: coarse partition scatter (full GPU).
// ---------------------------------------------------------------------------
__global__ __launch_bounds__(256) void part_scatter(const int* __restrict__ src,
        const int* __restrict__ dst, const float* __restrict__ ew, int E, int chunk,
        const int* __restrict__ bh, uint2* __restrict__ part) {
    __shared__ int ofs[NB];
    ofs[threadIdx.x] = bh[threadIdx.x * NBLK + blockIdx.x];
    __syncthreads();
    int beg = blockIdx.x * chunk;
    int end = min(E, beg + chunk);
    for (int i = beg + threadIdx.x; i < end; i += 256) {
        int d = dst[i];
        int b = d >> BSHIFT;
        int pos = atomicAdd(&ofs[b], 1);
        part[pos] = make_uint2((uint_t)src[i] | ((uint_t)(d & 511) << 20),
                               __float_as_uint(ew[i]));
    }
}

// ---------------------------------------------------------------------------
// Phase C: [0,nbuck) bucket_sort | [nbuck, nbuck+nx) dual gemm1.
// bucket_sort alone leaves ~60 CUs idle; gemm1 fills them.
// ---------------------------------------------------------------------------
__global__ __launch_bounds__(256) void phaseC(
        const uint2* __restrict__ part, const int* __restrict__ bb,
        int* __restrict__ rowptr, float2* __restrict__ sorted, int N_, int nbuck,
        const float* __restrict__ x, int M,
        const ushort_t* __restrict__ wt_s1, const ushort_t* __restrict__ wt_r1,
        void* __restrict__ Oa, ushort_t* __restrict__ Ob) {
    __shared__ ushort_t smem[2 * 128 * 136];
    int bid = blockIdx.x;
    if (bid >= nbuck) {
        gemm_dual_body<128, true, true>(smem, bid - nbuck, x, M, wt_s1, wt_r1, Oa, Ob);
        return;
    }
    int* hist = (int*)smem;          // 512 ints
    int* wsum = (int*)smem + 512;    // 4 ints
    int b = bid;
    int t = threadIdx.x;
    int start = bb[b], end = bb[b + 1];
    hist[t] = 0; hist[t + 256] = 0;
    __syncthreads();
    {
        int i = start + t;
        for (; i + 1792 < end; i += 2048) {
            int k[8];
#pragma unroll
            for (int j = 0; j < 8; ++j) k[j] = part[i + j * 256].x >> 20;
#pragma unroll
            for (int j = 0; j < 8; ++j) atomicAdd(&hist[k[j]], 1);
        }
        for (; i < end; i += 256) atomicAdd(&hist[part[i].x >> 20], 1);
    }
    __syncthreads();
    int v0 = hist[2 * t], v1 = hist[2 * t + 1];
    int pair = v0 + v1;
    int lane = t & 63, w = t >> 6;
    int incl = pair;
#pragma unroll
    for (int off = 1; off < 64; off <<= 1) {
        int u = __shfl_up(incl, off);
        if (lane >= off) incl += u;
    }
    if (lane == 63) wsum[w] = incl;
    __syncthreads();
    int wbase = 0;
#pragma unroll
    for (int i = 0; i < 4; ++i) if (i < w) wbase += wsum[i];
    int excl = wbase + incl - pair;
    __syncthreads();
    hist[2 * t]     = start + excl;
    hist[2 * t + 1] = start + excl + v0;
    int dst0 = (b << BSHIFT) + 2 * t;
    if (dst0 < N_)     rowptr[dst0]     = start + excl + v0;
    if (dst0 + 1 < N_) rowptr[dst0 + 1] = start + excl + v0 + v1;
    __syncthreads();
    {
        int i = start + t;
        for (; i + 1792 < end; i += 2048) {
            uint2 r[8];
#pragma unroll
            for (int j = 0; j < 8; ++j) r[j] = part[i + j * 256];
#pragma unroll
            for (int j = 0; j < 8; ++j) {
                int dl = r[j].x >> 20;
                int pos = atomicAdd(&hist[dl], 1);
                sorted[pos] = make_float2(__int_as_float((int)(r[j].x & 0xFFFFF)),
                                          __uint_as_float(r[j].y));
            }
        }
        for (; i < end; i += 256) {
            uint2 r = part[i];
            int dl = r.x >> 20;
            int pos = atomicAdd(&hist[dl], 1);
            sorted[pos] = make_float2(__int_as_float((int)(r.x & 0xFFFFF)),
                                      __uint_as_float(r.y));
        }
    }
}

// ---------------------------------------------------------------------------
// Fused gather-SpMM + attention, layer 1 (D=128). Wave per node, 8-deep
// batches. Wave-uniform node id via readfirstlane -> meta loads go down the
// scalar (SMEM) path, freeing the vector-memory path for row gathers.
// ---------------------------------------------------------------------------
__global__ __launch_bounds__(256) void fused1(
        const uint_t* __restrict__ selfp, const ushort_t* __restrict__ relft,
        const int* __restrict__ rowptr, const float2* __restrict__ sorted,
        const float* __restrict__ vk, const float* __restrict__ vq,
        const float* __restrict__ bias,
        uint_t* __restrict__ hout, float* __restrict__ attout, int M) {
    const int wv   = __builtin_amdgcn_readfirstlane(threadIdx.x >> 6);
    const int lane = threadIdx.x & 63;
    const int n = blockIdx.x * 4 + wv;
    if (n >= M) return;

    uint_t s2 = selfp[(size_t)n * 64 + lane];
    float sv0 = bf_lo(s2), sv1 = bf_hi(s2);
    float nb0 = 0.f, nb1 = 0.f;

    const int beg = (n > 0) ? rowptr[n - 1] : 0;
    const int end = rowptr[n];
    const int len = end - beg;
    const char* base = (const char*)relft;
    const uint_t lb = (uint_t)lane << 2;

    int e = beg;
    const int efull = beg + (len & ~7);
    for (; e < efull; e += 8) {
        float2 swb[8];
#pragma unroll
        for (int j = 0; j < 8; ++j) swb[j] = sorted[e + j];
        uint_t vv[8];
#pragma unroll
        for (int j = 0; j < 8; ++j)
            vv[j] = *(const uint_t*)(base + (((uint_t)__float_as_uint(swb[j].x) << 8) | lb));
#pragma unroll
        for (int j = 0; j < 8; ++j) {
            nb0 = fmaf(swb[j].y, bf_lo(vv[j]), nb0);
            nb1 = fmaf(swb[j].y, bf_hi(vv[j]), nb1);
        }
    }
    if (e < end) {   // masked tail batch (1..7 edges)
        float2 swb[8];
        float  wb[8];
#pragma unroll
        for (int j = 0; j < 8; ++j) {
            int idx = e + j;
            int cl  = idx < end ? idx : e;
            swb[j] = sorted[cl];
            wb[j]  = idx < end ? swb[j].y : 0.f;
        }
        uint_t vv[8];
#pragma unroll
        for (int j = 0; j < 8; ++j)
            vv[j] = *(const uint_t*)(base + (((uint_t)__float_as_uint(swb[j].x) << 8) | lb));
#pragma unroll
        for (int j = 0; j < 8; ++j) {
            nb0 = fmaf(wb[j], bf_lo(vv[j]), nb0);
            nb1 = fmaf(wb[j], bf_hi(vv[j]), nb1);
        }
    }

    float2 k2 = ((const float2*)vk)[lane];
    float2 q2 = ((const float2*)vq)[lane];
    float sk = sv0 * k2.x + sv1 * k2.y;
    float sq = sv0 * q2.x + sv1 * q2.y;
    float nk = nb0 * k2.x + nb1 * k2.y;
#pragma unroll
    for (int off = 32; off; off >>= 1) {
        sk += __shfl_xor(sk, off);
        sq += __shfl_xor(sq, off);
        nk += __shfl_xor(nk, off);
    }
    float e0 = sk + sq;
    float e1 = nk + sq;
    e0 = e0 > 0.f ? e0 : expm1f(e0);
    e1 = e1 > 0.f ? e1 : expm1f(e1);
    float m = fmaxf(e0, e1);
    float a0 = expf(e0 - m);
    float a1 = expf(e1 - m);
    float inv = 1.f / (a0 + a1);
    a0 *= inv; a1 *= inv;

    float2 b2 = ((const float2*)bias)[lane];
    float o0 = fmaf(a0, sv0, fmaf(a1, nb0, b2.x));
    float o1 = fmaf(a0, sv1, fmaf(a1, nb1, b2.y));
    o0 = o0 > 0.f ? o0 : expm1f(o0);
    o1 = o1 > 0.f ? o1 : expm1f(o1);
    hout[(size_t)n * 64 + lane] = (uint_t)bf_bits(o0) | ((uint_t)bf_bits(o1) << 16);
    if (lane == 0) {
        attout[2 * (size_t)n + 0] = a0;
        attout[2 * (size_t)n + 1] = a1;
    }
}

// ---------------------------------------------------------------------------
// Fused gather-SpMM + attention, layer 2 (D=64). Same structure, 1 feat/lane.
// ---------------------------------------------------------------------------
__global__ __launch_bounds__(256) void fused2(
        const float* __restrict__ selfp, const ushort_t* __restrict__ relft,
        const int* __restrict__ rowptr, const float2* __restrict__ sorted,
        const float* __restrict__ vk, const float* __restrict__ vq,
        const float* __restrict__ bias,
        float* __restrict__ hout, float* __restrict__ attout, int M) {
    const int wv   = __builtin_amdgcn_readfirstlane(threadIdx.x >> 6);
    const int lane = threadIdx.x & 63;
    const int n = blockIdx.x * 4 + wv;
    if (n >= M) return;

    float sv = selfp[(size_t)n * 64 + lane];
    float nb = 0.f;

    const int beg = (n > 0) ? rowptr[n - 1] : 0;
    const int end = rowptr[n];
    const int len = end - beg;
    const char* base = (const char*)relft;
    const uint_t lb = (uint_t)lane << 1;

    int e = beg;
    const int efull = beg + (len & ~7);
    for (; e < efull; e += 8) {
        float2 swb[8];
#pragma unroll
        for (int j = 0; j < 8; ++j) swb[j] = sorted[e + j];
        ushort_t vv[8];
#pragma unroll
        for (int j = 0; j < 8; ++j)
            vv[j] = *(const ushort_t*)(base + (((uint_t)__float_as_uint(swb[j].x) << 7) | lb));
#pragma unroll
        for (int j = 0; j < 8; ++j) nb = fmaf(swb[j].y, bf_one(vv[j]), nb);
    }
    if (e < end) {
        float2 swb[8];
        float  wb[8];
#pragma unroll
        for (int j = 0; j < 8; ++j) {
            int idx = e + j;
            int cl  = idx < end ? idx : e;
            swb[j] = sorted[cl];
            wb[j]  = idx < end ? swb[j].y : 0.f;
        }
        ushort_t vv[8];
#pragma unroll
        for (int j = 0; j < 8; ++j)
            vv[j] = *(const ushort_t*)(base + (((uint_t)__float_as_uint(swb[j].x) << 7) | lb));
#pragma unroll
        for (int j = 0; j < 8; ++j) nb = fmaf(wb[j], bf_one(vv[j]), nb);
    }

    float kk = vk[lane], qq = vq[lane];
    float sk = sv * kk;
    float sq = sv * qq;
    float nk = nb * kk;
#pragma unroll
    for (int off = 32; off; off >>= 1) {
        sk += __shfl_xor(sk, off);
        sq += __shfl_xor(sq, off);
        nk += __shfl_xor(nk, off);
    }
    float e0 = sk + sq;
    float e1 = nk + sq;
    e0 = e0 > 0.f ? e0 : expm1f(e0);
    e1 = e1 > 0.f ? e1 : expm1f(e1);
    float m = fmaxf(e0, e1);
    float a0 = expf(e0 - m);
    float a1 = expf(e1 - m);
    float inv = 1.f / (a0 + a1);
    a0 *= inv; a1 *= inv;

    hout[(size_t)n * 64 + lane] = fmaf(a0, sv, fmaf(a1, nb, bias[lane]));
    if (lane == 0) {
        attout[2 * (size_t)n + 0] = a0;
        attout[2 * (size_t)n + 1] = a1;
    }
}

// ---------------------------------------------------------------------------
// Pool: register accumulation over sorted gid, flush on graph change.
// ---------------------------------------------------------------------------
__global__ __launch_bounds__(256) void pool_sum_v2(
        const float* __restrict__ h, const int* __restrict__ gid,
        float* __restrict__ sums, float* __restrict__ cnt, int M, int chunk) {
    int wave = threadIdx.x >> 6;
    int lane = threadIdx.x & 63;
    int wid  = blockIdx.x * 4 + wave;
    int beg  = wid * chunk;
    int end  = min(M, beg + chunk);
    if (beg >= end) return;

    int   cur_g = gid[beg];
    float acc   = 0.f;
    int   cl    = 0;
    for (int n = beg; n < end; ++n) {
        int g = gid[n];
        if (g != cur_g) {
            atomicAdd(&sums[(size_t)cur_g * D_OUT + lane], acc);
            if (lane == 0) atomicAdd(&cnt[cur_g], (float)cl);
            cur_g = g; acc = 0.f; cl = 0;
        }
        acc += h[(size_t)n * D_OUT + lane];
        ++cl;
    }
    atomicAdd(&sums[(size_t)cur_g * D_OUT + lane], acc);
    if (lane == 0) atomicAdd(&cnt[cur_g], (float)cl);
}

__global__ void pool_mlp(const float* __restrict__ sums, const float* __restrict__ cnt,
                         const float* __restrict__ w1, const float* __restrict__ b1,
                         const float* __restrict__ w2, const float* __restrict__ b2,
                         float* __restrict__ out) {
    int g = threadIdx.x;
    if (g >= NG) return;
    float c = fmaxf(cnt[g], 1.0f);
    float inv = 1.0f / c;
    float hg[D_OUT];
#pragma unroll
    for (int d = 0; d < D_OUT; ++d) hg[d] = sums[g * D_OUT + d] * inv;
    float acc = b2[0];
    for (int j = 0; j < D_OUT / 2; ++j) {
        float hid = b1[j];
#pragma unroll 8
        for (int d = 0; d < D_OUT; ++d) hid = fmaf(hg[d], w1[d * (D_OUT / 2) + j], hid);
        hid = fmaxf(hid, 0.f);
        acc = fmaf(hid, w2[j], acc);
    }
    out[g] = acc;
}

// ---------------------------------------------------------------------------
extern "C" void kernel_launch(void* const* d_in, const int* in_sizes, int n_in,
                              void* d_out, int out_size, void* d_ws, size_t ws_size,
                              hipStream_t stream) {
    const float* x       = (const float*)d_in[0];
    const int*   esrc    = (const int*)  d_in[1];
    const int*   edst    = (const int*)  d_in[2];
    const float* ew      = (const float*)d_in[3];
    const int*   gid     = (const int*)  d_in[4];
    const float* w_self1 = (const float*)d_in[5];
    const float* w_rel1  = (const float*)d_in[6];
    const float* bias1   = (const float*)d_in[7];
    const float* w_q1    = (const float*)d_in[8];
    const float* w_k1    = (const float*)d_in[9];
    const float* w_att1  = (const float*)d_in[10];
    const float* w_self2 = (const float*)d_in[11];
    const float* w_rel2  = (const float*)d_in[12];
    const float* bias2   = (const float*)d_in[13];
    const float* w_q2    = (const float*)d_in[14];
    const float* w_k2    = (const float*)d_in[15];
    const float* w_att2  = (const float*)d_in[16];
    const float* mlp_w1  = (const float*)d_in[17];
    const float* mlp_b1  = (const float*)d_in[18];
    const float* mlp_w2  = (const float*)d_in[19];
    const float* mlp_b2  = (const float*)d_in[20];

    const int N = in_sizes[0] / D_IN;
    const int E = in_sizes[1];

    float* out = (float*)d_out;
    float* out_embd = out;
    float* out_att1 = out + NG;
    float* out_att2 = out + NG + 2 * (size_t)N;

    // ---- Workspace layout (float units) ----
    float* ws = (float*)d_ws;
    size_t nf = (size_t)N;
    float* bufS = ws;                  // selfft1 bf16 (Nx128) -> selfft2 fp32 (Nx64)
    float* bufR = ws + nf * 64;        // relft1 bf16 (Nx128) -> relft2 bf16 (Nx64)
    float* bufH = ws + nf * 128;       // part[] during sort -> h1 bf16 -> h2 fp32
    uint2* part = (uint2*)bufH;        // E uint2, dead before fused1
    int* ip     = (int*)(ws + nf * 192);   // 16B aligned
    int* bh     = ip;                  // NB*NBLK (16B aligned for int4)
    int* rowptr = ip + NB * NBLK;      // N
    int* bb     = rowptr + N;          // 257
    size_t int_end = nf * 192 + (size_t)NB * NBLK + nf + 257;
    int_end = (int_end + 1) & ~(size_t)1;
    float2* sorted = (float2*)(ws + int_end);     // E float2
    float* small = ws + int_end + 2 * (size_t)E;
    float* vk1 = small + 0;
    float* vq1 = small + 128;
    float* vk2 = small + 256;
    float* vq2 = small + 320;
    float* sums = small + 384;
    float* cnt  = small + 384 + NG * D_OUT;
    ushort_t* wtb = (ushort_t*)(small + 384 + NG * D_OUT + NG);
    ushort_t* wt_s1 = wtb;
    ushort_t* wt_r1 = wtb + 16384;
    ushort_t* wt_s2 = wtb + 32768;
    ushort_t* wt_r2 = wtb + 40960;

    const int chunk = (E + NBLK - 1) / NBLK;
    const int nbuck = (N + (1 << BSHIFT) - 1) >> BSHIFT;
    const int nx    = (N + 63) / 64;

    // Phase A: part_hist ∥ prep_wt ∥ prep_att ∥ zero accumulators
    phaseA<<<NBLK + 192 + 2 + 1, 256, 0, stream>>>(
        edst, E, chunk, bh,
        w_self1, w_rel1, w_self2, w_rel2, wtb,
        w_q1, w_k1, w_att1, w_q2, w_k2, w_att2, small, sums);

    part_scan<<<1, 256, 0, stream>>>(bh, bb, E);

    // Phase B: coarse partition scatter (full GPU)
    part_scatter<<<NBLK, 256, 0, stream>>>(esrc, edst, ew, E, chunk, bh, part);

    // Phase C: bucket_sort ∥ dual gemm1
    phaseC<<<nbuck + nx, 256, 0, stream>>>(
        part, bb, rowptr, sorted, N, nbuck,
        x, N, wt_s1, wt_r1, (void*)bufS, (ushort_t*)bufR);

    fused1<<<(N + 3) / 4, 256, 0, stream>>>(
        (const uint_t*)bufS, (const ushort_t*)bufR, rowptr, sorted,
        vk1, vq1, bias1, (uint_t*)bufH, out_att1, N);

    gemm2_kernel<<<nx, 256, 0, stream>>>(
        (const void*)bufH, N, wt_s2, wt_r2, (void*)bufS, (ushort_t*)bufR);

    fused2<<<(N + 3) / 4, 256, 0, stream>>>(
        bufS, (const ushort_t*)bufR, rowptr, sorted,
        vk2, vq2, bias2, bufH, out_att2, N);

    {
        int pblocks = 1024;
        int pchunk  = (N + pblocks * 4 - 1) / (pblocks * 4);
        pool_sum_v2<<<pblocks, 256, 0, stream>>>(bufH, gid, sums, cnt, N, pchunk);
    }
    pool_mlp<<<1, 64, 0, stream>>>(sums, cnt, mlp_w1, mlp_b1, mlp_w2, mlp_b2, out_embd);
}

// Round 11
// 304.057 us; speedup vs baseline: 14.5217x; 1.0002x over previous
//
#include <hip/hip_runtime.h>
#include <hip/hip_bf16.h>
#include <cstdint>
#include <cstddef>

static constexpr int D_IN  = 128;
static constexpr int D_HID = 128;
static constexpr int D_OUT = 64;
static constexpr int ATTD  = 64;
static constexpr int NG    = 64;
static constexpr int NB    = 256;   // coarse buckets (dst >> 9)
static constexpr int NBLK  = 256;   // partition blocks
static constexpr int BSHIFT = 9;    // 512 dst per bucket

typedef __attribute__((ext_vector_type(8))) short s16x8;
typedef __attribute__((ext_vector_type(4))) float f32x4;
typedef unsigned short ushort_t;
typedef unsigned int uint_t;

__device__ __forceinline__ unsigned short bf_bits(float f) {
    union { __hip_bfloat16 h; unsigned short u; } cv;
    cv.h = __float2bfloat16(f);
    return cv.u;
}
__device__ __forceinline__ float bf_lo(uint_t v) { return __uint_as_float(v << 16); }
__device__ __forceinline__ float bf_hi(uint_t v) { return __uint_as_float(v & 0xffff0000u); }
__device__ __forceinline__ float bf_one(unsigned short u) { return __uint_as_float(((uint_t)u) << 16); }

// ---------------------------------------------------------------------------
// MFMA bf16 dual GEMM body (C=128, layer 1): ONE block computes both
// Oa = A@Wa (bf16 out) and Ob = A@Wb (bf16 out). wt holds 2*C*(K+8) ushorts.
// ---------------------------------------------------------------------------
template <int C, bool A32, bool OA_BF>
__device__ __forceinline__ void gemm_dual_body(ushort_t* wt, int bx,
        const void* __restrict__ A, int M,
        const ushort_t* __restrict__ WTa, const ushort_t* __restrict__ WTb,
        void* __restrict__ Oa, ushort_t* __restrict__ Ob) {
    constexpr int K = 128;
    constexpr int RS = K + 8;

    for (int idx = threadIdx.x; idx < 2 * C * (K / 8); idx += 256) {
        int half = idx >= C * (K / 8);
        int l = idx - half * C * (K / 8);
        int c  = l >> 4;          // K/8 == 16
        int kc = l & 15;
        const ushort_t* W = half ? WTb : WTa;
        *(uint4*)&wt[half * C * RS + c * RS + kc * 8] = *(const uint4*)&W[c * K + kc * 8];
    }
    __syncthreads();

    const int w    = threadIdx.x >> 6;
    const int lane = threadIdx.x & 63;
    const int row  = bx * 64 + w * 16 + (lane & 15);
    const int rowc = row < M ? row : (M - 1);
    const int kb   = (lane >> 4) * 8;

    s16x8 afr[4];
    if (A32) {
        const float* Af = (const float*)A + (size_t)rowc * K + kb;
#pragma unroll
        for (int ks = 0; ks < 4; ++ks) {
            float4 f0 = *(const float4*)(Af + ks * 32);
            float4 f1 = *(const float4*)(Af + ks * 32 + 4);
            s16x8 a;
            a[0] = (short)bf_bits(f0.x); a[1] = (short)bf_bits(f0.y);
            a[2] = (short)bf_bits(f0.z); a[3] = (short)bf_bits(f0.w);
            a[4] = (short)bf_bits(f1.x); a[5] = (short)bf_bits(f1.y);
            a[6] = (short)bf_bits(f1.z); a[7] = (short)bf_bits(f1.w);
            afr[ks] = a;
        }
    } else {
        const ushort_t* Ab = (const ushort_t*)A + (size_t)rowc * K + kb;
#pragma unroll
        for (int ks = 0; ks < 4; ++ks) afr[ks] = *(const s16x8*)(Ab + ks * 32);
    }

    const int colc = lane & 15;
    const int r0   = bx * 64 + w * 16 + (lane >> 4) * 4;

#pragma unroll
    for (int z = 0; z < 2; ++z) {
        const ushort_t* wz = wt + z * C * RS;
#pragma unroll
        for (int ct = 0; ct < C / 16; ++ct) {
            f32x4 acc = {0.f, 0.f, 0.f, 0.f};
            const int colb = ct * 16 + colc;
#pragma unroll
            for (int ks = 0; ks < 4; ++ks) {
                s16x8 b = *(const s16x8*)&wz[colb * RS + ks * 32 + kb];
                acc = __builtin_amdgcn_mfma_f32_16x16x32_bf16(afr[ks], b, acc, 0, 0, 0);
            }
            if (z == 0) {
                if (OA_BF) {
                    ushort_t* O = (ushort_t*)Oa;
#pragma unroll
                    for (int j = 0; j < 4; ++j)
                        if (r0 + j < M) O[(size_t)(r0 + j) * C + colb] = bf_bits(acc[j]);
                } else {
                    float* O = (float*)Oa;
#pragma unroll
                    for (int j = 0; j < 4; ++j)
                        if (r0 + j < M) O[(size_t)(r0 + j) * C + colb] = acc[j];
                }
            } else {
#pragma unroll
                for (int j = 0; j < 4; ++j)
                    if (r0 + j < M) Ob[(size_t)(r0 + j) * C + colb] = bf_bits(acc[j]);
            }
        }
    }
}

// ---------------------------------------------------------------------------
// Phase A: [0,NBLK) part_hist | [NBLK,NBLK+192) prep_wt | +2 prep_att | +1 zero
// ---------------------------------------------------------------------------
__global__ __launch_bounds__(256) void phaseA(
        const int* __restrict__ edst, int E, int chunk, int* __restrict__ bh,
        const float* __restrict__ w_self1, const float* __restrict__ w_rel1,
        const float* __restrict__ w_self2, const float* __restrict__ w_rel2,
        ushort_t* __restrict__ wtb,
        const float* __restrict__ w_q1, const float* __restrict__ w_k1,
        const float* __restrict__ w_att1,
        const float* __restrict__ w_q2, const float* __restrict__ w_k2,
        const float* __restrict__ w_att2,
        float* __restrict__ small, float* __restrict__ zero_region) {
    __shared__ int h[NB];
    int bid = blockIdx.x;
    if (bid < NBLK) {
        h[threadIdx.x] = 0;
        __syncthreads();
        int beg = bid * chunk;
        int end = min(E, beg + chunk);
        for (int i = beg + threadIdx.x; i < end; i += 256)
            atomicAdd(&h[edst[i] >> BSHIFT], 1);
        __syncthreads();
        bh[threadIdx.x * NBLK + bid] = h[threadIdx.x];
    } else if (bid < NBLK + 192) {
        int idx = (bid - NBLK) * 256 + threadIdx.x;
        const float* src; int base, Cc;
        if (idx < 16384)      { src = w_self1; base = 0;     Cc = 128; }
        else if (idx < 32768) { src = w_rel1;  base = 16384; Cc = 128; }
        else if (idx < 40960) { src = w_self2; base = 32768; Cc = 64;  }
        else                  { src = w_rel2;  base = 40960; Cc = 64;  }
        int l = idx - base;
        int c = l >> 7;
        int k = l & 127;
        wtb[base + l] = bf_bits(src[k * Cc + c]);
    } else if (bid < NBLK + 194) {
        int idx = (bid - NBLK - 192) * 256 + threadIdx.x;
        if (idx < 384) {
            float acc = 0.f;
            if (idx < 128) {
                int d = idx;
                for (int a = 0; a < ATTD; ++a) acc += w_k1[d * ATTD + a] * w_att1[a];
                small[0 + d] = acc;
            } else if (idx < 256) {
                int d = idx - 128;
                for (int a = 0; a < ATTD; ++a) acc += w_q1[d * ATTD + a] * w_att1[ATTD + a];
                small[128 + d] = acc;
            } else if (idx < 320) {
                int d = idx - 256;
                for (int a = 0; a < ATTD; ++a) acc += w_k2[d * ATTD + a] * w_att2[a];
                small[256 + d] = acc;
            } else {
                int d = idx - 320;
                for (int a = 0; a < ATTD; ++a) acc += w_q2[d * ATTD + a] * w_att2[ATTD + a];
                small[320 + d] = acc;
            }
        }
    } else {
        for (int i = threadIdx.x; i < NG * D_OUT + NG; i += 256) zero_region[i] = 0.f;
    }
}

// single block, 256 threads, int4-vectorized two-pass scan.
__global__ void part_scan(int* __restrict__ bh, int* __restrict__ bb, int E) {
    __shared__ int wsum[4];
    int t = threadIdx.x;
    int4* row = (int4*)&bh[t * NBLK];
    int run = 0;
#pragma unroll 8
    for (int q = 0; q < NBLK / 4; ++q) {
        int4 v = row[q];
        int4 o;
        o.x = run;
        o.y = run + v.x;
        o.z = o.y + v.y;
        o.w = o.z + v.z;
        run = o.w + v.w;
        row[q] = o;
    }
    int lane = t & 63, w = t >> 6;
    int incl = run;
#pragma unroll
    for (int off = 1; off < 64; off <<= 1) {
        int u = __shfl_up(incl, off);
        if (lane >= off) incl += u;
    }
    if (lane == 63) wsum[w] = incl;
    __syncthreads();
    int wbase = 0;
#pragma unroll
    for (int i = 0; i < 4; ++i) if (i < w) wbase += wsum[i];
    int base = wbase + incl - run;
    bb[t] = base;
    if (t == 255) bb[256] = base + run;
#pragma unroll 8
    for (int q = 0; q < NBLK / 4; ++q) {
        int4 v = row[q];
        v.x += base; v.y += base; v.z += base; v.w += base;
        row[q] = v;
    }
}

// ---------------------------------------------------------------------------
// Phase B: coarse partition scatter (full GPU).
// ---------------------------------------------------------------------------
__global__ __launch_bounds__(256) void part_scatter(const int* __restrict__ src,
        const int* __restrict__ dst, const float* __restrict__ ew, int E, int chunk,
        const int* __restrict__ bh, uint2* __restrict__ part) {
    __shared__ int ofs[NB];
    ofs[threadIdx.x] = bh[threadIdx.x * NBLK + blockIdx.x];
    __syncthreads();
    int beg = blockIdx.x * chunk;
    int end = min(E, beg + chunk);
    for (int i = beg + threadIdx.x; i < end; i += 256) {
        int d = dst[i];
        int b = d >> BSHIFT;
        int pos = atomicAdd(&ofs[b], 1);
        part[pos] = make_uint2((uint_t)src[i] | ((uint_t)(d & 511) << 20),
                               __float_as_uint(ew[i]));
    }
}

// ---------------------------------------------------------------------------
// Phase C: [0,nbuck) bucket_sort | [nbuck, nbuck+nx) dual gemm1.
// ---------------------------------------------------------------------------
__global__ __launch_bounds__(256) void phaseC(
        const uint2* __restrict__ part, const int* __restrict__ bb,
        int* __restrict__ rowptr, float2* __restrict__ sorted, int N_, int nbuck,
        const float* __restrict__ x, int M,
        const ushort_t* __restrict__ wt_s1, const ushort_t* __restrict__ wt_r1,
        void* __restrict__ Oa, ushort_t* __restrict__ Ob) {
    __shared__ ushort_t smem[2 * 128 * 136];
    int bid = blockIdx.x;
    if (bid >= nbuck) {
        gemm_dual_body<128, true, true>(smem, bid - nbuck, x, M, wt_s1, wt_r1, Oa, Ob);
        return;
    }
    int* hist = (int*)smem;          // 512 ints
    int* wsum = (int*)smem + 512;    // 4 ints
    int b = bid;
    int t = threadIdx.x;
    int start = bb[b], end = bb[b + 1];
    hist[t] = 0; hist[t + 256] = 0;
    __syncthreads();
    {
        int i = start + t;
        for (; i + 1792 < end; i += 2048) {
            int k[8];
#pragma unroll
            for (int j = 0; j < 8; ++j) k[j] = part[i + j * 256].x >> 20;
#pragma unroll
            for (int j = 0; j < 8; ++j) atomicAdd(&hist[k[j]], 1);
        }
        for (; i < end; i += 256) atomicAdd(&hist[part[i].x >> 20], 1);
    }
    __syncthreads();
    int v0 = hist[2 * t], v1 = hist[2 * t + 1];
    int pair = v0 + v1;
    int lane = t & 63, w = t >> 6;
    int incl = pair;
#pragma unroll
    for (int off = 1; off < 64; off <<= 1) {
        int u = __shfl_up(incl, off);
        if (lane >= off) incl += u;
    }
    if (lane == 63) wsum[w] = incl;
    __syncthreads();
    int wbase = 0;
#pragma unroll
    for (int i = 0; i < 4; ++i) if (i < w) wbase += wsum[i];
    int excl = wbase + incl - pair;
    __syncthreads();
    hist[2 * t]     = start + excl;
    hist[2 * t + 1] = start + excl + v0;
    int dst0 = (b << BSHIFT) + 2 * t;
    if (dst0 < N_)     rowptr[dst0]     = start + excl + v0;
    if (dst0 + 1 < N_) rowptr[dst0 + 1] = start + excl + v0 + v1;
    __syncthreads();
    {
        int i = start + t;
        for (; i + 1792 < end; i += 2048) {
            uint2 r[8];
#pragma unroll
            for (int j = 0; j < 8; ++j) r[j] = part[i + j * 256];
#pragma unroll
            for (int j = 0; j < 8; ++j) {
                int dl = r[j].x >> 20;
                int pos = atomicAdd(&hist[dl], 1);
                sorted[pos] = make_float2(__int_as_float((int)(r[j].x & 0xFFFFF)),
                                          __uint_as_float(r[j].y));
            }
        }
        for (; i < end; i += 256) {
            uint2 r = part[i];
            int dl = r.x >> 20;
            int pos = atomicAdd(&hist[dl], 1);
            sorted[pos] = make_float2(__int_as_float((int)(r.x & 0xFFFFF)),
                                      __uint_as_float(r.y));
        }
    }
}

// ---------------------------------------------------------------------------
// fused1m: gather-SpMM + attention (layer 1) + FUSED layer-2 dual GEMM.
// 16 waves/block = 16 nodes = one MFMA A-tile. Per wave: gather + attention
// (round-10 structure, scalar meta path), deposit packed h1 row into LDS,
// barrier, then 8 waves MFMA h1-tile @ {w_self2, w_rel2} -> selfft2, relft2.
// h1 never touches global memory; gemm2 kernel is eliminated.
// ---------------------------------------------------------------------------
__global__ __launch_bounds__(1024) void fused1m(
        const uint_t* __restrict__ selfp, const ushort_t* __restrict__ relft,
        const int* __restrict__ rowptr, const float2* __restrict__ sorted,
        const float* __restrict__ vk, const float* __restrict__ vq,
        const float* __restrict__ bias,
        const ushort_t* __restrict__ wt_s2, const ushort_t* __restrict__ wt_r2,
        float* __restrict__ oS, ushort_t* __restrict__ oR,
        float* __restrict__ attout, int M) {
    constexpr int RS = 136;
    __shared__ ushort_t wt[2 * 64 * RS];   // 34.8 KB: w_self2 | w_rel2 (transposed, padded)
    __shared__ uint_t h1s[16 * 68];        // 4.3 KB: 16 packed h1 rows, +pad

    const int tid = threadIdx.x;
    // stage layer-2 weights (barrier below covers these writes)
    for (int idx = tid; idx < 2 * 64 * 16; idx += 1024) {
        int half = idx >= 64 * 16;
        int l = idx - half * 64 * 16;
        int c = l >> 4, kc = l & 15;
        const ushort_t* W = half ? wt_r2 : wt_s2;
        *(uint4*)&wt[half * 64 * RS + c * RS + kc * 8] = *(const uint4*)&W[c * 128 + kc * 8];
    }

    const int wv   = __builtin_amdgcn_readfirstlane(tid >> 6);
    const int lane = tid & 63;
    const int n = blockIdx.x * 16 + wv;

    if (n < M) {
        uint_t s2 = selfp[(size_t)n * 64 + lane];
        float sv0 = bf_lo(s2), sv1 = bf_hi(s2);
        float nb0 = 0.f, nb1 = 0.f;

        const int beg = (n > 0) ? rowptr[n - 1] : 0;
        const int end = rowptr[n];
        const int len = end - beg;
        const char* base = (const char*)relft;
        const uint_t lb = (uint_t)lane << 2;

        int e = beg;
        const int efull = beg + (len & ~7);
        for (; e < efull; e += 8) {
            float2 swb[8];
#pragma unroll
            for (int j = 0; j < 8; ++j) swb[j] = sorted[e + j];
            uint_t vv[8];
#pragma unroll
            for (int j = 0; j < 8; ++j)
                vv[j] = *(const uint_t*)(base + (((uint_t)__float_as_uint(swb[j].x) << 8) | lb));
#pragma unroll
            for (int j = 0; j < 8; ++j) {
                nb0 = fmaf(swb[j].y, bf_lo(vv[j]), nb0);
                nb1 = fmaf(swb[j].y, bf_hi(vv[j]), nb1);
            }
        }
        if (e < end) {   // masked tail batch (1..7 edges)
            float2 swb[8];
            float  wb[8];
#pragma unroll
            for (int j = 0; j < 8; ++j) {
                int idx = e + j;
                int cl  = idx < end ? idx : e;
                swb[j] = sorted[cl];
                wb[j]  = idx < end ? swb[j].y : 0.f;
            }
            uint_t vv[8];
#pragma unroll
            for (int j = 0; j < 8; ++j)
                vv[j] = *(const uint_t*)(base + (((uint_t)__float_as_uint(swb[j].x) << 8) | lb));
#pragma unroll
            for (int j = 0; j < 8; ++j) {
                nb0 = fmaf(wb[j], bf_lo(vv[j]), nb0);
                nb1 = fmaf(wb[j], bf_hi(vv[j]), nb1);
            }
        }

        float2 k2 = ((const float2*)vk)[lane];
        float2 q2 = ((const float2*)vq)[lane];
        float sk = sv0 * k2.x + sv1 * k2.y;
        float sq = sv0 * q2.x + sv1 * q2.y;
        float nk = nb0 * k2.x + nb1 * k2.y;
#pragma unroll
        for (int off = 32; off; off >>= 1) {
            sk += __shfl_xor(sk, off);
            sq += __shfl_xor(sq, off);
            nk += __shfl_xor(nk, off);
        }
        float e0 = sk + sq;
        float e1 = nk + sq;
        e0 = e0 > 0.f ? e0 : expm1f(e0);
        e1 = e1 > 0.f ? e1 : expm1f(e1);
        float m = fmaxf(e0, e1);
        float a0 = expf(e0 - m);
        float a1 = expf(e1 - m);
        float inv = 1.f / (a0 + a1);
        a0 *= inv; a1 *= inv;

        float2 b2 = ((const float2*)bias)[lane];
        float o0 = fmaf(a0, sv0, fmaf(a1, nb0, b2.x));
        float o1 = fmaf(a0, sv1, fmaf(a1, nb1, b2.y));
        o0 = o0 > 0.f ? o0 : expm1f(o0);
        o1 = o1 > 0.f ? o1 : expm1f(o1);
        h1s[wv * 68 + lane] = (uint_t)bf_bits(o0) | ((uint_t)bf_bits(o1) << 16);
        if (lane == 0) {
            attout[2 * (size_t)n + 0] = a0;
            attout[2 * (size_t)n + 1] = a1;
        }
    } else {
        h1s[wv * 68 + lane] = 0;
    }
    __syncthreads();

    // MFMA stage: waves 0-7 compute the 8 (matrix, col-tile) outputs.
    if (wv < 8) {
        const int z  = wv >> 2;          // 0: w_self2, 1: w_rel2
        const int ct = wv & 3;           // col tile 0..3
        const ushort_t* wz = wt + z * 64 * RS;
        const int colb = ct * 16 + (lane & 15);
        const int kb   = (lane >> 4) * 8;
        s16x8 afr[4];
#pragma unroll
        for (int ks = 0; ks < 4; ++ks)
            afr[ks] = *(const s16x8*)&h1s[(lane & 15) * 68 + ks * 16 + (lane >> 4) * 4];
        f32x4 acc = {0.f, 0.f, 0.f, 0.f};
#pragma unroll
        for (int ks = 0; ks < 4; ++ks) {
            s16x8 b = *(const s16x8*)&wz[colb * RS + ks * 32 + kb];
            acc = __builtin_amdgcn_mfma_f32_16x16x32_bf16(afr[ks], b, acc, 0, 0, 0);
        }
        const int r0 = blockIdx.x * 16 + (lane >> 4) * 4;
        if (z == 0) {
#pragma unroll
            for (int j = 0; j < 4; ++j)
                if (r0 + j < M) oS[(size_t)(r0 + j) * 64 + colb] = acc[j];
        } else {
#pragma unroll
            for (int j = 0; j < 4; ++j)
                if (r0 + j < M) oR[(size_t)(r0 + j) * 64 + colb] = bf_bits(acc[j]);
        }
    }
}

// ---------------------------------------------------------------------------
// Fused gather-SpMM + attention, layer 2 (D=64). Wave per node, scalar meta.
// ---------------------------------------------------------------------------
__global__ __launch_bounds__(256) void fused2(
        const float* __restrict__ selfp, const ushort_t* __restrict__ relft,
        const int* __restrict__ rowptr, const float2* __restrict__ sorted,
        const float* __restrict__ vk, const float* __restrict__ vq,
        const float* __restrict__ bias,
        float* __restrict__ hout, float* __restrict__ attout, int M) {
    const int wv   = __builtin_amdgcn_readfirstlane(threadIdx.x >> 6);
    const int lane = threadIdx.x & 63;
    const int n = blockIdx.x * 4 + wv;
    if (n >= M) return;

    float sv = selfp[(size_t)n * 64 + lane];
    float nb = 0.f;

    const int beg = (n > 0) ? rowptr[n - 1] : 0;
    const int end = rowptr[n];
    const int len = end - beg;
    const char* base = (const char*)relft;
    const uint_t lb = (uint_t)lane << 1;

    int e = beg;
    const int efull = beg + (len & ~7);
    for (; e < efull; e += 8) {
        float2 swb[8];
#pragma unroll
        for (int j = 0; j < 8; ++j) swb[j] = sorted[e + j];
        ushort_t vv[8];
#pragma unroll
        for (int j = 0; j < 8; ++j)
            vv[j] = *(const ushort_t*)(base + (((uint_t)__float_as_uint(swb[j].x) << 7) | lb));
#pragma unroll
        for (int j = 0; j < 8; ++j) nb = fmaf(swb[j].y, bf_one(vv[j]), nb);
    }
    if (e < end) {
        float2 swb[8];
        float  wb[8];
#pragma unroll
        for (int j = 0; j < 8; ++j) {
            int idx = e + j;
            int cl  = idx < end ? idx : e;
            swb[j] = sorted[cl];
            wb[j]  = idx < end ? swb[j].y : 0.f;
        }
        ushort_t vv[8];
#pragma unroll
        for (int j = 0; j < 8; ++j)
            vv[j] = *(const ushort_t*)(base + (((uint_t)__float_as_uint(swb[j].x) << 7) | lb));
#pragma unroll
        for (int j = 0; j < 8; ++j) nb = fmaf(wb[j], bf_one(vv[j]), nb);
    }

    float kk = vk[lane], qq = vq[lane];
    float sk = sv * kk;
    float sq = sv * qq;
    float nk = nb * kk;
#pragma unroll
    for (int off = 32; off; off >>= 1) {
        sk += __shfl_xor(sk, off);
        sq += __shfl_xor(sq, off);
        nk += __shfl_xor(nk, off);
    }
    float e0 = sk + sq;
    float e1 = nk + sq;
    e0 = e0 > 0.f ? e0 : expm1f(e0);
    e1 = e1 > 0.f ? e1 : expm1f(e1);
    float m = fmaxf(e0, e1);
    float a0 = expf(e0 - m);
    float a1 = expf(e1 - m);
    float inv = 1.f / (a0 + a1);
    a0 *= inv; a1 *= inv;

    hout[(size_t)n * 64 + lane] = fmaf(a0, sv, fmaf(a1, nb, bias[lane]));
    if (lane == 0) {
        attout[2 * (size_t)n + 0] = a0;
        attout[2 * (size_t)n + 1] = a1;
    }
}

// ---------------------------------------------------------------------------
// Pool: register accumulation over sorted gid, flush on graph change.
// ---------------------------------------------------------------------------
__global__ __launch_bounds__(256) void pool_sum_v2(
        const float* __restrict__ h, const int* __restrict__ gid,
        float* __restrict__ sums, float* __restrict__ cnt, int M, int chunk) {
    int wave = threadIdx.x >> 6;
    int lane = threadIdx.x & 63;
    int wid  = blockIdx.x * 4 + wave;
    int beg  = wid * chunk;
    int end  = min(M, beg + chunk);
    if (beg >= end) return;

    int   cur_g = gid[beg];
    float acc   = 0.f;
    int   cl    = 0;
    for (int n = beg; n < end; ++n) {
        int g = gid[n];
        if (g != cur_g) {
            atomicAdd(&sums[(size_t)cur_g * D_OUT + lane], acc);
            if (lane == 0) atomicAdd(&cnt[cur_g], (float)cl);
            cur_g = g; acc = 0.f; cl = 0;
        }
        acc += h[(size_t)n * D_OUT + lane];
        ++cl;
    }
    atomicAdd(&sums[(size_t)cur_g * D_OUT + lane], acc);
    if (lane == 0) atomicAdd(&cnt[cur_g], (float)cl);
}

__global__ void pool_mlp(const float* __restrict__ sums, const float* __restrict__ cnt,
                         const float* __restrict__ w1, const float* __restrict__ b1,
                         const float* __restrict__ w2, const float* __restrict__ b2,
                         float* __restrict__ out) {
    int g = threadIdx.x;
    if (g >= NG) return;
    float c = fmaxf(cnt[g], 1.0f);
    float inv = 1.0f / c;
    float hg[D_OUT];
#pragma unroll
    for (int d = 0; d < D_OUT; ++d) hg[d] = sums[g * D_OUT + d] * inv;
    float acc = b2[0];
    for (int j = 0; j < D_OUT / 2; ++j) {
        float hid = b1[j];
#pragma unroll 8
        for (int d = 0; d < D_OUT; ++d) hid = fmaf(hg[d], w1[d * (D_OUT / 2) + j], hid);
        hid = fmaxf(hid, 0.f);
        acc = fmaf(hid, w2[j], acc);
    }
    out[g] = acc;
}

// ---------------------------------------------------------------------------
extern "C" void kernel_launch(void* const* d_in, const int* in_sizes, int n_in,
                              void* d_out, int out_size, void* d_ws, size_t ws_size,
                              hipStream_t stream) {
    const float* x       = (const float*)d_in[0];
    const int*   esrc    = (const int*)  d_in[1];
    const int*   edst    = (const int*)  d_in[2];
    const float* ew      = (const float*)d_in[3];
    const int*   gid     = (const int*)  d_in[4];
    const float* w_self1 = (const float*)d_in[5];
    const float* w_rel1  = (const float*)d_in[6];
    const float* bias1   = (const float*)d_in[7];
    const float* w_q1    = (const float*)d_in[8];
    const float* w_k1    = (const float*)d_in[9];
    const float* w_att1  = (const float*)d_in[10];
    const float* w_self2 = (const float*)d_in[11];
    const float* w_rel2  = (const float*)d_in[12];
    const float* bias2   = (const float*)d_in[13];
    const float* w_q2    = (const float*)d_in[14];
    const float* w_k2    = (const float*)d_in[15];
    const float* w_att2  = (const float*)d_in[16];
    const float* mlp_w1  = (const float*)d_in[17];
    const float* mlp_b1  = (const float*)d_in[18];
    const float* mlp_w2  = (const float*)d_in[19];
    const float* mlp_b2  = (const float*)d_in[20];

    const int N = in_sizes[0] / D_IN;
    const int E = in_sizes[1];

    float* out = (float*)d_out;
    float* out_embd = out;
    float* out_att1 = out + NG;
    float* out_att2 = out + NG + 2 * (size_t)N;

    // ---- Workspace layout (float units) ----
    // bufS: selfft1 bf16 (Nx128 = Nx64 uint) -> h2 fp32 (Nx64)
    // bufR: relft1 bf16 (Nx128)
    // bufH: part[] (E uint2) -> selfft2 fp32 (Nx64)
    // bufT: relft2 bf16 (Nx64 ushort)
    float* ws = (float*)d_ws;
    size_t nf = (size_t)N;
    float* bufS = ws;
    float* bufR = ws + nf * 64;
    float* bufH = ws + nf * 128;
    float* bufT = ws + nf * 192;       // N*32 floats
    uint2* part = (uint2*)bufH;        // E uint2 = 12.8MB <= N*64*4B
    int* ip     = (int*)(ws + nf * 224);
    int* bh     = ip;                  // NB*NBLK (16B aligned for int4)
    int* rowptr = ip + NB * NBLK;      // N
    int* bb     = rowptr + N;          // 257
    size_t int_end = nf * 224 + (size_t)NB * NBLK + nf + 257;
    int_end = (int_end + 1) & ~(size_t)1;
    float2* sorted = (float2*)(ws + int_end);     // E float2
    float* small = ws + int_end + 2 * (size_t)E;
    float* vk1 = small + 0;
    float* vq1 = small + 128;
    float* vk2 = small + 256;
    float* vq2 = small + 320;
    float* sums = small + 384;
    float* cnt  = small + 384 + NG * D_OUT;
    ushort_t* wtb = (ushort_t*)(small + 384 + NG * D_OUT + NG);
    ushort_t* wt_s1 = wtb;
    ushort_t* wt_r1 = wtb + 16384;
    ushort_t* wt_s2 = wtb + 32768;
    ushort_t* wt_r2 = wtb + 40960;

    const int chunk = (E + NBLK - 1) / NBLK;
    const int nbuck = (N + (1 << BSHIFT) - 1) >> BSHIFT;
    const int nx    = (N + 63) / 64;

    // Phase A: part_hist ∥ prep_wt ∥ prep_att ∥ zero accumulators
    phaseA<<<NBLK + 192 + 2 + 1, 256, 0, stream>>>(
        edst, E, chunk, bh,
        w_self1, w_rel1, w_self2, w_rel2, wtb,
        w_q1, w_k1, w_att1, w_q2, w_k2, w_att2, small, sums);

    part_scan<<<1, 256, 0, stream>>>(bh, bb, E);

    // Phase B: coarse partition scatter
    part_scatter<<<NBLK, 256, 0, stream>>>(esrc, edst, ew, E, chunk, bh, part);

    // Phase C: bucket_sort ∥ dual gemm1
    phaseC<<<nbuck + nx, 256, 0, stream>>>(
        part, bb, rowptr, sorted, N, nbuck,
        x, N, wt_s1, wt_r1, (void*)bufS, (ushort_t*)bufR);

    // fused1m: layer-1 gather+attention + fused layer-2 dual GEMM
    fused1m<<<(N + 15) / 16, 1024, 0, stream>>>(
        (const uint_t*)bufS, (const ushort_t*)bufR, rowptr, sorted,
        vk1, vq1, bias1, wt_s2, wt_r2,
        bufH, (ushort_t*)bufT, out_att1, N);

    // fused2: layer-2 gather+attention; h2 -> bufS
    fused2<<<(N + 3) / 4, 256, 0, stream>>>(
        bufH, (const ushort_t*)bufT, rowptr, sorted,
        vk2, vq2, bias2, bufS, out_att2, N);

    {
        int pblocks = 1024;
        int pchunk  = (N + pblocks * 4 - 1) / (pblocks * 4);
        pool_sum_v2<<<pblocks, 256, 0, stream>>>(bufS, gid, sums, cnt, N, pchunk);
    }
    pool_mlp<<<1, 64, 0, stream>>>(sums, cnt, mlp_w1, mlp_b1, mlp_w2, mlp_b2, out_embd);
}

// Round 12
// 273.299 us; speedup vs baseline: 16.1560x; 1.1125x over previous
//
#include <hip/hip_runtime.h>
#include <hip/hip_bf16.h>
#include <cstdint>
#include <cstddef>

static constexpr int D_IN  = 128;
static constexpr int D_HID = 128;
static constexpr int D_OUT = 64;
static constexpr int ATTD  = 64;
static constexpr int NG    = 64;
static constexpr int NB    = 256;   // coarse buckets (dst >> 9)
static constexpr int NBLK  = 256;   // partition blocks
static constexpr int BSHIFT = 9;    // 512 dst per bucket

typedef __attribute__((ext_vector_type(8))) short s16x8;
typedef __attribute__((ext_vector_type(4))) float f32x4;
typedef unsigned short ushort_t;
typedef unsigned int uint_t;

__device__ __forceinline__ unsigned short bf_bits(float f) {
    union { __hip_bfloat16 h; unsigned short u; } cv;
    cv.h = __float2bfloat16(f);
    return cv.u;
}
__device__ __forceinline__ float bf_lo(uint_t v) { return __uint_as_float(v << 16); }
__device__ __forceinline__ float bf_hi(uint_t v) { return __uint_as_float(v & 0xffff0000u); }
__device__ __forceinline__ float bf_one(unsigned short u) { return __uint_as_float(((uint_t)u) << 16); }

// ---------------------------------------------------------------------------
// MFMA bf16 dual GEMM body: ONE block computes both Oa = A@Wa and Ob = A@Wb.
// wt must hold 2*C*(K+8) ushorts.
// ---------------------------------------------------------------------------
template <int C, bool A32, bool OA_BF>
__device__ __forceinline__ void gemm_dual_body(ushort_t* wt, int bx,
        const void* __restrict__ A, int M,
        const ushort_t* __restrict__ WTa, const ushort_t* __restrict__ WTb,
        void* __restrict__ Oa, ushort_t* __restrict__ Ob) {
    constexpr int K = 128;
    constexpr int RS = K + 8;

    for (int idx = threadIdx.x; idx < 2 * C * (K / 8); idx += 256) {
        int half = idx >= C * (K / 8);
        int l = idx - half * C * (K / 8);
        int c  = l >> 4;          // K/8 == 16
        int kc = l & 15;
        const ushort_t* W = half ? WTb : WTa;
        *(uint4*)&wt[half * C * RS + c * RS + kc * 8] = *(const uint4*)&W[c * K + kc * 8];
    }
    __syncthreads();

    const int w    = threadIdx.x >> 6;
    const int lane = threadIdx.x & 63;
    const int row  = bx * 64 + w * 16 + (lane & 15);
    const int rowc = row < M ? row : (M - 1);
    const int kb   = (lane >> 4) * 8;

    s16x8 afr[4];
    if (A32) {
        const float* Af = (const float*)A + (size_t)rowc * K + kb;
#pragma unroll
        for (int ks = 0; ks < 4; ++ks) {
            float4 f0 = *(const float4*)(Af + ks * 32);
            float4 f1 = *(const float4*)(Af + ks * 32 + 4);
            s16x8 a;
            a[0] = (short)bf_bits(f0.x); a[1] = (short)bf_bits(f0.y);
            a[2] = (short)bf_bits(f0.z); a[3] = (short)bf_bits(f0.w);
            a[4] = (short)bf_bits(f1.x); a[5] = (short)bf_bits(f1.y);
            a[6] = (short)bf_bits(f1.z); a[7] = (short)bf_bits(f1.w);
            afr[ks] = a;
        }
    } else {
        const ushort_t* Ab = (const ushort_t*)A + (size_t)rowc * K + kb;
#pragma unroll
        for (int ks = 0; ks < 4; ++ks) afr[ks] = *(const s16x8*)(Ab + ks * 32);
    }

    const int colc = lane & 15;
    const int r0   = bx * 64 + w * 16 + (lane >> 4) * 4;

#pragma unroll
    for (int z = 0; z < 2; ++z) {
        const ushort_t* wz = wt + z * C * RS;
#pragma unroll
        for (int ct = 0; ct < C / 16; ++ct) {
            f32x4 acc = {0.f, 0.f, 0.f, 0.f};
            const int colb = ct * 16 + colc;
#pragma unroll
            for (int ks = 0; ks < 4; ++ks) {
                s16x8 b = *(const s16x8*)&wz[colb * RS + ks * 32 + kb];
                acc = __builtin_amdgcn_mfma_f32_16x16x32_bf16(afr[ks], b, acc, 0, 0, 0);
            }
            if (z == 0) {
                if (OA_BF) {
                    ushort_t* O = (ushort_t*)Oa;
#pragma unroll
                    for (int j = 0; j < 4; ++j)
                        if (r0 + j < M) O[(size_t)(r0 + j) * C + colb] = bf_bits(acc[j]);
                } else {
                    float* O = (float*)Oa;
#pragma unroll
                    for (int j = 0; j < 4; ++j)
                        if (r0 + j < M) O[(size_t)(r0 + j) * C + colb] = acc[j];
                }
            } else {
#pragma unroll
                for (int j = 0; j < 4; ++j)
                    if (r0 + j < M) Ob[(size_t)(r0 + j) * C + colb] = bf_bits(acc[j]);
            }
        }
    }
}

// Standalone dual GEMM (layer 2, C=64)
__global__ __launch_bounds__(256) void gemm2_kernel(
        const void* __restrict__ A, int M,
        const ushort_t* __restrict__ WTa, const ushort_t* __restrict__ WTb,
        void* __restrict__ Oa, ushort_t* __restrict__ Ob) {
    __shared__ ushort_t wt[2 * 64 * 136];
    gemm_dual_body<64, false, false>(wt, blockIdx.x, A, M, WTa, WTb, Oa, Ob);
}

// ---------------------------------------------------------------------------
// Phase A: [0,NBLK) part_hist | [NBLK,NBLK+192) prep_wt | +2 prep_att | +1 zero
// ---------------------------------------------------------------------------
__global__ __launch_bounds__(256) void phaseA(
        const int* __restrict__ edst, int E, int chunk, int* __restrict__ bh,
        const float* __restrict__ w_self1, const float* __restrict__ w_rel1,
        const float* __restrict__ w_self2, const float* __restrict__ w_rel2,
        ushort_t* __restrict__ wtb,
        const float* __restrict__ w_q1, const float* __restrict__ w_k1,
        const float* __restrict__ w_att1,
        const float* __restrict__ w_q2, const float* __restrict__ w_k2,
        const float* __restrict__ w_att2,
        float* __restrict__ small, float* __restrict__ zero_region,
        int* __restrict__ dctr) {
    __shared__ int h[NB];
    int bid = blockIdx.x;
    if (bid < NBLK) {
        h[threadIdx.x] = 0;
        __syncthreads();
        int beg = bid * chunk;
        int end = min(E, beg + chunk);
        for (int i = beg + threadIdx.x; i < end; i += 256)
            atomicAdd(&h[edst[i] >> BSHIFT], 1);
        __syncthreads();
        bh[threadIdx.x * NBLK + bid] = h[threadIdx.x];
    } else if (bid < NBLK + 192) {
        int idx = (bid - NBLK) * 256 + threadIdx.x;
        const float* src; int base, Cc;
        if (idx < 16384)      { src = w_self1; base = 0;     Cc = 128; }
        else if (idx < 32768) { src = w_rel1;  base = 16384; Cc = 128; }
        else if (idx < 40960) { src = w_self2; base = 32768; Cc = 64;  }
        else                  { src = w_rel2;  base = 40960; Cc = 64;  }
        int l = idx - base;
        int c = l >> 7;
        int k = l & 127;
        wtb[base + l] = bf_bits(src[k * Cc + c]);
    } else if (bid < NBLK + 194) {
        int idx = (bid - NBLK - 192) * 256 + threadIdx.x;
        if (idx < 384) {
            float acc = 0.f;
            if (idx < 128) {
                int d = idx;
                for (int a = 0; a < ATTD; ++a) acc += w_k1[d * ATTD + a] * w_att1[a];
                small[0 + d] = acc;
            } else if (idx < 256) {
                int d = idx - 128;
                for (int a = 0; a < ATTD; ++a) acc += w_q1[d * ATTD + a] * w_att1[ATTD + a];
                small[128 + d] = acc;
            } else if (idx < 320) {
                int d = idx - 256;
                for (int a = 0; a < ATTD; ++a) acc += w_k2[d * ATTD + a] * w_att2[a];
                small[256 + d] = acc;
            } else {
                int d = idx - 320;
                for (int a = 0; a < ATTD; ++a) acc += w_q2[d * ATTD + a] * w_att2[ATTD + a];
                small[320 + d] = acc;
            }
        }
    } else {
        for (int i = threadIdx.x; i < NG * D_OUT + NG; i += 256) zero_region[i] = 0.f;
        if (threadIdx.x == 0) *dctr = 0;
    }
}

// ---------------------------------------------------------------------------
// scanA: 256 blocks. Block t exclusive-scans bucket row bh[t][0..NBLK) in
// place and publishes its total via device atomics; the LAST finishing block
// performs the 256-entry cross-bucket exclusive scan -> bb[].
// (atomicExch / threadfence / atomicAdd handshake keeps it XCD-coherent.)
// ---------------------------------------------------------------------------
__global__ __launch_bounds__(256) void scanA(int* __restrict__ bh,
        int* __restrict__ bt, int* __restrict__ bb, int* __restrict__ dctr) {
    __shared__ int wsum[4];
    __shared__ int lastFlag;
    const int t = blockIdx.x;     // bucket
    const int i = threadIdx.x;    // partition block
    if (i == 0) lastFlag = 0;
    int v = bh[t * NBLK + i];
    int lane = i & 63, w = i >> 6;
    int incl = v;
#pragma unroll
    for (int off = 1; off < 64; off <<= 1) {
        int u = __shfl_up(incl, off);
        if (lane >= off) incl += u;
    }
    if (lane == 63) wsum[w] = incl;
    __syncthreads();
    int wbase = 0;
#pragma unroll
    for (int k = 0; k < 4; ++k) if (k < w) wbase += wsum[k];
    int excl = wbase + incl - v;
    bh[t * NBLK + i] = excl;
    __syncthreads();               // wsum reads done before potential reuse
    if (i == 255) {
        atomicExch(&bt[t], excl + v);     // bucket total, coherent
        __threadfence();
        int old = atomicAdd(dctr, 1);
        if (old == NBLK - 1) lastFlag = 1;
    }
    __syncthreads();
    if (lastFlag) {
        int vb = atomicAdd(&bt[i], 0);    // coherent read
        int incl2 = vb;
#pragma unroll
        for (int off = 1; off < 64; off <<= 1) {
            int u = __shfl_up(incl2, off);
            if (lane >= off) incl2 += u;
        }
        if (lane == 63) wsum[w] = incl2;
        __syncthreads();
        int wb2 = 0;
#pragma unroll
        for (int k = 0; k < 4; ++k) if (k < w) wb2 += wsum[k];
        int excl2 = wb2 + incl2 - vb;
        bb[i] = excl2;
        if (i == 255) bb[256] = excl2 + vb;
    }
}

// ---------------------------------------------------------------------------
// Phase B: [0,NBLK) part_scatter (adds bb[t] on the fly) | [NBLK,NBLK+g1) gemm1
// ---------------------------------------------------------------------------
__global__ __launch_bounds__(256) void phaseB(
        const int* __restrict__ src, const int* __restrict__ dst,
        const float* __restrict__ ew, int E, int chunk,
        const int* __restrict__ bh, const int* __restrict__ bb,
        uint2* __restrict__ part,
        const float* __restrict__ x, int M,
        const ushort_t* __restrict__ wt_s1, const ushort_t* __restrict__ wt_r1,
        void* __restrict__ Oa, ushort_t* __restrict__ Ob) {
    __shared__ ushort_t smem[2 * 128 * 136];
    int bid = blockIdx.x;
    if (bid < NBLK) {
        int* ofs = (int*)smem;
        ofs[threadIdx.x] = bh[threadIdx.x * NBLK + bid] + bb[threadIdx.x];
        __syncthreads();
        int beg = bid * chunk;
        int end = min(E, beg + chunk);
        for (int i = beg + threadIdx.x; i < end; i += 256) {
            int d = dst[i];
            int b = d >> BSHIFT;
            int pos = atomicAdd(&ofs[b], 1);
            part[pos] = make_uint2((uint_t)src[i] | ((uint_t)(d & 511) << 20),
                                   __float_as_uint(ew[i]));
        }
    } else {
        gemm_dual_body<128, true, true>(smem, bid - NBLK, x, M, wt_s1, wt_r1, Oa, Ob);
    }
}

// ---------------------------------------------------------------------------
// Phase C: [0,nbuck) bucket_sort | [nbuck, ...) gemm1 remainder (bx = g1+idx)
// ---------------------------------------------------------------------------
__global__ __launch_bounds__(256) void phaseC(
        const uint2* __restrict__ part, const int* __restrict__ bb,
        int* __restrict__ rowptr, float2* __restrict__ sorted, int N_, int nbuck,
        int g1,
        const float* __restrict__ x, int M,
        const ushort_t* __restrict__ wt_s1, const ushort_t* __restrict__ wt_r1,
        void* __restrict__ Oa, ushort_t* __restrict__ Ob) {
    __shared__ ushort_t smem[2 * 128 * 136];
    int bid = blockIdx.x;
    if (bid >= nbuck) {
        gemm_dual_body<128, true, true>(smem, g1 + (bid - nbuck), x, M, wt_s1, wt_r1, Oa, Ob);
        return;
    }
    int* hist = (int*)smem;          // 512 ints
    int* wsum = (int*)smem + 512;    // 4 ints
    int b = bid;
    int t = threadIdx.x;
    int start = bb[b], end = bb[b + 1];
    hist[t] = 0; hist[t + 256] = 0;
    __syncthreads();
    {
        int i = start + t;
        for (; i + 1792 < end; i += 2048) {
            int k[8];
#pragma unroll
            for (int j = 0; j < 8; ++j) k[j] = part[i + j * 256].x >> 20;
#pragma unroll
            for (int j = 0; j < 8; ++j) atomicAdd(&hist[k[j]], 1);
        }
        for (; i < end; i += 256) atomicAdd(&hist[part[i].x >> 20], 1);
    }
    __syncthreads();
    int v0 = hist[2 * t], v1 = hist[2 * t + 1];
    int pair = v0 + v1;
    int lane = t & 63, w = t >> 6;
    int incl = pair;
#pragma unroll
    for (int off = 1; off < 64; off <<= 1) {
        int u = __shfl_up(incl, off);
        if (lane >= off) incl += u;
    }
    if (lane == 63) wsum[w] = incl;
    __syncthreads();
    int wbase = 0;
#pragma unroll
    for (int i = 0; i < 4; ++i) if (i < w) wbase += wsum[i];
    int excl = wbase + incl - pair;
    __syncthreads();
    hist[2 * t]     = start + excl;
    hist[2 * t + 1] = start + excl + v0;
    int dst0 = (b << BSHIFT) + 2 * t;
    if (dst0 < N_)     rowptr[dst0]     = start + excl + v0;
    if (dst0 + 1 < N_) rowptr[dst0 + 1] = start + excl + v0 + v1;
    __syncthreads();
    {
        int i = start + t;
        for (; i + 1792 < end; i += 2048) {
            uint2 r[8];
#pragma unroll
            for (int j = 0; j < 8; ++j) r[j] = part[i + j * 256];
#pragma unroll
            for (int j = 0; j < 8; ++j) {
                int dl = r[j].x >> 20;
                int pos = atomicAdd(&hist[dl], 1);
                sorted[pos] = make_float2(__int_as_float((int)(r[j].x & 0xFFFFF)),
                                          __uint_as_float(r[j].y));
            }
        }
        for (; i < end; i += 256) {
            uint2 r = part[i];
            int dl = r.x >> 20;
            int pos = atomicAdd(&hist[dl], 1);
            sorted[pos] = make_float2(__int_as_float((int)(r.x & 0xFFFFF)),
                                      __uint_as_float(r.y));
        }
    }
}

// ---------------------------------------------------------------------------
// Fused gather-SpMM + attention, layer 1 (D=128). Wave per node, 8-deep
// batches, scalar (SMEM) meta path via wave-uniform node id.
// ---------------------------------------------------------------------------
__global__ __launch_bounds__(256) void fused1(
        const uint_t* __restrict__ selfp, const ushort_t* __restrict__ relft,
        const int* __restrict__ rowptr, const float2* __restrict__ sorted,
        const float* __restrict__ vk, const float* __restrict__ vq,
        const float* __restrict__ bias,
        uint_t* __restrict__ hout, float* __restrict__ attout, int M) {
    const int wv   = __builtin_amdgcn_readfirstlane(threadIdx.x >> 6);
    const int lane = threadIdx.x & 63;
    const int n = blockIdx.x * 4 + wv;
    if (n >= M) return;

    uint_t s2 = selfp[(size_t)n * 64 + lane];
    float sv0 = bf_lo(s2), sv1 = bf_hi(s2);
    float nb0 = 0.f, nb1 = 0.f;

    const int beg = (n > 0) ? rowptr[n - 1] : 0;
    const int end = rowptr[n];
    const int len = end - beg;
    const char* base = (const char*)relft;
    const uint_t lb = (uint_t)lane << 2;

    int e = beg;
    const int efull = beg + (len & ~7);
    for (; e < efull; e += 8) {
        float2 swb[8];
#pragma unroll
        for (int j = 0; j < 8; ++j) swb[j] = sorted[e + j];
        uint_t vv[8];
#pragma unroll
        for (int j = 0; j < 8; ++j)
            vv[j] = *(const uint_t*)(base + (((uint_t)__float_as_uint(swb[j].x) << 8) | lb));
#pragma unroll
        for (int j = 0; j < 8; ++j) {
            nb0 = fmaf(swb[j].y, bf_lo(vv[j]), nb0);
            nb1 = fmaf(swb[j].y, bf_hi(vv[j]), nb1);
        }
    }
    if (e < end) {   // masked tail batch (1..7 edges)
        float2 swb[8];
        float  wb[8];
#pragma unroll
        for (int j = 0; j < 8; ++j) {
            int idx = e + j;
            int cl  = idx < end ? idx : e;
            swb[j] = sorted[cl];
            wb[j]  = idx < end ? swb[j].y : 0.f;
        }
        uint_t vv[8];
#pragma unroll
        for (int j = 0; j < 8; ++j)
            vv[j] = *(const uint_t*)(base + (((uint_t)__float_as_uint(swb[j].x) << 8) | lb));
#pragma unroll
        for (int j = 0; j < 8; ++j) {
            nb0 = fmaf(wb[j], bf_lo(vv[j]), nb0);
            nb1 = fmaf(wb[j], bf_hi(vv[j]), nb1);
        }
    }

    float2 k2 = ((const float2*)vk)[lane];
    float2 q2 = ((const float2*)vq)[lane];
    float sk = sv0 * k2.x + sv1 * k2.y;
    float sq = sv0 * q2.x + sv1 * q2.y;
    float nk = nb0 * k2.x + nb1 * k2.y;
#pragma unroll
    for (int off = 32; off; off >>= 1) {
        sk += __shfl_xor(sk, off);
        sq += __shfl_xor(sq, off);
        nk += __shfl_xor(nk, off);
    }
    float e0 = sk + sq;
    float e1 = nk + sq;
    e0 = e0 > 0.f ? e0 : expm1f(e0);
    e1 = e1 > 0.f ? e1 : expm1f(e1);
    float m = fmaxf(e0, e1);
    float a0 = expf(e0 - m);
    float a1 = expf(e1 - m);
    float inv = 1.f / (a0 + a1);
    a0 *= inv; a1 *= inv;

    float2 b2 = ((const float2*)bias)[lane];
    float o0 = fmaf(a0, sv0, fmaf(a1, nb0, b2.x));
    float o1 = fmaf(a0, sv1, fmaf(a1, nb1, b2.y));
    o0 = o0 > 0.f ? o0 : expm1f(o0);
    o1 = o1 > 0.f ? o1 : expm1f(o1);
    hout[(size_t)n * 64 + lane] = (uint_t)bf_bits(o0) | ((uint_t)bf_bits(o1) << 16);
    if (lane == 0) {
        attout[2 * (size_t)n + 0] = a0;
        attout[2 * (size_t)n + 1] = a1;
    }
}

// ---------------------------------------------------------------------------
// Fused gather-SpMM + attention, layer 2 (D=64). Wave per node, scalar meta.
// ---------------------------------------------------------------------------
__global__ __launch_bounds__(256) void fused2(
        const float* __restrict__ selfp, const ushort_t* __restrict__ relft,
        const int* __restrict__ rowptr, const float2* __restrict__ sorted,
        const float* __restrict__ vk, const float* __restrict__ vq,
        const float* __restrict__ bias,
        float* __restrict__ hout, float* __restrict__ attout, int M) {
    const int wv   = __builtin_amdgcn_readfirstlane(threadIdx.x >> 6);
    const int lane = threadIdx.x & 63;
    const int n = blockIdx.x * 4 + wv;
    if (n >= M) return;

    float sv = selfp[(size_t)n * 64 + lane];
    float nb = 0.f;

    const int beg = (n > 0) ? rowptr[n - 1] : 0;
    const int end = rowptr[n];
    const int len = end - beg;
    const char* base = (const char*)relft;
    const uint_t lb = (uint_t)lane << 1;

    int e = beg;
    const int efull = beg + (len & ~7);
    for (; e < efull; e += 8) {
        float2 swb[8];
#pragma unroll
        for (int j = 0; j < 8; ++j) swb[j] = sorted[e + j];
        ushort_t vv[8];
#pragma unroll
        for (int j = 0; j < 8; ++j)
            vv[j] = *(const ushort_t*)(base + (((uint_t)__float_as_uint(swb[j].x) << 7) | lb));
#pragma unroll
        for (int j = 0; j < 8; ++j) nb = fmaf(swb[j].y, bf_one(vv[j]), nb);
    }
    if (e < end) {
        float2 swb[8];
        float  wb[8];
#pragma unroll
        for (int j = 0; j < 8; ++j) {
            int idx = e + j;
            int cl  = idx < end ? idx : e;
            swb[j] = sorted[cl];
            wb[j]  = idx < end ? swb[j].y : 0.f;
        }
        ushort_t vv[8];
#pragma unroll
        for (int j = 0; j < 8; ++j)
            vv[j] = *(const ushort_t*)(base + (((uint_t)__float_as_uint(swb[j].x) << 7) | lb));
#pragma unroll
        for (int j = 0; j < 8; ++j) nb = fmaf(wb[j], bf_one(vv[j]), nb);
    }

    float kk = vk[lane], qq = vq[lane];
    float sk = sv * kk;
    float sq = sv * qq;
    float nk = nb * kk;
#pragma unroll
    for (int off = 32; off; off >>= 1) {
        sk += __shfl_xor(sk, off);
        sq += __shfl_xor(sq, off);
        nk += __shfl_xor(nk, off);
    }
    float e0 = sk + sq;
    float e1 = nk + sq;
    e0 = e0 > 0.f ? e0 : expm1f(e0);
    e1 = e1 > 0.f ? e1 : expm1f(e1);
    float m = fmaxf(e0, e1);
    float a0 = expf(e0 - m);
    float a1 = expf(e1 - m);
    float inv = 1.f / (a0 + a1);
    a0 *= inv; a1 *= inv;

    hout[(size_t)n * 64 + lane] = fmaf(a0, sv, fmaf(a1, nb, bias[lane]));
    if (lane == 0) {
        attout[2 * (size_t)n + 0] = a0;
        attout[2 * (size_t)n + 1] = a1;
    }
}

// ---------------------------------------------------------------------------
// Pool: register accumulation over sorted gid, flush on graph change.
// ---------------------------------------------------------------------------
__global__ __launch_bounds__(256) void pool_sum_v2(
        const float* __restrict__ h, const int* __restrict__ gid,
        float* __restrict__ sums, float* __restrict__ cnt, int M, int chunk) {
    int wave = threadIdx.x >> 6;
    int lane = threadIdx.x & 63;
    int wid  = blockIdx.x * 4 + wave;
    int beg  = wid * chunk;
    int end  = min(M, beg + chunk);
    if (beg >= end) return;

    int   cur_g = gid[beg];
    float acc   = 0.f;
    int   cl    = 0;
    for (int n = beg; n < end; ++n) {
        int g = gid[n];
        if (g != cur_g) {
            atomicAdd(&sums[(size_t)cur_g * D_OUT + lane], acc);
            if (lane == 0) atomicAdd(&cnt[cur_g], (float)cl);
            cur_g = g; acc = 0.f; cl = 0;
        }
        acc += h[(size_t)n * D_OUT + lane];
        ++cl;
    }
    atomicAdd(&sums[(size_t)cur_g * D_OUT + lane], acc);
    if (lane == 0) atomicAdd(&cnt[cur_g], (float)cl);
}

__global__ void pool_mlp(const float* __restrict__ sums, const float* __restrict__ cnt,
                         const float* __restrict__ w1, const float* __restrict__ b1,
                         const float* __restrict__ w2, const float* __restrict__ b2,
                         float* __restrict__ out) {
    int g = threadIdx.x;
    if (g >= NG) return;
    float c = fmaxf(cnt[g], 1.0f);
    float inv = 1.0f / c;
    float hg[D_OUT];
#pragma unroll
    for (int d = 0; d < D_OUT; ++d) hg[d] = sums[g * D_OUT + d] * inv;
    float acc = b2[0];
    for (int j = 0; j < D_OUT / 2; ++j) {
        float hid = b1[j];
#pragma unroll 8
        for (int d = 0; d < D_OUT; ++d) hid = fmaf(hg[d], w1[d * (D_OUT / 2) + j], hid);
        hid = fmaxf(hid, 0.f);
        acc = fmaf(hid, w2[j], acc);
    }
    out[g] = acc;
}

// ---------------------------------------------------------------------------
extern "C" void kernel_launch(void* const* d_in, const int* in_sizes, int n_in,
                              void* d_out, int out_size, void* d_ws, size_t ws_size,
                              hipStream_t stream) {
    const float* x       = (const float*)d_in[0];
    const int*   esrc    = (const int*)  d_in[1];
    const int*   edst    = (const int*)  d_in[2];
    const float* ew      = (const float*)d_in[3];
    const int*   gid     = (const int*)  d_in[4];
    const float* w_self1 = (const float*)d_in[5];
    const float* w_rel1  = (const float*)d_in[6];
    const float* bias1   = (const float*)d_in[7];
    const float* w_q1    = (const float*)d_in[8];
    const float* w_k1    = (const float*)d_in[9];
    const float* w_att1  = (const float*)d_in[10];
    const float* w_self2 = (const float*)d_in[11];
    const float* w_rel2  = (const float*)d_in[12];
    const float* bias2   = (const float*)d_in[13];
    const float* w_q2    = (const float*)d_in[14];
    const float* w_k2    = (const float*)d_in[15];
    const float* w_att2  = (const float*)d_in[16];
    const float* mlp_w1  = (const float*)d_in[17];
    const float* mlp_b1  = (const float*)d_in[18];
    const float* mlp_w2  = (const float*)d_in[19];
    const float* mlp_b2  = (const float*)d_in[20];

    const int N = in_sizes[0] / D_IN;
    const int E = in_sizes[1];

    float* out = (float*)d_out;
    float* out_embd = out;
    float* out_att1 = out + NG;
    float* out_att2 = out + NG + 2 * (size_t)N;

    // ---- Workspace layout (float units) ----
    float* ws = (float*)d_ws;
    size_t nf = (size_t)N;
    float* bufS = ws;                  // selfft1 bf16 (Nx128) -> selfft2 fp32 (Nx64)
    float* bufR = ws + nf * 64;        // relft1 bf16 (Nx128) -> relft2 bf16 (Nx64)
    float* bufH = ws + nf * 128;       // part[] during sort -> h1 bf16 -> h2 fp32
    uint2* part = (uint2*)bufH;        // E uint2
    int* ip     = (int*)(ws + nf * 192);   // 16B aligned
    int* bh     = ip;                  // NB*NBLK
    int* rowptr = ip + NB * NBLK;      // N
    int* bb     = rowptr + N;          // 257
    int* bt     = bb + 257;            // 256
    int* dctr   = bt + 256;            // 1
    size_t int_end = nf * 192 + (size_t)NB * NBLK + nf + 257 + 256 + 1;
    int_end = (int_end + 1) & ~(size_t)1;
    float2* sorted = (float2*)(ws + int_end);     // E float2
    float* small = ws + int_end + 2 * (size_t)E;
    float* vk1 = small + 0;
    float* vq1 = small + 128;
    float* vk2 = small + 256;
    float* vq2 = small + 320;
    float* sums = small + 384;
    float* cnt  = small + 384 + NG * D_OUT;
    ushort_t* wtb = (ushort_t*)(small + 384 + NG * D_OUT + NG);
    ushort_t* wt_s1 = wtb;
    ushort_t* wt_r1 = wtb + 16384;
    ushort_t* wt_s2 = wtb + 32768;
    ushort_t* wt_r2 = wtb + 40960;

    const int chunk = (E + NBLK - 1) / NBLK;
    const int nbuck = (N + (1 << BSHIFT) - 1) >> BSHIFT;
    const int nx    = (N + 63) / 64;
    const int g1    = (nx * 3) / 5;    // gemm1 blocks co-scheduled with scatter

    // Phase A: part_hist ∥ prep_wt ∥ prep_att ∥ zero accumulators + dctr
    phaseA<<<NBLK + 192 + 2 + 1, 256, 0, stream>>>(
        edst, E, chunk, bh,
        w_self1, w_rel1, w_self2, w_rel2, wtb,
        w_q1, w_k1, w_att1, w_q2, w_k2, w_att2, small, sums, dctr);

    // Parallel scan: per-bucket row scan + last-block cross-bucket scan
    scanA<<<NBLK, 256, 0, stream>>>(bh, bt, bb, dctr);

    // Phase B: part_scatter ∥ gemm1 (first g1 blocks)
    phaseB<<<NBLK + g1, 256, 0, stream>>>(
        esrc, edst, ew, E, chunk, bh, bb, part,
        x, N, wt_s1, wt_r1, (void*)bufS, (ushort_t*)bufR);

    // Phase C: bucket_sort ∥ gemm1 (remaining blocks)
    phaseC<<<nbuck + (nx - g1), 256, 0, stream>>>(
        part, bb, rowptr, sorted, N, nbuck, g1,
        x, N, wt_s1, wt_r1, (void*)bufS, (ushort_t*)bufR);

    fused1<<<(N + 3) / 4, 256, 0, stream>>>(
        (const uint_t*)bufS, (const ushort_t*)bufR, rowptr, sorted,
        vk1, vq1, bias1, (uint_t*)bufH, out_att1, N);

    gemm2_kernel<<<nx, 256, 0, stream>>>(
        (const void*)bufH, N, wt_s2, wt_r2, (void*)bufS, (ushort_t*)bufR);

    fused2<<<(N + 3) / 4, 256, 0, stream>>>(
        bufS, (const ushort_t*)bufR, rowptr, sorted,
        vk2, vq2, bias2, bufH, out_att2, N);

    {
        int pblocks = 1024;
        int pchunk  = (N + pblocks * 4 - 1) / (pblocks * 4);
        pool_sum_v2<<<pblocks, 256, 0, stream>>>(bufH, gid, sums, cnt, N, pchunk);
    }
    pool_mlp<<<1, 64, 0, stream>>>(sums, cnt, mlp_w1, mlp_b1, mlp_w2, mlp_b2, out_embd);
}